// Round 11
// baseline (1389.512 us; speedup 1.0000x reference)
//
#include <hip/hip_runtime.h>
#include <hip/hip_bf16.h>
#include <float.h>
#include <math.h>

// Problem constants
#define B_    4
#define H_    4
#define T_    8
#define D_    7
#define C_    128
#define HH_   14
#define S_    196     // 14*14
#define S4_   49      // S_/4
#define BT_   32      // B*T
#define HC_   512     // H*C
#define NODE_ 57      // 1 + T*D
#define K_    3
#define KD_   21      // K*D

#define BIG_  (BT_*D_*HC_*S_)   // 22,478,848 elements per big buffer
#define MS_   (B_*HC_*S_)       // 401,408 floats (master-size)
#define UB_   (BT_*D_*S_)       // 43904 big-pw u count
#define UM_   (B_*S_)           // 784 master u count
#define UMP_  896               // master u padded to 7*128
#define NT_   24                // K-tiles (3 x 512 / 64)
#define WS_   1024              // Waug stride: [hi 512 | lo 512]
#define NE4_  784               // 16ch*196s in f32x4 units

typedef unsigned short u16;
typedef unsigned int   u32;
typedef short bf16x8 __attribute__((ext_vector_type(8)));
typedef float f32x4  __attribute__((ext_vector_type(4)));

__device__ __forceinline__ float wave_max(float v){
    #pragma unroll
    for(int o=32;o>0;o>>=1) v = fmaxf(v, __shfl_xor(v,o,64));
    return v;
}
__device__ __forceinline__ float wave_sum(float v){
    #pragma unroll
    for(int o=32;o>0;o>>=1) v += __shfl_xor(v,o,64);
    return v;
}
__device__ __forceinline__ u16 f2bf(float f){
    u32 u = __float_as_uint(f);
    u += 0x7FFF + ((u>>16)&1);
    return (u16)(u>>16);
}
__device__ __forceinline__ float bf2f(u16 h){ return __uint_as_float(((u32)h)<<16); }

// async global->LDS, 16B per lane; LDS dest = wave-uniform base + lane*16
__device__ __forceinline__ void gld16(const void* g, void* l){
    __builtin_amdgcn_global_load_lds(
        (__attribute__((address_space(1))) void*)(void*)g,
        (__attribute__((address_space(3))) void*)l, 16, 0, 0);
}

// ---------------- pooling (max over S_) ----------------
__global__ void k_pool_x(const float* __restrict__ x, float* __restrict__ out){
    int v = blockIdx.x*4 + (threadIdx.x>>6);
    int lane = threadIdx.x & 63;
    int c = v & (C_-1);
    int r = v >> 7;
    int d = r % D_; r /= D_;
    int h = r & (H_-1); r >>= 2;
    int bt = r;
    int b = bt >> 3, t = bt & 7;
    const float* row = x + ((size_t)((b*H_+h)*NODE_ + 1 + t*D_ + d)*C_ + c)*S_;
    float m = -FLT_MAX;
    for(int s=lane; s<S_; s+=64) m = fmaxf(m, row[s]);
    m = wave_max(m);
    if(lane==0) out[v] = m;
}

__global__ void k_pool_conv(const float* __restrict__ in, float* __restrict__ out){
    int v = blockIdx.x*4 + (threadIdx.x>>6);
    int lane = threadIdx.x & 63;
    int c = v & (C_-1);
    int r = v >> 7;
    int d = r % D_; r /= D_;
    int h = r & (H_-1); r >>= 2;
    int bt = r;
    const float* row = in + ((size_t)((bt*D_+d)*HC_ + h*C_ + c))*S_;
    float m = -FLT_MAX;
    for(int s=lane; s<S_; s+=64) m = fmaxf(m, row[s]);
    m = wave_max(m);
    if(lane==0) out[v] = m;
}

__global__ void k_pool_x_master(const float* __restrict__ x, float* __restrict__ out){
    int v = blockIdx.x*4 + (threadIdx.x>>6);
    int lane = threadIdx.x & 63;
    int c = v & (C_-1);
    int h = (v>>7) & (H_-1);
    int b = v >> 9;
    const float* row = x + ((size_t)((b*H_+h)*NODE_)*C_ + c)*S_;
    float m = -FLT_MAX;
    for(int s=lane; s<S_; s+=64) m = fmaxf(m, row[s]);
    m = wave_max(m);
    if(lane==0) out[v] = m;
}

__global__ void k_pool_m1(const float* __restrict__ in, float* __restrict__ out){
    int v = blockIdx.x*4 + (threadIdx.x>>6);
    int lane = threadIdx.x & 63;
    int c = v & (C_-1);
    int h = (v>>7) & (H_-1);
    int b = v >> 9;
    const float* row = in + ((size_t)(b*HC_ + h*C_ + c))*S_;
    float m = -FLT_MAX;
    for(int s=lane; s<S_; s+=64) m = fmaxf(m, row[s]);
    m = wave_max(m);
    if(lane==0) out[v] = m;
}

__global__ void k_normalize(float* __restrict__ v){
    int vec = blockIdx.x;
    float val = v[(size_t)vec*C_ + threadIdx.x];
    float ss = wave_sum(val*val);
    __shared__ float sh[2];
    if((threadIdx.x&63)==0) sh[threadIdx.x>>6] = ss;
    __syncthreads();
    float tot = sh[0]+sh[1];
    v[(size_t)vec*C_ + threadIdx.x] = val / fmaxf(sqrtf(tot), 1e-12f);
}

// ---------------- A matrices ----------------
__global__ void k_A_if(const float* __restrict__ vn, const float* __restrict__ bias,
                       const float* __restrict__ alpha_p, float* __restrict__ A){
    int bh = blockIdx.x;           // bt*H + h
    __shared__ float vs[D_*C_];
    __shared__ float z[D_][D_];
    for(int e=threadIdx.x; e<D_*C_; e+=64) vs[e] = vn[(size_t)bh*D_*C_ + e];
    __syncthreads();
    float alpha = alpha_p[0];
    if(threadIdx.x < D_*D_){
        int n = threadIdx.x/D_, m = threadIdx.x%D_;
        float acc=0.f;
        for(int c=0;c<C_;c++) acc += vs[n*C_+c]*vs[m*C_+c];
        z[n][m] = acc/alpha + bias[n*D_+m];
    }
    __syncthreads();
    if(threadIdx.x < D_){
        int n = threadIdx.x;
        float mx=-FLT_MAX;
        for(int m=0;m<D_;m++) mx=fmaxf(mx,z[n][m]);
        float e[D_]; float sum=0.f;
        for(int m=0;m<D_;m++){ e[m]=expf(z[n][m]-mx); sum+=e[m]; }
        for(int m=0;m<D_;m++) A[((size_t)bh*D_+n)*D_+m] = e[m]/sum;
    }
}

__global__ void k_A_tm(const float* __restrict__ vm, const float* __restrict__ vnrm,
                       const float* __restrict__ bias, const float* __restrict__ alpha_p,
                       float* __restrict__ A){
    int bh = blockIdx.x;           // b*H + h
    int b = bh>>2, h = bh&3;
    __shared__ float v0[C_];
    __shared__ float z[NODE_];
    for(int e=threadIdx.x;e<C_;e+=64) v0[e]=vm[(size_t)bh*C_+e];
    __syncthreads();
    float alpha=alpha_p[0];
    if(threadIdx.x<NODE_){
        int m=threadIdx.x;
        float acc=0.f;
        if(m==0){
            for(int c=0;c<C_;c++) acc+=v0[c]*v0[c];
        } else {
            int t=(m-1)/D_, d=(m-1)%D_;
            const float* vp = vnrm + (size_t)(((b*T_+t)*H_+h)*D_+d)*C_;
            for(int c=0;c<C_;c++) acc+=v0[c]*vp[c];
        }
        z[m]=acc/alpha + bias[m];
    }
    __syncthreads();
    if(threadIdx.x==0){
        float mx=-FLT_MAX;
        for(int m=0;m<NODE_;m++) mx=fmaxf(mx,z[m]);
        float sum=0.f;
        for(int m=0;m<NODE_;m++){ z[m]=expf(z[m]-mx); sum+=z[m]; }
        for(int m=0;m<NODE_;m++) A[(size_t)bh*NODE_+m]=z[m]/sum;
    }
}

__global__ void k_topk(const float* __restrict__ voHat, int* __restrict__ idx){
    int bh = blockIdx.x;           // b*H + h
    int b = bh>>2, h = bh&3;
    __shared__ float mv[T_][C_];
    __shared__ float As[T_][T_];
    for(int e=threadIdx.x;e<T_*C_;e+=64){
        int t=e>>7, c=e&(C_-1);
        mv[t][c]=voHat[(size_t)(((b*T_+t)*H_+h)*D_+(D_-1))*C_+c];
    }
    __syncthreads();
    {
        int t=threadIdx.x>>3, s2=threadIdx.x&7;
        float acc=0.f;
        for(int c=0;c<C_;c++) acc+=mv[t][c]*mv[s2][c];
        As[t][s2]=acc;
    }
    __syncthreads();
    if(threadIdx.x<T_){
        int t=threadIdx.x;
        bool used[T_];
        for(int j=0;j<T_;j++) used[j]=false;
        for(int k=0;k<K_;k++){
            float mn=FLT_MAX; int bi=0;
            for(int s2=0;s2<T_;s2++){
                if(!used[s2] && As[t][s2]<mn){ mn=As[t][s2]; bi=s2; }
            }
            used[bi]=true;
            idx[((size_t)bh*T_+t)*K_+k]=bi;
        }
    }
}

__global__ void k_A_rev(const float* __restrict__ voHat, const int* __restrict__ idx,
                        const float* __restrict__ bias, const float* __restrict__ alpha_p,
                        float* __restrict__ A){
    int bth = blockIdx.x;          // bt*H + h
    int bt = bth>>2, h = bth&3;
    int b = bt>>3, t = bt&7;
    __shared__ float vo[D_][C_];
    __shared__ float vd[KD_][C_];
    __shared__ float z[D_][KD_];
    for(int e=threadIdx.x;e<D_*C_;e+=256){
        int n=e>>7, c=e&(C_-1);
        vo[n][c]=voHat[(size_t)((bt*H_+h)*D_+n)*C_+c];
    }
    for(int e=threadIdx.x;e<KD_*C_;e+=256){
        int m=e>>7, c=e&(C_-1);
        int k=m/D_, dp=m%D_;
        int tt=idx[((size_t)(b*H_+h)*T_+t)*K_+k];
        vd[m][c]=voHat[(size_t)(((b*T_+tt)*H_+h)*D_+dp)*C_+c];
    }
    __syncthreads();
    float alpha=alpha_p[0];
    if(threadIdx.x<D_*KD_){
        int n=threadIdx.x/KD_, m=threadIdx.x%KD_;
        float acc=0.f;
        for(int c=0;c<C_;c++) acc+=vo[n][c]*vd[m][c];
        z[n][m] = -acc/alpha + bias[n*KD_+m];
    }
    __syncthreads();
    if(threadIdx.x<D_){
        int n=threadIdx.x;
        float mx=-FLT_MAX;
        for(int m=0;m<KD_;m++) mx=fmaxf(mx,z[n][m]);
        float sum=0.f;
        for(int m=0;m<KD_;m++){ z[n][m]=expf(z[n][m]-mx); sum+=z[n][m]; }
        for(int m=0;m<KD_;m++) A[(size_t)((bt*H_+h)*D_+n)*KD_+m]=z[n][m]/sum;
    }
}

// ---------------- master aggregation (float4-vectorized) ----------------
__global__ void k_agg_tm(const float* __restrict__ mastersrc, int master_is_x,
                         const float* __restrict__ normal, const float* __restrict__ A,
                         float* __restrict__ out){
    int v = blockIdx.x*256 + threadIdx.x;       // < MS_/4
    int s4 = v % S4_;
    int r  = v / S4_;
    int hc = r & (HC_-1);
    int b  = r >> 9;
    int h = hc >> 7, c = hc & (C_-1);
    const float* Ap = A + (size_t)(b*H_+h)*NODE_;
    f32x4 m0;
    if(master_is_x) m0 = *(const f32x4*)(mastersrc + ((size_t)((b*H_+h)*NODE_)*C_ + c)*S_ + s4*4);
    else            m0 = *(const f32x4*)(mastersrc + (size_t)(b*HC_+hc)*S_ + s4*4);
    f32x4 acc = Ap[0]*m0;
    for(int t=0;t<T_;t++){
        const float* np = normal + ((size_t)((b*T_+t)*D_)*HC_+hc)*S_ + s4*4;
        #pragma unroll
        for(int d=0;d<D_;d++)
            acc += Ap[1+t*D_+d] * *(const f32x4*)(np + (size_t)d*HC_*S_);
    }
    *(f32x4*)(out + (size_t)r*S_ + s4*4) = acc;
}

// -------- shared dw+split tail (16-channel tiles) --------
__device__ __forceinline__ void dw_split_tail(float (*ti)[S_], float (*to)[S_],
                                              const float* __restrict__ w,
                                              const float* __restrict__ bias,
                                              int img, int ch0,
                                              u16* __restrict__ Xh, u16* __restrict__ Xl){
    int tid = threadIdx.x;
    for(int e=tid; e<16*S_; e+=256){
        int chl = e/S_, s = e - (e/S_)*S_;
        int ch = ch0 + chl;
        int y = s/HH_, xx = s - (s/HH_)*HH_;
        float acc = bias[ch];
        #pragma unroll
        for(int ky=0;ky<3;ky++){
            int yy=y+ky-1;
            if(yy<0||yy>=HH_) continue;
            #pragma unroll
            for(int kx=0;kx<3;kx++){
                int xx2=xx+kx-1;
                if(xx2<0||xx2>=HH_) continue;
                acc += ti[chl][yy*HH_+xx2]*w[ch*9+ky*3+kx];
            }
        }
        to[chl][s]=acc;
    }
    __syncthreads();
    for(int e=tid; e<16*S_; e+=256){
        int s = e>>4, chl = e&15;
        float f = to[chl][s];
        u16 h = f2bf(f);
        float lo = f - bf2f(h);
        size_t o = ((size_t)img*S_ + s)*HC_ + ch0 + chl;
        Xh[o] = h;
        Xl[o] = f2bf(lo);
    }
}

// ---------------- plain depthwise+split (master path) ----------------
__launch_bounds__(256)
__global__ void k_dwsplit(const float* __restrict__ in, const float* __restrict__ w,
                          const float* __restrict__ bias,
                          u16* __restrict__ Xh, u16* __restrict__ Xl){
    int img = blockIdx.x >> 5;
    int ch0 = (blockIdx.x & 31) * 16;
    __shared__ float ti[16][S_];
    __shared__ float to[16][S_];
    int tid = threadIdx.x;
    for(int e=tid; e<16*S4_; e+=256){
        int chl = e/S4_, s4 = e - (e/S4_)*S4_;
        *(f32x4*)&ti[chl][s4*4] =
            *(const f32x4*)(in + ((size_t)img*HC_ + ch0 + chl)*S_ + s4*4);
    }
    __syncthreads();
    dw_split_tail(ti, to, w, bias, img, ch0, Xh, Xl);
}

// ---------------- dwsplit + fused max-pool of the INPUT (pre-dw) ----------------
__launch_bounds__(256)
__global__ void k_dwsplit_pool(const float* __restrict__ in, const float* __restrict__ w,
                               const float* __restrict__ bias,
                               u16* __restrict__ Xh, u16* __restrict__ Xl,
                               float* __restrict__ pooled){
    int img = blockIdx.x >> 5;
    int ch0 = (blockIdx.x & 31) * 16;
    __shared__ float ti[16][S_];
    __shared__ float to[16][S_];
    __shared__ float pm[16][17];
    int tid = threadIdx.x;
    for(int e=tid; e<16*S4_; e+=256){
        int chl = e/S4_, s4 = e - (e/S4_)*S4_;
        *(f32x4*)&ti[chl][s4*4] =
            *(const f32x4*)(in + ((size_t)img*HC_ + ch0 + chl)*S_ + s4*4);
    }
    __syncthreads();
    dw_split_tail(ti, to, w, bias, img, ch0, Xh, Xl);
    {
        int chl = tid & 15, g = tid >> 4;
        float m = -FLT_MAX;
        for(int s=g; s<S_; s+=16) m = fmaxf(m, ti[chl][s]);
        pm[chl][g] = m;
    }
    __syncthreads();
    if(tid < 16){
        float mm = -FLT_MAX;
        #pragma unroll
        for(int g2=0; g2<16; g2++) mm = fmaxf(mm, pm[tid][g2]);
        int bt = img/7, d = img - (img/7)*7;
        pooled[(size_t)((bt*4 + (ch0>>7))*7 + d)*C_ + (ch0 & 127) + tid] = mm;
    }
}

// ---------------- fused IF (d-shared, reg-acc): block = (bt, 16-ch chunk) ----------------
// Streams the 7 shared source plane-chunks ONCE; acc[7][4] f32x4 in registers;
// then unrolled per-d {regs->LDS, dw, split}. Writes stay round-9-coalesced.
__launch_bounds__(256)
__global__ void k_fused_if(const float* __restrict__ x, const float* __restrict__ A,
                           const float* __restrict__ w, const float* __restrict__ bias,
                           u16* __restrict__ Xh, u16* __restrict__ Xl){
    int bt  = blockIdx.x >> 5;
    int ch0 = (blockIdx.x & 31) * 16;
    int h = ch0 >> 7, c0 = ch0 & 127;
    int b = bt >> 3, t = bt & 7;
    __shared__ float Ash[D_*D_];
    __shared__ float ti[16][S_];
    __shared__ float to[16][S_];
    int tid = threadIdx.x;
    if(tid < D_*D_) Ash[tid] = A[(size_t)((bt*4+h)*D_)*D_ + tid];
    __syncthreads();
    const float* xb = x + ((size_t)((b*H_+h)*NODE_ + 1 + t*D_)*C_ + c0)*S_;
    f32x4 acc[D_][4];
    #pragma unroll
    for(int d=0;d<D_;d++)
        #pragma unroll
        for(int q=0;q<4;q++) acc[d][q] = (f32x4){0.f,0.f,0.f,0.f};
    #pragma unroll
    for(int m=0;m<D_;m++){
        const f32x4* sp = (const f32x4*)(xb + (size_t)m*C_*S_);
        f32x4 v[4];
        #pragma unroll
        for(int q=0;q<4;q++){
            int e4 = tid + q*256;
            v[q] = (e4 < NE4_) ? sp[e4] : (f32x4){0.f,0.f,0.f,0.f};
        }
        #pragma unroll
        for(int d=0;d<D_;d++){
            float a = Ash[d*D_+m];
            #pragma unroll
            for(int q=0;q<4;q++) acc[d][q] += a*v[q];
        }
    }
    float* tif = &ti[0][0];
    #pragma unroll
    for(int d=0;d<D_;d++){
        __syncthreads();
        #pragma unroll
        for(int q=0;q<4;q++){
            int e4 = tid + q*256;
            if(e4 < NE4_) *(f32x4*)&tif[e4*4] = acc[d][q];
        }
        __syncthreads();
        dw_split_tail(ti, to, w, bias, bt*D_+d, ch0, Xh, Xl);
    }
}

// ---------------- fused REV (d-shared, reg-acc): block = (bt, 16-ch chunk) ----------------
// Streams the 21 gathered source plane-chunks ONCE (idx depends only on b,h,t).
__launch_bounds__(256)
__global__ void k_fused_rev(const float* __restrict__ n2, const float* __restrict__ A,
                            const int* __restrict__ idx,
                            const float* __restrict__ w, const float* __restrict__ bias,
                            u16* __restrict__ Xh, u16* __restrict__ Xl){
    int bt  = blockIdx.x >> 5;
    int ch0 = (blockIdx.x & 31) * 16;
    int h = ch0 >> 7;
    int b = bt >> 3, t = bt & 7;
    __shared__ float Ash[D_*KD_];
    __shared__ int tts[3];
    __shared__ float ti[16][S_];
    __shared__ float to[16][S_];
    int tid = threadIdx.x;
    if(tid < D_*KD_) Ash[tid] = A[(size_t)((bt*4+h)*D_)*KD_ + tid];
    if(tid>=160 && tid<163)
        tts[tid-160] = idx[((size_t)(b*H_+h)*T_+t)*K_ + (tid-160)];
    __syncthreads();
    const float* bases[K_];
    #pragma unroll
    for(int k=0;k<K_;k++)
        bases[k] = n2 + ((size_t)((b*T_+tts[k])*D_)*HC_ + ch0)*S_;
    f32x4 acc[D_][4];
    #pragma unroll
    for(int d=0;d<D_;d++)
        #pragma unroll
        for(int q=0;q<4;q++) acc[d][q] = (f32x4){0.f,0.f,0.f,0.f};
    #pragma unroll
    for(int j=0;j<KD_;j++){
        const int k = j/D_, dp = j - (j/D_)*D_;
        const f32x4* sp = (const f32x4*)(bases[k] + (size_t)dp*HC_*S_);
        f32x4 v[4];
        #pragma unroll
        for(int q=0;q<4;q++){
            int e4 = tid + q*256;
            v[q] = (e4 < NE4_) ? sp[e4] : (f32x4){0.f,0.f,0.f,0.f};
        }
        #pragma unroll
        for(int d=0;d<D_;d++){
            float a = Ash[d*KD_+j];
            #pragma unroll
            for(int q=0;q<4;q++) acc[d][q] += a*v[q];
        }
    }
    float* tif = &ti[0][0];
    #pragma unroll
    for(int d=0;d<D_;d++){
        __syncthreads();
        #pragma unroll
        for(int q=0;q<4;q++){
            int e4 = tid + q*256;
            if(e4 < NE4_) *(f32x4*)&tif[e4*4] = acc[d][q];
        }
        __syncthreads();
        dw_split_tail(ti, to, w, bias, bt*D_+d, ch0, Xh, Xl);
    }
}

// ---------------- weight prep: fp32 [oc][ic] -> bf16 Waug [oc][hi 512 | lo 512] ----------------
__global__ void k_prepW(const float* __restrict__ Wg, u16* __restrict__ Waug){
    int i = blockIdx.x*256 + threadIdx.x;   // < 512*512
    int oc = i >> 9, ic = i & 511;
    float f = Wg[i];
    u16 h = f2bf(f);
    float lo = f - bf2f(h);
    size_t base = (size_t)oc*WS_;
    Waug[base + ic]       = h;
    Waug[base + 512 + ic] = f2bf(lo);
}

// ---------------- MFMA pointwise GEMM (split-bf16, 24 K-tiles) ----------------
__launch_bounds__(512)
__global__ void k_pwmfma(const u16* __restrict__ Xh, const u16* __restrict__ Xl,
                         const u16* __restrict__ Waug, const float* __restrict__ bias,
                         const float* __restrict__ res, float* __restrict__ out,
                         int nwg, int utot){
    __shared__ u16 SM[2][16384];           // 2 x 32KB: [As 8192 u16 | Bs 8192 u16]
    const int tid  = threadIdx.x;
    const int q = nwg >> 3, r = nwg & 7;
    int xcd = blockIdx.x & 7, j = blockIdx.x >> 3;
    int L = xcd*q + (xcd < r ? xcd : r) + j;
    const int u0   = (L >> 2) * 128;
    const int oc0  = (L & 3) * 128;
    const int lane = tid & 63;
    const int w    = tid >> 6;             // 0..7
    const int wr   = w >> 1, wc = w & 1;   // 4 x 2 wave grid
    const int l15  = lane & 15, lg = lane >> 4;

    f32x4 acc[2][4];
    #pragma unroll
    for(int mi=0;mi<2;mi++)
        #pragma unroll
        for(int ni=0;ni<4;ni++)
            acc[mi][ni] = (f32x4){0.f,0.f,0.f,0.f};

    auto STAGE = [&](int t){               // 4 gld16 issues per wave (2A + 2B)
        int jj, wk, xk; const u16* Xp;
        if(t < 16){ jj = t>>1; wk = (t&1) ? 512 + jj*64 : jj*64; Xp = Xh; xk = jj*64; }
        else      { jj = t-16; wk = jj*64;                        Xp = Xl; xk = jj*64; }
        u16* Asb = SM[t&1];
        u16* Bsb = Asb + 8192;
        #pragma unroll
        for(int i=0;i<2;i++){
            int seg = w*2 + i;             // 0..15, 8 rows each
            int row = seg*8 + (lane>>3);
            int cg  = (lane&7) ^ (lane>>3);
            gld16(Waug + (size_t)(oc0+row)*WS_ + wk + cg*8, Asb + seg*512);
            gld16(Xp   + (size_t)(u0 +row)*512 + xk + cg*8, Bsb + seg*512);
        }
    };
    auto COMPUTE = [&](int cur){
        const u16* Asb = SM[cur];
        const u16* Bsb = SM[cur] + 8192;
        #pragma unroll
        for(int ks=0;ks<2;ks++){
            bf16x8 a[2], b[4];
            #pragma unroll
            for(int mi=0;mi<2;mi++){
                int row = wr*32 + mi*16 + l15;
                int ch  = ((ks<<2) + lg) ^ (row & 7);
                a[mi] = *(const bf16x8*)(Asb + row*64 + ch*8);
            }
            #pragma unroll
            for(int ni=0;ni<4;ni++){
                int row = wc*64 + ni*16 + l15;
                int ch  = ((ks<<2) + lg) ^ (row & 7);
                b[ni] = *(const bf16x8*)(Bsb + row*64 + ch*8);
            }
            #pragma unroll
            for(int mi=0;mi<2;mi++)
                #pragma unroll
                for(int ni=0;ni<4;ni++)
                    acc[mi][ni] = __builtin_amdgcn_mfma_f32_16x16x32_bf16(a[mi], b[ni], acc[mi][ni], 0,0,0);
        }
    };

    STAGE(0);
    for(int t=0; t<NT_; t++){
        if(t+1 < NT_){
            STAGE(t+1);                                      // 8 outstanding/wave
            asm volatile("s_waitcnt vmcnt(4)" ::: "memory"); // tile t landed
        } else {
            asm volatile("s_waitcnt vmcnt(0)" ::: "memory");
        }
        __builtin_amdgcn_s_barrier();      // all waves' tile-t loads in LDS
        asm volatile("" ::: "memory");
        COMPUTE(t&1);
        asm volatile("" ::: "memory");
        __builtin_amdgcn_s_barrier();      // buf[t&1] free for restage
    }

    #pragma unroll
    for(int ni=0;ni<4;ni++){
        int u = u0 + wc*64 + ni*16 + l15;
        if(u >= utot) continue;
        int img = u / S_, s = u - img*S_;
        #pragma unroll
        for(int mi=0;mi<2;mi++){
            int ocb = oc0 + wr*32 + mi*16 + lg*4;
            #pragma unroll
            for(int q2=0;q2<4;q2++){
                int oc = ocb + q2;
                size_t oidx = ((size_t)img*HC_ + oc)*S_ + s;
                float v = acc[mi][ni][q2] + bias[oc];
                if(res) v += res[oidx];
                out[oidx] = v;
            }
        }
    }
}

extern "C" void kernel_launch(void* const* d_in, const int* in_sizes, int n_in,
                              void* d_out, int out_size, void* d_ws, size_t ws_size,
                              hipStream_t stream){
    (void)in_sizes; (void)n_in; (void)out_size; (void)ws_size;
    const float* x         = (const float*)d_in[0];
    const float* alpha_if  = (const float*)d_in[1];
    const float* alpha_tm1 = (const float*)d_in[2];
    const float* alpha_rev = (const float*)d_in[3];
    const float* alpha_tm2 = (const float*)d_in[4];
    const float* bias_if   = (const float*)d_in[5];
    const float* bias_tm1  = (const float*)d_in[6];
    const float* bias_rev  = (const float*)d_in[7];
    const float* bias_tm2  = (const float*)d_in[8];
    const float* if_dw =(const float*)d_in[9];  const float* if_dwb =(const float*)d_in[10];
    const float* if_pw =(const float*)d_in[11]; const float* if_pwb =(const float*)d_in[12];
    const float* tm1_dw=(const float*)d_in[13]; const float* tm1_dwb=(const float*)d_in[14];
    const float* tm1_pw=(const float*)d_in[15]; const float* tm1_pwb=(const float*)d_in[16];
    const float* rev_dw=(const float*)d_in[17]; const float* rev_dwb=(const float*)d_in[18];
    const float* rev_pw=(const float*)d_in[19]; const float* rev_pwb=(const float*)d_in[20];
    const float* tm2_dw=(const float*)d_in[21]; const float* tm2_dwb=(const float*)d_in[22];
    const float* tm2_pw=(const float*)d_in[23]; const float* tm2_pwb=(const float*)d_in[24];
    const float* tr_dw =(const float*)d_in[25]; const float* tr_dwb =(const float*)d_in[26];
    const float* tr_pw =(const float*)d_in[27]; const float* tr_pwb =(const float*)d_in[28];

    float* ws = (float*)d_ws;
    float* G0      = ws;                          // BIG_ fp32
    float* G1      = G0 + (size_t)BIG_;           // BIG_ fp32
    u16*   Xh      = (u16*)(ws + 2*(size_t)BIG_); // BIG_ u16
    u16*   Xl      = Xh + (size_t)BIG_;           // BIG_ u16
    u16*   WA0     = Xl + (size_t)BIG_;           // 512*1024 u16 each
    u16*   WA1     = WA0 + 512*WS_;
    u16*   WA2     = WA1 + 512*WS_;
    u16*   WA3     = WA2 + 512*WS_;               // tm1
    u16*   WA4     = WA3 + 512*WS_;               // tm2
    u16*   XhM     = WA4 + 512*WS_;               // UMP_*512 u16 master X
    u16*   XlM     = XhM + (size_t)UMP_*HC_;
    float* master1 = (float*)(XlM + (size_t)UMP_*HC_);   // MS_
    float* Ma      = master1 + MS_;               // MS_
    float* pooledN = Ma + MS_;                    // 114688
    float* pooledM = pooledN + BT_*H_*D_*C_;      // 2048
    float* Aif     = pooledM + B_*H_*C_;          // 6272
    float* Atm1    = Aif + BT_*H_*D_*D_;          // 912
    float* Arev    = Atm1 + B_*H_*NODE_;          // 18816
    float* Atm2    = Arev + BT_*H_*D_*KD_;        // 912
    int*   idxb    = (int*)(Atm2 + B_*H_*NODE_);  // 384 ints
    float* out     = (float*)d_out;

    const int NV  = BT_*H_*D_*C_;     // pooled rows
    const int gemmGrid  = (UB_/128)*4;          // 1372
    const int gemmGridM = (UMP_/128)*4;         // 28
    const int dsGrid    = BT_*D_*32;  // 7168 (16-ch chunks)
    const int dsGridM   = B_*32;      // 128
    const int fusedGrid = BT_*32;     // 1024 (bt x 16-ch chunks, d-shared)
    float* null_res = nullptr;

    // weight prep (all five pw weights)
    k_prepW<<<1024, 256, 0, stream>>>(if_pw,  WA0);
    k_prepW<<<1024, 256, 0, stream>>>(tr_pw,  WA1);
    k_prepW<<<1024, 256, 0, stream>>>(rev_pw, WA2);
    k_prepW<<<1024, 256, 0, stream>>>(tm1_pw, WA3);
    k_prepW<<<1024, 256, 0, stream>>>(tm2_pw, WA4);

    // ---- stage 1: IF ----
    k_pool_x   <<<NV/4, 256, 0, stream>>>(x, pooledN);
    k_normalize<<<NV/C_, 128, 0, stream>>>(pooledN);
    k_A_if     <<<BT_*H_, 64, 0, stream>>>(pooledN, bias_if, alpha_if, Aif);
    k_fused_if <<<fusedGrid, 256, 0, stream>>>(x, Aif, if_dw, if_dwb, Xh, Xl);
    k_pwmfma   <<<gemmGrid, 512, 0, stream>>>(Xh, Xl, WA0, if_pwb, null_res, G1, gemmGrid, UB_);
    // G1 = normal1

    // ---- stage 2+3 (reordered): tr dwsplit+pool first, then masters, then tr GEMM ----
    k_dwsplit_pool<<<dsGrid, 256, 0, stream>>>(G1, tr_dw, tr_dwb, Xh, Xl, pooledN);
    k_normalize<<<NV/C_, 128, 0, stream>>>(pooledN);
    k_pool_x_master<<<(B_*H_*C_)/4, 256, 0, stream>>>(x, pooledM);
    k_normalize<<<B_*H_, 128, 0, stream>>>(pooledM);
    k_A_tm     <<<B_*H_, 64, 0, stream>>>(pooledM, pooledN, bias_tm1, alpha_tm1, Atm1);
    k_agg_tm   <<<MS_/1024, 256, 0, stream>>>(x, 1, G1, Atm1, Ma);
    k_dwsplit  <<<dsGridM, 256, 0, stream>>>(Ma, tm1_dw, tm1_dwb, XhM, XlM);
    k_pwmfma   <<<gemmGridM, 512, 0, stream>>>(XhM, XlM, WA3, tm1_pwb, null_res, master1, gemmGridM, UM_);
    k_pwmfma   <<<gemmGrid, 512, 0, stream>>>(Xh, Xl, WA1, tr_pwb, null_res, G0, gemmGrid, UB_);
    // G0 = normal2

    // ---- stage 4: rev ----
    k_pool_conv<<<NV/4, 256, 0, stream>>>(G0, pooledN);
    k_normalize<<<NV/C_, 128, 0, stream>>>(pooledN);
    k_topk     <<<B_*H_, 64, 0, stream>>>(pooledN, idxb);
    k_A_rev    <<<BT_*H_, 256, 0, stream>>>(pooledN, idxb, bias_rev, alpha_rev, Arev);
    k_fused_rev<<<fusedGrid, 256, 0, stream>>>(G0, Arev, idxb, rev_dw, rev_dwb, Xh, Xl);
    k_pwmfma   <<<gemmGrid, 512, 0, stream>>>(Xh, Xl, WA2, rev_pwb, G0, G1, gemmGrid, UB_);
    // G1 = normal3 (residual fused)

    // ---- stage 5: tm2 master -> output ----
    k_pool_conv<<<NV/4, 256, 0, stream>>>(G1, pooledN);
    k_normalize<<<NV/C_, 128, 0, stream>>>(pooledN);
    k_pool_m1  <<<(B_*H_*C_)/4, 256, 0, stream>>>(master1, pooledM);
    k_normalize<<<B_*H_, 128, 0, stream>>>(pooledM);
    k_A_tm     <<<B_*H_, 64, 0, stream>>>(pooledM, pooledN, bias_tm2, alpha_tm2, Atm2);
    k_agg_tm   <<<MS_/1024, 256, 0, stream>>>(master1, 0, G1, Atm2, Ma);
    k_dwsplit  <<<dsGridM, 256, 0, stream>>>(Ma, tm2_dw, tm2_dwb, XhM, XlM);
    k_pwmfma   <<<gemmGridM, 512, 0, stream>>>(XhM, XlM, WA4, tm2_pwb, null_res, out, gemmGridM, UM_);
}

// Round 12
// 1370.435 us; speedup vs baseline: 1.0139x; 1.0139x over previous
//
#include <hip/hip_runtime.h>
#include <hip/hip_bf16.h>
#include <float.h>
#include <math.h>

// Problem constants
#define B_    4
#define H_    4
#define T_    8
#define D_    7
#define C_    128
#define HH_   14
#define S_    196     // 14*14
#define S4_   49      // S_/4
#define BT_   32      // B*T
#define HC_   512     // H*C
#define NODE_ 57      // 1 + T*D
#define K_    3
#define KD_   21      // K*D

#define BIG_  (BT_*D_*HC_*S_)   // 22,478,848 elements per big buffer
#define MS_   (B_*HC_*S_)       // 401,408 floats (master-size)
#define UB_   (BT_*D_*S_)       // 43904 big-pw u count
#define UM_   (B_*S_)           // 784 master u count
#define UMP_  896               // master u padded to 7*128
#define NT_   24                // K-tiles (3 x 512 / 64)
#define WS_   1024              // Waug stride: [hi 512 | lo 512]
#define NE4_  784               // 16ch*196s in f32x4 units
#define PSTR4_ (C_*S4_)         // f32x4 stride between planes (6272)

typedef unsigned short u16;
typedef unsigned int   u32;
typedef short bf16x8 __attribute__((ext_vector_type(8)));
typedef float f32x4  __attribute__((ext_vector_type(4)));

__device__ __forceinline__ float wave_max(float v){
    #pragma unroll
    for(int o=32;o>0;o>>=1) v = fmaxf(v, __shfl_xor(v,o,64));
    return v;
}
__device__ __forceinline__ float wave_sum(float v){
    #pragma unroll
    for(int o=32;o>0;o>>=1) v += __shfl_xor(v,o,64);
    return v;
}
__device__ __forceinline__ u16 f2bf(float f){
    u32 u = __float_as_uint(f);
    u += 0x7FFF + ((u>>16)&1);
    return (u16)(u>>16);
}
__device__ __forceinline__ float bf2f(u16 h){ return __uint_as_float(((u32)h)<<16); }

// async global->LDS, 16B per lane; LDS dest = wave-uniform base + lane*16
__device__ __forceinline__ void gld16(const void* g, void* l){
    __builtin_amdgcn_global_load_lds(
        (__attribute__((address_space(1))) void*)(void*)g,
        (__attribute__((address_space(3))) void*)l, 16, 0, 0);
}

// ---------------- pooling (max over S_) ----------------
__global__ void k_pool_x(const float* __restrict__ x, float* __restrict__ out){
    int v = blockIdx.x*4 + (threadIdx.x>>6);
    int lane = threadIdx.x & 63;
    int c = v & (C_-1);
    int r = v >> 7;
    int d = r % D_; r /= D_;
    int h = r & (H_-1); r >>= 2;
    int bt = r;
    int b = bt >> 3, t = bt & 7;
    const float* row = x + ((size_t)((b*H_+h)*NODE_ + 1 + t*D_ + d)*C_ + c)*S_;
    float m = -FLT_MAX;
    for(int s=lane; s<S_; s+=64) m = fmaxf(m, row[s]);
    m = wave_max(m);
    if(lane==0) out[v] = m;
}

__global__ void k_pool_conv(const float* __restrict__ in, float* __restrict__ out){
    int v = blockIdx.x*4 + (threadIdx.x>>6);
    int lane = threadIdx.x & 63;
    int c = v & (C_-1);
    int r = v >> 7;
    int d = r % D_; r /= D_;
    int h = r & (H_-1); r >>= 2;
    int bt = r;
    const float* row = in + ((size_t)((bt*D_+d)*HC_ + h*C_ + c))*S_;
    float m = -FLT_MAX;
    for(int s=lane; s<S_; s+=64) m = fmaxf(m, row[s]);
    m = wave_max(m);
    if(lane==0) out[v] = m;
}

__global__ void k_pool_x_master(const float* __restrict__ x, float* __restrict__ out){
    int v = blockIdx.x*4 + (threadIdx.x>>6);
    int lane = threadIdx.x & 63;
    int c = v & (C_-1);
    int h = (v>>7) & (H_-1);
    int b = v >> 9;
    const float* row = x + ((size_t)((b*H_+h)*NODE_)*C_ + c)*S_;
    float m = -FLT_MAX;
    for(int s=lane; s<S_; s+=64) m = fmaxf(m, row[s]);
    m = wave_max(m);
    if(lane==0) out[v] = m;
}

__global__ void k_pool_m1(const float* __restrict__ in, float* __restrict__ out){
    int v = blockIdx.x*4 + (threadIdx.x>>6);
    int lane = threadIdx.x & 63;
    int c = v & (C_-1);
    int h = (v>>7) & (H_-1);
    int b = v >> 9;
    const float* row = in + ((size_t)(b*HC_ + h*C_ + c))*S_;
    float m = -FLT_MAX;
    for(int s=lane; s<S_; s+=64) m = fmaxf(m, row[s]);
    m = wave_max(m);
    if(lane==0) out[v] = m;
}

__global__ void k_normalize(float* __restrict__ v){
    int vec = blockIdx.x;
    float val = v[(size_t)vec*C_ + threadIdx.x];
    float ss = wave_sum(val*val);
    __shared__ float sh[2];
    if((threadIdx.x&63)==0) sh[threadIdx.x>>6] = ss;
    __syncthreads();
    float tot = sh[0]+sh[1];
    v[(size_t)vec*C_ + threadIdx.x] = val / fmaxf(sqrtf(tot), 1e-12f);
}

// ---------------- A matrices ----------------
__global__ void k_A_if(const float* __restrict__ vn, const float* __restrict__ bias,
                       const float* __restrict__ alpha_p, float* __restrict__ A){
    int bh = blockIdx.x;           // bt*H + h
    __shared__ float vs[D_*C_];
    __shared__ float z[D_][D_];
    for(int e=threadIdx.x; e<D_*C_; e+=64) vs[e] = vn[(size_t)bh*D_*C_ + e];
    __syncthreads();
    float alpha = alpha_p[0];
    if(threadIdx.x < D_*D_){
        int n = threadIdx.x/D_, m = threadIdx.x%D_;
        float acc=0.f;
        for(int c=0;c<C_;c++) acc += vs[n*C_+c]*vs[m*C_+c];
        z[n][m] = acc/alpha + bias[n*D_+m];
    }
    __syncthreads();
    if(threadIdx.x < D_){
        int n = threadIdx.x;
        float mx=-FLT_MAX;
        for(int m=0;m<D_;m++) mx=fmaxf(mx,z[n][m]);
        float e[D_]; float sum=0.f;
        for(int m=0;m<D_;m++){ e[m]=expf(z[n][m]-mx); sum+=e[m]; }
        for(int m=0;m<D_;m++) A[((size_t)bh*D_+n)*D_+m] = e[m]/sum;
    }
}

__global__ void k_A_tm(const float* __restrict__ vm, const float* __restrict__ vnrm,
                       const float* __restrict__ bias, const float* __restrict__ alpha_p,
                       float* __restrict__ A){
    int bh = blockIdx.x;           // b*H + h
    int b = bh>>2, h = bh&3;
    __shared__ float v0[C_];
    __shared__ float z[NODE_];
    for(int e=threadIdx.x;e<C_;e+=64) v0[e]=vm[(size_t)bh*C_+e];
    __syncthreads();
    float alpha=alpha_p[0];
    if(threadIdx.x<NODE_){
        int m=threadIdx.x;
        float acc=0.f;
        if(m==0){
            for(int c=0;c<C_;c++) acc+=v0[c]*v0[c];
        } else {
            int t=(m-1)/D_, d=(m-1)%D_;
            const float* vp = vnrm + (size_t)(((b*T_+t)*H_+h)*D_+d)*C_;
            for(int c=0;c<C_;c++) acc+=v0[c]*vp[c];
        }
        z[m]=acc/alpha + bias[m];
    }
    __syncthreads();
    if(threadIdx.x==0){
        float mx=-FLT_MAX;
        for(int m=0;m<NODE_;m++) mx=fmaxf(mx,z[m]);
        float sum=0.f;
        for(int m=0;m<NODE_;m++){ z[m]=expf(z[m]-mx); sum+=z[m]; }
        for(int m=0;m<NODE_;m++) A[(size_t)bh*NODE_+m]=z[m]/sum;
    }
}

__global__ void k_topk(const float* __restrict__ voHat, int* __restrict__ idx){
    int bh = blockIdx.x;           // b*H + h
    int b = bh>>2, h = bh&3;
    __shared__ float mv[T_][C_];
    __shared__ float As[T_][T_];
    for(int e=threadIdx.x;e<T_*C_;e+=64){
        int t=e>>7, c=e&(C_-1);
        mv[t][c]=voHat[(size_t)(((b*T_+t)*H_+h)*D_+(D_-1))*C_+c];
    }
    __syncthreads();
    {
        int t=threadIdx.x>>3, s2=threadIdx.x&7;
        float acc=0.f;
        for(int c=0;c<C_;c++) acc+=mv[t][c]*mv[s2][c];
        As[t][s2]=acc;
    }
    __syncthreads();
    if(threadIdx.x<T_){
        int t=threadIdx.x;
        bool used[T_];
        for(int j=0;j<T_;j++) used[j]=false;
        for(int k=0;k<K_;k++){
            float mn=FLT_MAX; int bi=0;
            for(int s2=0;s2<T_;s2++){
                if(!used[s2] && As[t][s2]<mn){ mn=As[t][s2]; bi=s2; }
            }
            used[bi]=true;
            idx[((size_t)bh*T_+t)*K_+k]=bi;
        }
    }
}

__global__ void k_A_rev(const float* __restrict__ voHat, const int* __restrict__ idx,
                        const float* __restrict__ bias, const float* __restrict__ alpha_p,
                        float* __restrict__ A){
    int bth = blockIdx.x;          // bt*H + h
    int bt = bth>>2, h = bth&3;
    int b = bt>>3, t = bt&7;
    __shared__ float vo[D_][C_];
    __shared__ float vd[KD_][C_];
    __shared__ float z[D_][KD_];
    for(int e=threadIdx.x;e<D_*C_;e+=256){
        int n=e>>7, c=e&(C_-1);
        vo[n][c]=voHat[(size_t)((bt*H_+h)*D_+n)*C_+c];
    }
    for(int e=threadIdx.x;e<KD_*C_;e+=256){
        int m=e>>7, c=e&(C_-1);
        int k=m/D_, dp=m%D_;
        int tt=idx[((size_t)(b*H_+h)*T_+t)*K_+k];
        vd[m][c]=voHat[(size_t)(((b*T_+tt)*H_+h)*D_+dp)*C_+c];
    }
    __syncthreads();
    float alpha=alpha_p[0];
    if(threadIdx.x<D_*KD_){
        int n=threadIdx.x/KD_, m=threadIdx.x%KD_;
        float acc=0.f;
        for(int c=0;c<C_;c++) acc+=vo[n][c]*vd[m][c];
        z[n][m] = -acc/alpha + bias[n*KD_+m];
    }
    __syncthreads();
    if(threadIdx.x<D_){
        int n=threadIdx.x;
        float mx=-FLT_MAX;
        for(int m=0;m<KD_;m++) mx=fmaxf(mx,z[n][m]);
        float sum=0.f;
        for(int m=0;m<KD_;m++){ z[n][m]=expf(z[n][m]-mx); sum+=z[n][m]; }
        for(int m=0;m<KD_;m++) A[(size_t)((bt*H_+h)*D_+n)*KD_+m]=z[n][m]/sum;
    }
}

// ---------------- master aggregation (float4-vectorized) ----------------
__global__ void k_agg_tm(const float* __restrict__ mastersrc, int master_is_x,
                         const float* __restrict__ normal, const float* __restrict__ A,
                         float* __restrict__ out){
    int v = blockIdx.x*256 + threadIdx.x;       // < MS_/4
    int s4 = v % S4_;
    int r  = v / S4_;
    int hc = r & (HC_-1);
    int b  = r >> 9;
    int h = hc >> 7, c = hc & (C_-1);
    const float* Ap = A + (size_t)(b*H_+h)*NODE_;
    f32x4 m0;
    if(master_is_x) m0 = *(const f32x4*)(mastersrc + ((size_t)((b*H_+h)*NODE_)*C_ + c)*S_ + s4*4);
    else            m0 = *(const f32x4*)(mastersrc + (size_t)(b*HC_+hc)*S_ + s4*4);
    f32x4 acc = Ap[0]*m0;
    for(int t=0;t<T_;t++){
        const float* np = normal + ((size_t)((b*T_+t)*D_)*HC_+hc)*S_ + s4*4;
        #pragma unroll
        for(int d=0;d<D_;d++)
            acc += Ap[1+t*D_+d] * *(const f32x4*)(np + (size_t)d*HC_*S_);
    }
    *(f32x4*)(out + (size_t)r*S_ + s4*4) = acc;
}

// -------- shared dw+split tail (16-channel tiles) --------
__device__ __forceinline__ void dw_split_tail(float (*ti)[S_], float (*to)[S_],
                                              const float* __restrict__ w,
                                              const float* __restrict__ bias,
                                              int img, int ch0,
                                              u16* __restrict__ Xh, u16* __restrict__ Xl){
    int tid = threadIdx.x;
    for(int e=tid; e<16*S_; e+=256){
        int chl = e/S_, s = e - (e/S_)*S_;
        int ch = ch0 + chl;
        int y = s/HH_, xx = s - (s/HH_)*HH_;
        float acc = bias[ch];
        #pragma unroll
        for(int ky=0;ky<3;ky++){
            int yy=y+ky-1;
            if(yy<0||yy>=HH_) continue;
            #pragma unroll
            for(int kx=0;kx<3;kx++){
                int xx2=xx+kx-1;
                if(xx2<0||xx2>=HH_) continue;
                acc += ti[chl][yy*HH_+xx2]*w[ch*9+ky*3+kx];
            }
        }
        to[chl][s]=acc;
    }
    __syncthreads();
    for(int e=tid; e<16*S_; e+=256){
        int s = e>>4, chl = e&15;
        float f = to[chl][s];
        u16 h = f2bf(f);
        float lo = f - bf2f(h);
        size_t o = ((size_t)img*S_ + s)*HC_ + ch0 + chl;
        Xh[o] = h;
        Xl[o] = f2bf(lo);
    }
}

// ---------------- plain depthwise+split (master path) ----------------
__launch_bounds__(256)
__global__ void k_dwsplit(const float* __restrict__ in, const float* __restrict__ w,
                          const float* __restrict__ bias,
                          u16* __restrict__ Xh, u16* __restrict__ Xl){
    int img = blockIdx.x >> 5;
    int ch0 = (blockIdx.x & 31) * 16;
    __shared__ float ti[16][S_];
    __shared__ float to[16][S_];
    int tid = threadIdx.x;
    for(int e=tid; e<16*S4_; e+=256){
        int chl = e/S4_, s4 = e - (e/S4_)*S4_;
        *(f32x4*)&ti[chl][s4*4] =
            *(const f32x4*)(in + ((size_t)img*HC_ + ch0 + chl)*S_ + s4*4);
    }
    __syncthreads();
    dw_split_tail(ti, to, w, bias, img, ch0, Xh, Xl);
}

// ---------------- dwsplit + fused max-pool of the INPUT (pre-dw) ----------------
__launch_bounds__(256)
__global__ void k_dwsplit_pool(const float* __restrict__ in, const float* __restrict__ w,
                               const float* __restrict__ bias,
                               u16* __restrict__ Xh, u16* __restrict__ Xl,
                               float* __restrict__ pooled){
    int img = blockIdx.x >> 5;
    int ch0 = (blockIdx.x & 31) * 16;
    __shared__ float ti[16][S_];
    __shared__ float to[16][S_];
    __shared__ float pm[16][17];
    int tid = threadIdx.x;
    for(int e=tid; e<16*S4_; e+=256){
        int chl = e/S4_, s4 = e - (e/S4_)*S4_;
        *(f32x4*)&ti[chl][s4*4] =
            *(const f32x4*)(in + ((size_t)img*HC_ + ch0 + chl)*S_ + s4*4);
    }
    __syncthreads();
    dw_split_tail(ti, to, w, bias, img, ch0, Xh, Xl);
    {
        int chl = tid & 15, g = tid >> 4;
        float m = -FLT_MAX;
        for(int s=g; s<S_; s+=16) m = fmaxf(m, ti[chl][s]);
        pm[chl][g] = m;
    }
    __syncthreads();
    if(tid < 16){
        float mm = -FLT_MAX;
        #pragma unroll
        for(int g2=0; g2<16; g2++) mm = fmaxf(mm, pm[tid][g2]);
        int bt = img/7, d = img - (img/7)*7;
        pooled[(size_t)((bt*4 + (ch0>>7))*7 + d)*C_ + (ch0 & 127) + tid] = mm;
    }
}

// ---------------- fused IF (d-shared, 2-group reg-acc) ----------------
// block = (bt, 16-ch chunk); group ND d-outputs per source pass (64 VGPR acc max)
template<int ND>
__device__ __forceinline__ void if_group(const float* __restrict__ xb, const float* __restrict__ Ash,
                                         int d0, float (*ti)[S_], float (*to)[S_],
                                         const float* __restrict__ w, const float* __restrict__ bias,
                                         int bt, int ch0,
                                         u16* __restrict__ Xh, u16* __restrict__ Xl){
    int tid = threadIdx.x;
    f32x4 acc[ND][4];
    #pragma unroll
    for(int dd=0;dd<ND;dd++)
        #pragma unroll
        for(int q=0;q<4;q++) acc[dd][q]=(f32x4){0.f,0.f,0.f,0.f};
    #pragma unroll
    for(int q=0;q<4;q++){
        int e4 = tid + q*256;
        bool ok = e4 < NE4_;
        #pragma unroll
        for(int m=0;m<D_;m++){
            f32x4 v = ok ? *((const f32x4*)xb + (size_t)m*PSTR4_ + e4) : (f32x4){0.f,0.f,0.f,0.f};
            #pragma unroll
            for(int dd=0;dd<ND;dd++)
                acc[dd][q] += Ash[(d0+dd)*D_+m]*v;
        }
    }
    float* tif = &ti[0][0];
    #pragma unroll
    for(int dd=0;dd<ND;dd++){
        __syncthreads();
        #pragma unroll
        for(int q=0;q<4;q++){
            int e4 = tid + q*256;
            if(e4 < NE4_) *(f32x4*)&tif[e4*4] = acc[dd][q];
        }
        __syncthreads();
        dw_split_tail(ti, to, w, bias, bt*D_+d0+dd, ch0, Xh, Xl);
    }
}

__launch_bounds__(256)
__global__ void k_fused_if(const float* __restrict__ x, const float* __restrict__ A,
                           const float* __restrict__ w, const float* __restrict__ bias,
                           u16* __restrict__ Xh, u16* __restrict__ Xl){
    int bt  = blockIdx.x >> 5;
    int ch0 = (blockIdx.x & 31) * 16;
    int h = ch0 >> 7, c0 = ch0 & 127;
    int b = bt >> 3, t = bt & 7;
    __shared__ float Ash[D_*D_];
    __shared__ float ti[16][S_];
    __shared__ float to[16][S_];
    int tid = threadIdx.x;
    if(tid < D_*D_) Ash[tid] = A[(size_t)((bt*4+h)*D_)*D_ + tid];
    __syncthreads();
    const float* xb = x + ((size_t)((b*H_+h)*NODE_ + 1 + t*D_)*C_ + c0)*S_;
    if_group<4>(xb, Ash, 0, ti, to, w, bias, bt, ch0, Xh, Xl);
    if_group<3>(xb, Ash, 4, ti, to, w, bias, bt, ch0, Xh, Xl);
}

// ---------------- fused REV (d-shared, 2-group reg-acc) ----------------
template<int ND>
__device__ __forceinline__ void rev_group(const float* __restrict__ b0, const float* __restrict__ b1,
                                          const float* __restrict__ b2, const float* __restrict__ Ash,
                                          int d0, float (*ti)[S_], float (*to)[S_],
                                          const float* __restrict__ w, const float* __restrict__ bias,
                                          int bt, int ch0,
                                          u16* __restrict__ Xh, u16* __restrict__ Xl){
    int tid = threadIdx.x;
    f32x4 acc[ND][4];
    #pragma unroll
    for(int dd=0;dd<ND;dd++)
        #pragma unroll
        for(int q=0;q<4;q++) acc[dd][q]=(f32x4){0.f,0.f,0.f,0.f};
    const size_t pstr4 = (size_t)HC_*S4_;
    #pragma unroll
    for(int q=0;q<4;q++){
        int e4 = tid + q*256;
        bool ok = e4 < NE4_;
        #pragma unroll
        for(int j=0;j<KD_;j++){
            const int k = j/D_, dp = j - k*D_;
            const float* bk = (k==0) ? b0 : (k==1) ? b1 : b2;
            f32x4 v = ok ? *((const f32x4*)bk + dp*pstr4 + e4) : (f32x4){0.f,0.f,0.f,0.f};
            #pragma unroll
            for(int dd=0;dd<ND;dd++)
                acc[dd][q] += Ash[(d0+dd)*KD_+j]*v;
        }
    }
    float* tif = &ti[0][0];
    #pragma unroll
    for(int dd=0;dd<ND;dd++){
        __syncthreads();
        #pragma unroll
        for(int q=0;q<4;q++){
            int e4 = tid + q*256;
            if(e4 < NE4_) *(f32x4*)&tif[e4*4] = acc[dd][q];
        }
        __syncthreads();
        dw_split_tail(ti, to, w, bias, bt*D_+d0+dd, ch0, Xh, Xl);
    }
}

__launch_bounds__(256)
__global__ void k_fused_rev(const float* __restrict__ n2, const float* __restrict__ A,
                            const int* __restrict__ idx,
                            const float* __restrict__ w, const float* __restrict__ bias,
                            u16* __restrict__ Xh, u16* __restrict__ Xl){
    int bt  = blockIdx.x >> 5;
    int ch0 = (blockIdx.x & 31) * 16;
    int h = ch0 >> 7;
    int b = bt >> 3, t = bt & 7;
    __shared__ float Ash[D_*KD_];
    __shared__ int tts[3];
    __shared__ float ti[16][S_];
    __shared__ float to[16][S_];
    int tid = threadIdx.x;
    if(tid < D_*KD_) Ash[tid] = A[(size_t)((bt*4+h)*D_)*KD_ + tid];
    if(tid>=160 && tid<163)
        tts[tid-160] = idx[((size_t)(b*H_+h)*T_+t)*K_ + (tid-160)];
    __syncthreads();
    const float* b0 = n2 + ((size_t)((b*T_+tts[0])*D_)*HC_ + ch0)*S_;
    const float* b1 = n2 + ((size_t)((b*T_+tts[1])*D_)*HC_ + ch0)*S_;
    const float* b2 = n2 + ((size_t)((b*T_+tts[2])*D_)*HC_ + ch0)*S_;
    rev_group<4>(b0, b1, b2, Ash, 0, ti, to, w, bias, bt, ch0, Xh, Xl);
    rev_group<3>(b0, b1, b2, Ash, 4, ti, to, w, bias, bt, ch0, Xh, Xl);
}

// ---------------- weight prep: fp32 [oc][ic] -> bf16 Waug [oc][hi 512 | lo 512] ----------------
__global__ void k_prepW(const float* __restrict__ Wg, u16* __restrict__ Waug){
    int i = blockIdx.x*256 + threadIdx.x;   // < 512*512
    int oc = i >> 9, ic = i & 511;
    float f = Wg[i];
    u16 h = f2bf(f);
    float lo = f - bf2f(h);
    size_t base = (size_t)oc*WS_;
    Waug[base + ic]       = h;
    Waug[base + 512 + ic] = f2bf(lo);
}

// ---------------- MFMA pointwise GEMM (split-bf16, 24 K-tiles) ----------------
__launch_bounds__(512)
__global__ void k_pwmfma(const u16* __restrict__ Xh, const u16* __restrict__ Xl,
                         const u16* __restrict__ Waug, const float* __restrict__ bias,
                         const float* __restrict__ res, float* __restrict__ out,
                         int nwg, int utot){
    __shared__ u16 SM[2][16384];           // 2 x 32KB: [As 8192 u16 | Bs 8192 u16]
    const int tid  = threadIdx.x;
    const int q = nwg >> 3, r = nwg & 7;
    int xcd = blockIdx.x & 7, j = blockIdx.x >> 3;
    int L = xcd*q + (xcd < r ? xcd : r) + j;
    const int u0   = (L >> 2) * 128;
    const int oc0  = (L & 3) * 128;
    const int lane = tid & 63;
    const int w    = tid >> 6;             // 0..7
    const int wr   = w >> 1, wc = w & 1;   // 4 x 2 wave grid
    const int l15  = lane & 15, lg = lane >> 4;

    f32x4 acc[2][4];
    #pragma unroll
    for(int mi=0;mi<2;mi++)
        #pragma unroll
        for(int ni=0;ni<4;ni++)
            acc[mi][ni] = (f32x4){0.f,0.f,0.f,0.f};

    auto STAGE = [&](int t){               // 4 gld16 issues per wave (2A + 2B)
        int jj, wk, xk; const u16* Xp;
        if(t < 16){ jj = t>>1; wk = (t&1) ? 512 + jj*64 : jj*64; Xp = Xh; xk = jj*64; }
        else      { jj = t-16; wk = jj*64;                        Xp = Xl; xk = jj*64; }
        u16* Asb = SM[t&1];
        u16* Bsb = Asb + 8192;
        #pragma unroll
        for(int i=0;i<2;i++){
            int seg = w*2 + i;             // 0..15, 8 rows each
            int row = seg*8 + (lane>>3);
            int cg  = (lane&7) ^ (lane>>3);
            gld16(Waug + (size_t)(oc0+row)*WS_ + wk + cg*8, Asb + seg*512);
            gld16(Xp   + (size_t)(u0 +row)*512 + xk + cg*8, Bsb + seg*512);
        }
    };
    auto COMPUTE = [&](int cur){
        const u16* Asb = SM[cur];
        const u16* Bsb = SM[cur] + 8192;
        #pragma unroll
        for(int ks=0;ks<2;ks++){
            bf16x8 a[2], b[4];
            #pragma unroll
            for(int mi=0;mi<2;mi++){
                int row = wr*32 + mi*16 + l15;
                int ch  = ((ks<<2) + lg) ^ (row & 7);
                a[mi] = *(const bf16x8*)(Asb + row*64 + ch*8);
            }
            #pragma unroll
            for(int ni=0;ni<4;ni++){
                int row = wc*64 + ni*16 + l15;
                int ch  = ((ks<<2) + lg) ^ (row & 7);
                b[ni] = *(const bf16x8*)(Bsb + row*64 + ch*8);
            }
            #pragma unroll
            for(int mi=0;mi<2;mi++)
                #pragma unroll
                for(int ni=0;ni<4;ni++)
                    acc[mi][ni] = __builtin_amdgcn_mfma_f32_16x16x32_bf16(a[mi], b[ni], acc[mi][ni], 0,0,0);
        }
    };

    STAGE(0);
    for(int t=0; t<NT_; t++){
        if(t+1 < NT_){
            STAGE(t+1);                                      // 8 outstanding/wave
            asm volatile("s_waitcnt vmcnt(4)" ::: "memory"); // tile t landed
        } else {
            asm volatile("s_waitcnt vmcnt(0)" ::: "memory");
        }
        __builtin_amdgcn_s_barrier();      // all waves' tile-t loads in LDS
        asm volatile("" ::: "memory");
        COMPUTE(t&1);
        asm volatile("" ::: "memory");
        __builtin_amdgcn_s_barrier();      // buf[t&1] free for restage
    }

    #pragma unroll
    for(int ni=0;ni<4;ni++){
        int u = u0 + wc*64 + ni*16 + l15;
        if(u >= utot) continue;
        int img = u / S_, s = u - img*S_;
        #pragma unroll
        for(int mi=0;mi<2;mi++){
            int ocb = oc0 + wr*32 + mi*16 + lg*4;
            #pragma unroll
            for(int q2=0;q2<4;q2++){
                int oc = ocb + q2;
                size_t oidx = ((size_t)img*HC_ + oc)*S_ + s;
                float v = acc[mi][ni][q2] + bias[oc];
                if(res) v += res[oidx];
                out[oidx] = v;
            }
        }
    }
}

extern "C" void kernel_launch(void* const* d_in, const int* in_sizes, int n_in,
                              void* d_out, int out_size, void* d_ws, size_t ws_size,
                              hipStream_t stream){
    (void)in_sizes; (void)n_in; (void)out_size; (void)ws_size;
    const float* x         = (const float*)d_in[0];
    const float* alpha_if  = (const float*)d_in[1];
    const float* alpha_tm1 = (const float*)d_in[2];
    const float* alpha_rev = (const float*)d_in[3];
    const float* alpha_tm2 = (const float*)d_in[4];
    const float* bias_if   = (const float*)d_in[5];
    const float* bias_tm1  = (const float*)d_in[6];
    const float* bias_rev  = (const float*)d_in[7];
    const float* bias_tm2  = (const float*)d_in[8];
    const float* if_dw =(const float*)d_in[9];  const float* if_dwb =(const float*)d_in[10];
    const float* if_pw =(const float*)d_in[11]; const float* if_pwb =(const float*)d_in[12];
    const float* tm1_dw=(const float*)d_in[13]; const float* tm1_dwb=(const float*)d_in[14];
    const float* tm1_pw=(const float*)d_in[15]; const float* tm1_pwb=(const float*)d_in[16];
    const float* rev_dw=(const float*)d_in[17]; const float* rev_dwb=(const float*)d_in[18];
    const float* rev_pw=(const float*)d_in[19]; const float* rev_pwb=(const float*)d_in[20];
    const float* tm2_dw=(const float*)d_in[21]; const float* tm2_dwb=(const float*)d_in[22];
    const float* tm2_pw=(const float*)d_in[23]; const float* tm2_pwb=(const float*)d_in[24];
    const float* tr_dw =(const float*)d_in[25]; const float* tr_dwb =(const float*)d_in[26];
    const float* tr_pw =(const float*)d_in[27]; const float* tr_pwb =(const float*)d_in[28];

    float* ws = (float*)d_ws;
    float* G0      = ws;                          // BIG_ fp32
    float* G1      = G0 + (size_t)BIG_;           // BIG_ fp32
    u16*   Xh      = (u16*)(ws + 2*(size_t)BIG_); // BIG_ u16
    u16*   Xl      = Xh + (size_t)BIG_;           // BIG_ u16
    u16*   WA0     = Xl + (size_t)BIG_;           // 512*1024 u16 each
    u16*   WA1     = WA0 + 512*WS_;
    u16*   WA2     = WA1 + 512*WS_;
    u16*   WA3     = WA2 + 512*WS_;               // tm1
    u16*   WA4     = WA3 + 512*WS_;               // tm2
    u16*   XhM     = WA4 + 512*WS_;               // UMP_*512 u16 master X
    u16*   XlM     = XhM + (size_t)UMP_*HC_;
    float* master1 = (float*)(XlM + (size_t)UMP_*HC_);   // MS_
    float* Ma      = master1 + MS_;               // MS_
    float* pooledN = Ma + MS_;                    // 114688
    float* pooledM = pooledN + BT_*H_*D_*C_;      // 2048
    float* Aif     = pooledM + B_*H_*C_;          // 6272
    float* Atm1    = Aif + BT_*H_*D_*D_;          // 912
    float* Arev    = Atm1 + B_*H_*NODE_;          // 18816
    float* Atm2    = Arev + BT_*H_*D_*KD_;        // 912
    int*   idxb    = (int*)(Atm2 + B_*H_*NODE_);  // 384 ints
    float* out     = (float*)d_out;

    const int NV  = BT_*H_*D_*C_;     // pooled rows
    const int gemmGrid  = (UB_/128)*4;          // 1372
    const int gemmGridM = (UMP_/128)*4;         // 28
    const int dsGrid    = BT_*D_*32;  // 7168 (16-ch chunks)
    const int dsGridM   = B_*32;      // 128
    const int fusedGrid = BT_*32;     // 1024 (bt x 16-ch chunks, d-shared)
    float* null_res = nullptr;

    // weight prep (all five pw weights)
    k_prepW<<<1024, 256, 0, stream>>>(if_pw,  WA0);
    k_prepW<<<1024, 256, 0, stream>>>(tr_pw,  WA1);
    k_prepW<<<1024, 256, 0, stream>>>(rev_pw, WA2);
    k_prepW<<<1024, 256, 0, stream>>>(tm1_pw, WA3);
    k_prepW<<<1024, 256, 0, stream>>>(tm2_pw, WA4);

    // ---- stage 1: IF ----
    k_pool_x   <<<NV/4, 256, 0, stream>>>(x, pooledN);
    k_normalize<<<NV/C_, 128, 0, stream>>>(pooledN);
    k_A_if     <<<BT_*H_, 64, 0, stream>>>(pooledN, bias_if, alpha_if, Aif);
    k_fused_if <<<fusedGrid, 256, 0, stream>>>(x, Aif, if_dw, if_dwb, Xh, Xl);
    k_pwmfma   <<<gemmGrid, 512, 0, stream>>>(Xh, Xl, WA0, if_pwb, null_res, G1, gemmGrid, UB_);
    // G1 = normal1

    // ---- stage 2+3 (reordered): tr dwsplit+pool first, then masters, then tr GEMM ----
    k_dwsplit_pool<<<dsGrid, 256, 0, stream>>>(G1, tr_dw, tr_dwb, Xh, Xl, pooledN);
    k_normalize<<<NV/C_, 128, 0, stream>>>(pooledN);
    k_pool_x_master<<<(B_*H_*C_)/4, 256, 0, stream>>>(x, pooledM);
    k_normalize<<<B_*H_, 128, 0, stream>>>(pooledM);
    k_A_tm     <<<B_*H_, 64, 0, stream>>>(pooledM, pooledN, bias_tm1, alpha_tm1, Atm1);
    k_agg_tm   <<<MS_/1024, 256, 0, stream>>>(x, 1, G1, Atm1, Ma);
    k_dwsplit  <<<dsGridM, 256, 0, stream>>>(Ma, tm1_dw, tm1_dwb, XhM, XlM);
    k_pwmfma   <<<gemmGridM, 512, 0, stream>>>(XhM, XlM, WA3, tm1_pwb, null_res, master1, gemmGridM, UM_);
    k_pwmfma   <<<gemmGrid, 512, 0, stream>>>(Xh, Xl, WA1, tr_pwb, null_res, G0, gemmGrid, UB_);
    // G0 = normal2

    // ---- stage 4: rev ----
    k_pool_conv<<<NV/4, 256, 0, stream>>>(G0, pooledN);
    k_normalize<<<NV/C_, 128, 0, stream>>>(pooledN);
    k_topk     <<<B_*H_, 64, 0, stream>>>(pooledN, idxb);
    k_A_rev    <<<BT_*H_, 256, 0, stream>>>(pooledN, idxb, bias_rev, alpha_rev, Arev);
    k_fused_rev<<<fusedGrid, 256, 0, stream>>>(G0, Arev, idxb, rev_dw, rev_dwb, Xh, Xl);
    k_pwmfma   <<<gemmGrid, 512, 0, stream>>>(Xh, Xl, WA2, rev_pwb, G0, G1, gemmGrid, UB_);
    // G1 = normal3 (residual fused)

    // ---- stage 5: tm2 master -> output ----
    k_pool_conv<<<NV/4, 256, 0, stream>>>(G1, pooledN);
    k_normalize<<<NV/C_, 128, 0, stream>>>(pooledN);
    k_pool_m1  <<<(B_*H_*C_)/4, 256, 0, stream>>>(master1, pooledM);
    k_normalize<<<B_*H_, 128, 0, stream>>>(pooledM);
    k_A_tm     <<<B_*H_, 64, 0, stream>>>(pooledM, pooledN, bias_tm2, alpha_tm2, Atm2);
    k_agg_tm   <<<MS_/1024, 256, 0, stream>>>(master1, 0, G1, Atm2, Ma);
    k_dwsplit  <<<dsGridM, 256, 0, stream>>>(Ma, tm2_dw, tm2_dwb, XhM, XlM);
    k_pwmfma   <<<gemmGridM, 512, 0, stream>>>(XhM, XlM, WA4, tm2_pwb, null_res, out, gemmGridM, UM_);
}

// Round 13
// 1013.381 us; speedup vs baseline: 1.3712x; 1.3523x over previous
//
#include <hip/hip_runtime.h>
#include <hip/hip_bf16.h>
#include <float.h>
#include <math.h>

// Problem constants
#define B_    4
#define H_    4
#define T_    8
#define D_    7
#define C_    128
#define HH_   14
#define S_    196     // 14*14
#define S4_   49      // S_/4
#define BT_   32      // B*T
#define HC_   512     // H*C
#define NODE_ 57      // 1 + T*D
#define K_    3
#define KD_   21      // K*D

#define BIG_  (BT_*D_*HC_*S_)   // 22,478,848 elements per big buffer
#define MS_   (B_*HC_*S_)       // 401,408 floats (master-size)
#define UB_   (BT_*D_*S_)       // 43904 big-pw u count
#define UM_   (B_*S_)           // 784 master u count
#define UMP_  896               // master u padded to 7*128
#define NT_   24                // K-tiles (3 x 512 / 64)
#define WS_   1024              // Waug stride: [hi 512 | lo 512]
#define NE4_  784               // 16ch*196s in f32x4 units

typedef unsigned short u16;
typedef unsigned int   u32;
typedef short bf16x8 __attribute__((ext_vector_type(8)));
typedef float f32x4  __attribute__((ext_vector_type(4)));

__device__ __forceinline__ float wave_max(float v){
    #pragma unroll
    for(int o=32;o>0;o>>=1) v = fmaxf(v, __shfl_xor(v,o,64));
    return v;
}
__device__ __forceinline__ float wave_sum(float v){
    #pragma unroll
    for(int o=32;o>0;o>>=1) v += __shfl_xor(v,o,64);
    return v;
}
__device__ __forceinline__ u16 f2bf(float f){
    u32 u = __float_as_uint(f);
    u += 0x7FFF + ((u>>16)&1);
    return (u16)(u>>16);
}
__device__ __forceinline__ float bf2f(u16 h){ return __uint_as_float(((u32)h)<<16); }

// async global->LDS, 16B per lane; LDS dest = wave-uniform base + lane*16
__device__ __forceinline__ void gld16(const void* g, void* l){
    __builtin_amdgcn_global_load_lds(
        (__attribute__((address_space(1))) void*)(void*)g,
        (__attribute__((address_space(3))) void*)l, 16, 0, 0);
}

// ---------------- pooling (max over S_) ----------------
__global__ void k_pool_x(const float* __restrict__ x, float* __restrict__ out){
    int v = blockIdx.x*4 + (threadIdx.x>>6);
    int lane = threadIdx.x & 63;
    int c = v & (C_-1);
    int r = v >> 7;
    int d = r % D_; r /= D_;
    int h = r & (H_-1); r >>= 2;
    int bt = r;
    int b = bt >> 3, t = bt & 7;
    const float* row = x + ((size_t)((b*H_+h)*NODE_ + 1 + t*D_ + d)*C_ + c)*S_;
    float m = -FLT_MAX;
    for(int s=lane; s<S_; s+=64) m = fmaxf(m, row[s]);
    m = wave_max(m);
    if(lane==0) out[v] = m;
}

__global__ void k_pool_conv(const float* __restrict__ in, float* __restrict__ out){
    int v = blockIdx.x*4 + (threadIdx.x>>6);
    int lane = threadIdx.x & 63;
    int c = v & (C_-1);
    int r = v >> 7;
    int d = r % D_; r /= D_;
    int h = r & (H_-1); r >>= 2;
    int bt = r;
    const float* row = in + ((size_t)((bt*D_+d)*HC_ + h*C_ + c))*S_;
    float m = -FLT_MAX;
    for(int s=lane; s<S_; s+=64) m = fmaxf(m, row[s]);
    m = wave_max(m);
    if(lane==0) out[v] = m;
}

__global__ void k_pool_x_master(const float* __restrict__ x, float* __restrict__ out){
    int v = blockIdx.x*4 + (threadIdx.x>>6);
    int lane = threadIdx.x & 63;
    int c = v & (C_-1);
    int h = (v>>7) & (H_-1);
    int b = v >> 9;
    const float* row = x + ((size_t)((b*H_+h)*NODE_)*C_ + c)*S_;
    float m = -FLT_MAX;
    for(int s=lane; s<S_; s+=64) m = fmaxf(m, row[s]);
    m = wave_max(m);
    if(lane==0) out[v] = m;
}

__global__ void k_pool_m1(const float* __restrict__ in, float* __restrict__ out){
    int v = blockIdx.x*4 + (threadIdx.x>>6);
    int lane = threadIdx.x & 63;
    int c = v & (C_-1);
    int h = (v>>7) & (H_-1);
    int b = v >> 9;
    const float* row = in + ((size_t)(b*HC_ + h*C_ + c))*S_;
    float m = -FLT_MAX;
    for(int s=lane; s<S_; s+=64) m = fmaxf(m, row[s]);
    m = wave_max(m);
    if(lane==0) out[v] = m;
}

__global__ void k_normalize(float* __restrict__ v){
    int vec = blockIdx.x;
    float val = v[(size_t)vec*C_ + threadIdx.x];
    float ss = wave_sum(val*val);
    __shared__ float sh[2];
    if((threadIdx.x&63)==0) sh[threadIdx.x>>6] = ss;
    __syncthreads();
    float tot = sh[0]+sh[1];
    v[(size_t)vec*C_ + threadIdx.x] = val / fmaxf(sqrtf(tot), 1e-12f);
}

// ---------------- A matrices ----------------
__global__ void k_A_if(const float* __restrict__ vn, const float* __restrict__ bias,
                       const float* __restrict__ alpha_p, float* __restrict__ A){
    int bh = blockIdx.x;           // bt*H + h
    __shared__ float vs[D_*C_];
    __shared__ float z[D_][D_];
    for(int e=threadIdx.x; e<D_*C_; e+=64) vs[e] = vn[(size_t)bh*D_*C_ + e];
    __syncthreads();
    float alpha = alpha_p[0];
    if(threadIdx.x < D_*D_){
        int n = threadIdx.x/D_, m = threadIdx.x%D_;
        float acc=0.f;
        for(int c=0;c<C_;c++) acc += vs[n*C_+c]*vs[m*C_+c];
        z[n][m] = acc/alpha + bias[n*D_+m];
    }
    __syncthreads();
    if(threadIdx.x < D_){
        int n = threadIdx.x;
        float mx=-FLT_MAX;
        for(int m=0;m<D_;m++) mx=fmaxf(mx,z[n][m]);
        float e[D_]; float sum=0.f;
        for(int m=0;m<D_;m++){ e[m]=expf(z[n][m]-mx); sum+=e[m]; }
        for(int m=0;m<D_;m++) A[((size_t)bh*D_+n)*D_+m] = e[m]/sum;
    }
}

__global__ void k_A_tm(const float* __restrict__ vm, const float* __restrict__ vnrm,
                       const float* __restrict__ bias, const float* __restrict__ alpha_p,
                       float* __restrict__ A){
    int bh = blockIdx.x;           // b*H + h
    int b = bh>>2, h = bh&3;
    __shared__ float v0[C_];
    __shared__ float z[NODE_];
    for(int e=threadIdx.x;e<C_;e+=64) v0[e]=vm[(size_t)bh*C_+e];
    __syncthreads();
    float alpha=alpha_p[0];
    if(threadIdx.x<NODE_){
        int m=threadIdx.x;
        float acc=0.f;
        if(m==0){
            for(int c=0;c<C_;c++) acc+=v0[c]*v0[c];
        } else {
            int t=(m-1)/D_, d=(m-1)%D_;
            const float* vp = vnrm + (size_t)(((b*T_+t)*H_+h)*D_+d)*C_;
            for(int c=0;c<C_;c++) acc+=v0[c]*vp[c];
        }
        z[m]=acc/alpha + bias[m];
    }
    __syncthreads();
    if(threadIdx.x==0){
        float mx=-FLT_MAX;
        for(int m=0;m<NODE_;m++) mx=fmaxf(mx,z[m]);
        float sum=0.f;
        for(int m=0;m<NODE_;m++){ z[m]=expf(z[m]-mx); sum+=z[m]; }
        for(int m=0;m<NODE_;m++) A[(size_t)bh*NODE_+m]=z[m]/sum;
    }
}

__global__ void k_topk(const float* __restrict__ voHat, int* __restrict__ idx){
    int bh = blockIdx.x;           // b*H + h
    int b = bh>>2, h = bh&3;
    __shared__ float mv[T_][C_];
    __shared__ float As[T_][T_];
    for(int e=threadIdx.x;e<T_*C_;e+=64){
        int t=e>>7, c=e&(C_-1);
        mv[t][c]=voHat[(size_t)(((b*T_+t)*H_+h)*D_+(D_-1))*C_+c];
    }
    __syncthreads();
    {
        int t=threadIdx.x>>3, s2=threadIdx.x&7;
        float acc=0.f;
        for(int c=0;c<C_;c++) acc+=mv[t][c]*mv[s2][c];
        As[t][s2]=acc;
    }
    __syncthreads();
    if(threadIdx.x<T_){
        int t=threadIdx.x;
        bool used[T_];
        for(int j=0;j<T_;j++) used[j]=false;
        for(int k=0;k<K_;k++){
            float mn=FLT_MAX; int bi=0;
            for(int s2=0;s2<T_;s2++){
                if(!used[s2] && As[t][s2]<mn){ mn=As[t][s2]; bi=s2; }
            }
            used[bi]=true;
            idx[((size_t)bh*T_+t)*K_+k]=bi;
        }
    }
}

__global__ void k_A_rev(const float* __restrict__ voHat, const int* __restrict__ idx,
                        const float* __restrict__ bias, const float* __restrict__ alpha_p,
                        float* __restrict__ A){
    int bth = blockIdx.x;          // bt*H + h
    int bt = bth>>2, h = bth&3;
    int b = bt>>3, t = bt&7;
    __shared__ float vo[D_][C_];
    __shared__ float vd[KD_][C_];
    __shared__ float z[D_][KD_];
    for(int e=threadIdx.x;e<D_*C_;e+=256){
        int n=e>>7, c=e&(C_-1);
        vo[n][c]=voHat[(size_t)((bt*H_+h)*D_+n)*C_+c];
    }
    for(int e=threadIdx.x;e<KD_*C_;e+=256){
        int m=e>>7, c=e&(C_-1);
        int k=m/D_, dp=m%D_;
        int tt=idx[((size_t)(b*H_+h)*T_+t)*K_+k];
        vd[m][c]=voHat[(size_t)(((b*T_+tt)*H_+h)*D_+dp)*C_+c];
    }
    __syncthreads();
    float alpha=alpha_p[0];
    if(threadIdx.x<D_*KD_){
        int n=threadIdx.x/KD_, m=threadIdx.x%KD_;
        float acc=0.f;
        for(int c=0;c<C_;c++) acc+=vo[n][c]*vd[m][c];
        z[n][m] = -acc/alpha + bias[n*KD_+m];
    }
    __syncthreads();
    if(threadIdx.x<D_){
        int n=threadIdx.x;
        float mx=-FLT_MAX;
        for(int m=0;m<KD_;m++) mx=fmaxf(mx,z[n][m]);
        float sum=0.f;
        for(int m=0;m<KD_;m++){ z[n][m]=expf(z[n][m]-mx); sum+=z[n][m]; }
        for(int m=0;m<KD_;m++) A[(size_t)((bt*H_+h)*D_+n)*KD_+m]=z[n][m]/sum;
    }
}

// ---------------- master aggregation (float4-vectorized) ----------------
__global__ void k_agg_tm(const float* __restrict__ mastersrc, int master_is_x,
                         const float* __restrict__ normal, const float* __restrict__ A,
                         float* __restrict__ out){
    int v = blockIdx.x*256 + threadIdx.x;       // < MS_/4
    int s4 = v % S4_;
    int r  = v / S4_;
    int hc = r & (HC_-1);
    int b  = r >> 9;
    int h = hc >> 7, c = hc & (C_-1);
    const float* Ap = A + (size_t)(b*H_+h)*NODE_;
    f32x4 m0;
    if(master_is_x) m0 = *(const f32x4*)(mastersrc + ((size_t)((b*H_+h)*NODE_)*C_ + c)*S_ + s4*4);
    else            m0 = *(const f32x4*)(mastersrc + (size_t)(b*HC_+hc)*S_ + s4*4);
    f32x4 acc = Ap[0]*m0;
    for(int t=0;t<T_;t++){
        const float* np = normal + ((size_t)((b*T_+t)*D_)*HC_+hc)*S_ + s4*4;
        #pragma unroll
        for(int d=0;d<D_;d++)
            acc += Ap[1+t*D_+d] * *(const f32x4*)(np + (size_t)d*HC_*S_);
    }
    *(f32x4*)(out + (size_t)r*S_ + s4*4) = acc;
}

// -------- shared dw+split tail (16-channel tiles) --------
__device__ __forceinline__ void dw_split_tail(float (*ti)[S_], float (*to)[S_],
                                              const float* __restrict__ w,
                                              const float* __restrict__ bias,
                                              int img, int ch0,
                                              u16* __restrict__ Xh, u16* __restrict__ Xl){
    int tid = threadIdx.x;
    for(int e=tid; e<16*S_; e+=256){
        int chl = e/S_, s = e - (e/S_)*S_;
        int ch = ch0 + chl;
        int y = s/HH_, xx = s - (s/HH_)*HH_;
        float acc = bias[ch];
        #pragma unroll
        for(int ky=0;ky<3;ky++){
            int yy=y+ky-1;
            if(yy<0||yy>=HH_) continue;
            #pragma unroll
            for(int kx=0;kx<3;kx++){
                int xx2=xx+kx-1;
                if(xx2<0||xx2>=HH_) continue;
                acc += ti[chl][yy*HH_+xx2]*w[ch*9+ky*3+kx];
            }
        }
        to[chl][s]=acc;
    }
    __syncthreads();
    for(int e=tid; e<16*S_; e+=256){
        int s = e>>4, chl = e&15;
        float f = to[chl][s];
        u16 h = f2bf(f);
        float lo = f - bf2f(h);
        size_t o = ((size_t)img*S_ + s)*HC_ + ch0 + chl;
        Xh[o] = h;
        Xl[o] = f2bf(lo);
    }
}

// ---------------- plain depthwise+split (master path) ----------------
__launch_bounds__(256)
__global__ void k_dwsplit(const float* __restrict__ in, const float* __restrict__ w,
                          const float* __restrict__ bias,
                          u16* __restrict__ Xh, u16* __restrict__ Xl){
    int img = blockIdx.x >> 5;
    int ch0 = (blockIdx.x & 31) * 16;
    __shared__ float ti[16][S_];
    __shared__ float to[16][S_];
    int tid = threadIdx.x;
    for(int e=tid; e<16*S4_; e+=256){
        int chl = e/S4_, s4 = e - (e/S4_)*S4_;
        *(f32x4*)&ti[chl][s4*4] =
            *(const f32x4*)(in + ((size_t)img*HC_ + ch0 + chl)*S_ + s4*4);
    }
    __syncthreads();
    dw_split_tail(ti, to, w, bias, img, ch0, Xh, Xl);
}

// ---------------- dwsplit + fused max-pool of the INPUT (pre-dw) ----------------
__launch_bounds__(256)
__global__ void k_dwsplit_pool(const float* __restrict__ in, const float* __restrict__ w,
                               const float* __restrict__ bias,
                               u16* __restrict__ Xh, u16* __restrict__ Xl,
                               float* __restrict__ pooled){
    int img = blockIdx.x >> 5;
    int ch0 = (blockIdx.x & 31) * 16;
    __shared__ float ti[16][S_];
    __shared__ float to[16][S_];
    __shared__ float pm[16][17];
    int tid = threadIdx.x;
    for(int e=tid; e<16*S4_; e+=256){
        int chl = e/S4_, s4 = e - (e/S4_)*S4_;
        *(f32x4*)&ti[chl][s4*4] =
            *(const f32x4*)(in + ((size_t)img*HC_ + ch0 + chl)*S_ + s4*4);
    }
    __syncthreads();
    dw_split_tail(ti, to, w, bias, img, ch0, Xh, Xl);
    {
        int chl = tid & 15, g = tid >> 4;
        float m = -FLT_MAX;
        for(int s=g; s<S_; s+=16) m = fmaxf(m, ti[chl][s]);
        pm[chl][g] = m;
    }
    __syncthreads();
    if(tid < 16){
        float mm = -FLT_MAX;
        #pragma unroll
        for(int g2=0; g2<16; g2++) mm = fmaxf(mm, pm[tid][g2]);
        int bt = img/7, d = img - (img/7)*7;
        pooled[(size_t)((bt*4 + (ch0>>7))*7 + d)*C_ + (ch0 & 127) + tid] = mm;
    }
}

// ---------------- fused IF (d-paired, LDS accumulators) ----------------
// block = (bt, d-group, 16-ch chunk); computes d0 and (if nd==2) d0+1 in one
// pass over the 7 shared source planes. Register profile = round-9 (light).
__launch_bounds__(256)
__global__ void k_fused_if(const float* __restrict__ x, const float* __restrict__ A,
                           const float* __restrict__ w, const float* __restrict__ bias,
                           u16* __restrict__ Xh, u16* __restrict__ Xl){
    int blk = blockIdx.x;
    int ch0 = (blk & 31) * 16;
    int g   = (blk >> 5) & 3;
    int bt  = blk >> 7;
    int d0 = g*2, nd = (g==3) ? 1 : 2;
    int h = ch0 >> 7, c0 = ch0 & 127;
    int b = bt >> 3, t = bt & 7;
    __shared__ float Ash[2*D_];
    __shared__ float t0[16][S_];
    __shared__ float t1[16][S_];
    __shared__ float to[16][S_];
    int tid = threadIdx.x;
    if(tid < 2*D_)
        Ash[tid] = (tid < nd*D_) ? A[((size_t)((bt*4+h)*D_ + d0))*D_ + tid] : 0.f;
    __syncthreads();
    const float* xb = x + ((size_t)((b*H_+h)*NODE_ + 1 + t*D_)*C_ + c0)*S_;
    float* t0f = &t0[0][0];
    float* t1f = &t1[0][0];
    for(int e=tid; e<NE4_; e+=256){
        f32x4 a0 = {0.f,0.f,0.f,0.f}, a1 = {0.f,0.f,0.f,0.f};
        #pragma unroll
        for(int m=0;m<D_;m++){
            f32x4 v = *((const f32x4*)xb + (size_t)m*(C_*S4_) + e);
            a0 += Ash[m]*v;
            a1 += Ash[D_+m]*v;
        }
        *(f32x4*)&t0f[e*4] = a0;
        *(f32x4*)&t1f[e*4] = a1;
    }
    __syncthreads();
    dw_split_tail(t0, to, w, bias, bt*D_+d0, ch0, Xh, Xl);
    if(nd==2){
        __syncthreads();
        dw_split_tail(t1, to, w, bias, bt*D_+d0+1, ch0, Xh, Xl);
    }
}

// ---------------- fused REV (d-paired, LDS accumulators) ----------------
__launch_bounds__(256)
__global__ void k_fused_rev(const float* __restrict__ n2, const float* __restrict__ A,
                            const int* __restrict__ idx,
                            const float* __restrict__ w, const float* __restrict__ bias,
                            u16* __restrict__ Xh, u16* __restrict__ Xl){
    int blk = blockIdx.x;
    int ch0 = (blk & 31) * 16;
    int g   = (blk >> 5) & 3;
    int bt  = blk >> 7;
    int d0 = g*2, nd = (g==3) ? 1 : 2;
    int h = ch0 >> 7;
    int b = bt >> 3, t = bt & 7;
    __shared__ float Ash[2*KD_];
    __shared__ int tts[3];
    __shared__ float t0[16][S_];
    __shared__ float t1[16][S_];
    __shared__ float to[16][S_];
    int tid = threadIdx.x;
    if(tid < 2*KD_)
        Ash[tid] = (tid < nd*KD_) ? A[((size_t)((bt*4+h)*D_ + d0))*KD_ + tid] : 0.f;
    if(tid>=64 && tid<67)
        tts[tid-64] = idx[((size_t)(b*H_+h)*T_+t)*K_ + (tid-64)];
    __syncthreads();
    const float* b0 = n2 + ((size_t)((b*T_+tts[0])*D_)*HC_ + ch0)*S_;
    const float* b1 = n2 + ((size_t)((b*T_+tts[1])*D_)*HC_ + ch0)*S_;
    const float* b2 = n2 + ((size_t)((b*T_+tts[2])*D_)*HC_ + ch0)*S_;
    float* t0f = &t0[0][0];
    float* t1f = &t1[0][0];
    for(int e=tid; e<NE4_; e+=256){
        f32x4 a0 = {0.f,0.f,0.f,0.f}, a1 = {0.f,0.f,0.f,0.f};
        #pragma unroll
        for(int j=0;j<KD_;j++){
            const int k = j/D_, dp = j - (j/D_)*D_;
            const float* bk = (k==0) ? b0 : (k==1) ? b1 : b2;
            f32x4 v = *((const f32x4*)bk + (size_t)dp*(HC_*S4_) + e);
            a0 += Ash[j]*v;
            a1 += Ash[KD_+j]*v;
        }
        *(f32x4*)&t0f[e*4] = a0;
        *(f32x4*)&t1f[e*4] = a1;
    }
    __syncthreads();
    dw_split_tail(t0, to, w, bias, bt*D_+d0, ch0, Xh, Xl);
    if(nd==2){
        __syncthreads();
        dw_split_tail(t1, to, w, bias, bt*D_+d0+1, ch0, Xh, Xl);
    }
}

// ---------------- weight prep: fp32 [oc][ic] -> bf16 Waug [oc][hi 512 | lo 512] ----------------
__global__ void k_prepW(const float* __restrict__ Wg, u16* __restrict__ Waug){
    int i = blockIdx.x*256 + threadIdx.x;   // < 512*512
    int oc = i >> 9, ic = i & 511;
    float f = Wg[i];
    u16 h = f2bf(f);
    float lo = f - bf2f(h);
    size_t base = (size_t)oc*WS_;
    Waug[base + ic]       = h;
    Waug[base + 512 + ic] = f2bf(lo);
}

// ---------------- MFMA pointwise GEMM (split-bf16, 24 K-tiles) ----------------
__launch_bounds__(512)
__global__ void k_pwmfma(const u16* __restrict__ Xh, const u16* __restrict__ Xl,
                         const u16* __restrict__ Waug, const float* __restrict__ bias,
                         const float* __restrict__ res, float* __restrict__ out,
                         int nwg, int utot){
    __shared__ u16 SM[2][16384];           // 2 x 32KB: [As 8192 u16 | Bs 8192 u16]
    const int tid  = threadIdx.x;
    const int q = nwg >> 3, r = nwg & 7;
    int xcd = blockIdx.x & 7, j = blockIdx.x >> 3;
    int L = xcd*q + (xcd < r ? xcd : r) + j;
    const int u0   = (L >> 2) * 128;
    const int oc0  = (L & 3) * 128;
    const int lane = tid & 63;
    const int w    = tid >> 6;             // 0..7
    const int wr   = w >> 1, wc = w & 1;   // 4 x 2 wave grid
    const int l15  = lane & 15, lg = lane >> 4;

    f32x4 acc[2][4];
    #pragma unroll
    for(int mi=0;mi<2;mi++)
        #pragma unroll
        for(int ni=0;ni<4;ni++)
            acc[mi][ni] = (f32x4){0.f,0.f,0.f,0.f};

    auto STAGE = [&](int t){               // 4 gld16 issues per wave (2A + 2B)
        int jj, wk, xk; const u16* Xp;
        if(t < 16){ jj = t>>1; wk = (t&1) ? 512 + jj*64 : jj*64; Xp = Xh; xk = jj*64; }
        else      { jj = t-16; wk = jj*64;                        Xp = Xl; xk = jj*64; }
        u16* Asb = SM[t&1];
        u16* Bsb = Asb + 8192;
        #pragma unroll
        for(int i=0;i<2;i++){
            int seg = w*2 + i;             // 0..15, 8 rows each
            int row = seg*8 + (lane>>3);
            int cg  = (lane&7) ^ (lane>>3);
            gld16(Waug + (size_t)(oc0+row)*WS_ + wk + cg*8, Asb + seg*512);
            gld16(Xp   + (size_t)(u0 +row)*512 + xk + cg*8, Bsb + seg*512);
        }
    };
    auto COMPUTE = [&](int cur){
        const u16* Asb = SM[cur];
        const u16* Bsb = SM[cur] + 8192;
        #pragma unroll
        for(int ks=0;ks<2;ks++){
            bf16x8 a[2], b[4];
            #pragma unroll
            for(int mi=0;mi<2;mi++){
                int row = wr*32 + mi*16 + l15;
                int ch  = ((ks<<2) + lg) ^ (row & 7);
                a[mi] = *(const bf16x8*)(Asb + row*64 + ch*8);
            }
            #pragma unroll
            for(int ni=0;ni<4;ni++){
                int row = wc*64 + ni*16 + l15;
                int ch  = ((ks<<2) + lg) ^ (row & 7);
                b[ni] = *(const bf16x8*)(Bsb + row*64 + ch*8);
            }
            #pragma unroll
            for(int mi=0;mi<2;mi++)
                #pragma unroll
                for(int ni=0;ni<4;ni++)
                    acc[mi][ni] = __builtin_amdgcn_mfma_f32_16x16x32_bf16(a[mi], b[ni], acc[mi][ni], 0,0,0);
        }
    };

    STAGE(0);
    for(int t=0; t<NT_; t++){
        if(t+1 < NT_){
            STAGE(t+1);                                      // 8 outstanding/wave
            asm volatile("s_waitcnt vmcnt(4)" ::: "memory"); // tile t landed
        } else {
            asm volatile("s_waitcnt vmcnt(0)" ::: "memory");
        }
        __builtin_amdgcn_s_barrier();      // all waves' tile-t loads in LDS
        asm volatile("" ::: "memory");
        COMPUTE(t&1);
        asm volatile("" ::: "memory");
        __builtin_amdgcn_s_barrier();      // buf[t&1] free for restage
    }

    #pragma unroll
    for(int ni=0;ni<4;ni++){
        int u = u0 + wc*64 + ni*16 + l15;
        if(u >= utot) continue;
        int img = u / S_, s = u - img*S_;
        #pragma unroll
        for(int mi=0;mi<2;mi++){
            int ocb = oc0 + wr*32 + mi*16 + lg*4;
            #pragma unroll
            for(int q2=0;q2<4;q2++){
                int oc = ocb + q2;
                size_t oidx = ((size_t)img*HC_ + oc)*S_ + s;
                float v = acc[mi][ni][q2] + bias[oc];
                if(res) v += res[oidx];
                out[oidx] = v;
            }
        }
    }
}

extern "C" void kernel_launch(void* const* d_in, const int* in_sizes, int n_in,
                              void* d_out, int out_size, void* d_ws, size_t ws_size,
                              hipStream_t stream){
    (void)in_sizes; (void)n_in; (void)out_size; (void)ws_size;
    const float* x         = (const float*)d_in[0];
    const float* alpha_if  = (const float*)d_in[1];
    const float* alpha_tm1 = (const float*)d_in[2];
    const float* alpha_rev = (const float*)d_in[3];
    const float* alpha_tm2 = (const float*)d_in[4];
    const float* bias_if   = (const float*)d_in[5];
    const float* bias_tm1  = (const float*)d_in[6];
    const float* bias_rev  = (const float*)d_in[7];
    const float* bias_tm2  = (const float*)d_in[8];
    const float* if_dw =(const float*)d_in[9];  const float* if_dwb =(const float*)d_in[10];
    const float* if_pw =(const float*)d_in[11]; const float* if_pwb =(const float*)d_in[12];
    const float* tm1_dw=(const float*)d_in[13]; const float* tm1_dwb=(const float*)d_in[14];
    const float* tm1_pw=(const float*)d_in[15]; const float* tm1_pwb=(const float*)d_in[16];
    const float* rev_dw=(const float*)d_in[17]; const float* rev_dwb=(const float*)d_in[18];
    const float* rev_pw=(const float*)d_in[19]; const float* rev_pwb=(const float*)d_in[20];
    const float* tm2_dw=(const float*)d_in[21]; const float* tm2_dwb=(const float*)d_in[22];
    const float* tm2_pw=(const float*)d_in[23]; const float* tm2_pwb=(const float*)d_in[24];
    const float* tr_dw =(const float*)d_in[25]; const float* tr_dwb =(const float*)d_in[26];
    const float* tr_pw =(const float*)d_in[27]; const float* tr_pwb =(const float*)d_in[28];

    float* ws = (float*)d_ws;
    float* G0      = ws;                          // BIG_ fp32
    float* G1      = G0 + (size_t)BIG_;           // BIG_ fp32
    u16*   Xh      = (u16*)(ws + 2*(size_t)BIG_); // BIG_ u16
    u16*   Xl      = Xh + (size_t)BIG_;           // BIG_ u16
    u16*   WA0     = Xl + (size_t)BIG_;           // 512*1024 u16 each
    u16*   WA1     = WA0 + 512*WS_;
    u16*   WA2     = WA1 + 512*WS_;
    u16*   WA3     = WA2 + 512*WS_;               // tm1
    u16*   WA4     = WA3 + 512*WS_;               // tm2
    u16*   XhM     = WA4 + 512*WS_;               // UMP_*512 u16 master X
    u16*   XlM     = XhM + (size_t)UMP_*HC_;
    float* master1 = (float*)(XlM + (size_t)UMP_*HC_);   // MS_
    float* Ma      = master1 + MS_;               // MS_
    float* pooledN = Ma + MS_;                    // 114688
    float* pooledM = pooledN + BT_*H_*D_*C_;      // 2048
    float* Aif     = pooledM + B_*H_*C_;          // 6272
    float* Atm1    = Aif + BT_*H_*D_*D_;          // 912
    float* Arev    = Atm1 + B_*H_*NODE_;          // 18816
    float* Atm2    = Arev + BT_*H_*D_*KD_;        // 912
    int*   idxb    = (int*)(Atm2 + B_*H_*NODE_);  // 384 ints
    float* out     = (float*)d_out;

    const int NV  = BT_*H_*D_*C_;     // pooled rows
    const int gemmGrid  = (UB_/128)*4;          // 1372
    const int gemmGridM = (UMP_/128)*4;         // 28
    const int dsGrid    = BT_*D_*32;  // 7168 (16-ch chunks)
    const int dsGridM   = B_*32;      // 128
    const int fusedGrid = BT_*4*32;   // 4096 (bt x d-group x 16-ch chunk)
    float* null_res = nullptr;

    // weight prep (all five pw weights)
    k_prepW<<<1024, 256, 0, stream>>>(if_pw,  WA0);
    k_prepW<<<1024, 256, 0, stream>>>(tr_pw,  WA1);
    k_prepW<<<1024, 256, 0, stream>>>(rev_pw, WA2);
    k_prepW<<<1024, 256, 0, stream>>>(tm1_pw, WA3);
    k_prepW<<<1024, 256, 0, stream>>>(tm2_pw, WA4);

    // ---- stage 1: IF ----
    k_pool_x   <<<NV/4, 256, 0, stream>>>(x, pooledN);
    k_normalize<<<NV/C_, 128, 0, stream>>>(pooledN);
    k_A_if     <<<BT_*H_, 64, 0, stream>>>(pooledN, bias_if, alpha_if, Aif);
    k_fused_if <<<fusedGrid, 256, 0, stream>>>(x, Aif, if_dw, if_dwb, Xh, Xl);
    k_pwmfma   <<<gemmGrid, 512, 0, stream>>>(Xh, Xl, WA0, if_pwb, null_res, G1, gemmGrid, UB_);
    // G1 = normal1

    // ---- stage 2+3 (reordered): tr dwsplit+pool first, then masters, then tr GEMM ----
    k_dwsplit_pool<<<dsGrid, 256, 0, stream>>>(G1, tr_dw, tr_dwb, Xh, Xl, pooledN);
    k_normalize<<<NV/C_, 128, 0, stream>>>(pooledN);
    k_pool_x_master<<<(B_*H_*C_)/4, 256, 0, stream>>>(x, pooledM);
    k_normalize<<<B_*H_, 128, 0, stream>>>(pooledM);
    k_A_tm     <<<B_*H_, 64, 0, stream>>>(pooledM, pooledN, bias_tm1, alpha_tm1, Atm1);
    k_agg_tm   <<<MS_/1024, 256, 0, stream>>>(x, 1, G1, Atm1, Ma);
    k_dwsplit  <<<dsGridM, 256, 0, stream>>>(Ma, tm1_dw, tm1_dwb, XhM, XlM);
    k_pwmfma   <<<gemmGridM, 512, 0, stream>>>(XhM, XlM, WA3, tm1_pwb, null_res, master1, gemmGridM, UM_);
    k_pwmfma   <<<gemmGrid, 512, 0, stream>>>(Xh, Xl, WA1, tr_pwb, null_res, G0, gemmGrid, UB_);
    // G0 = normal2

    // ---- stage 4: rev ----
    k_pool_conv<<<NV/4, 256, 0, stream>>>(G0, pooledN);
    k_normalize<<<NV/C_, 128, 0, stream>>>(pooledN);
    k_topk     <<<B_*H_, 64, 0, stream>>>(pooledN, idxb);
    k_A_rev    <<<BT_*H_, 256, 0, stream>>>(pooledN, idxb, bias_rev, alpha_rev, Arev);
    k_fused_rev<<<fusedGrid, 256, 0, stream>>>(G0, Arev, idxb, rev_dw, rev_dwb, Xh, Xl);
    k_pwmfma   <<<gemmGrid, 512, 0, stream>>>(Xh, Xl, WA2, rev_pwb, G0, G1, gemmGrid, UB_);
    // G1 = normal3 (residual fused)

    // ---- stage 5: tm2 master -> output ----
    k_pool_conv<<<NV/4, 256, 0, stream>>>(G1, pooledN);
    k_normalize<<<NV/C_, 128, 0, stream>>>(pooledN);
    k_pool_m1  <<<(B_*H_*C_)/4, 256, 0, stream>>>(master1, pooledM);
    k_normalize<<<B_*H_, 128, 0, stream>>>(pooledM);
    k_A_tm     <<<B_*H_, 64, 0, stream>>>(pooledM, pooledN, bias_tm2, alpha_tm2, Atm2);
    k_agg_tm   <<<MS_/1024, 256, 0, stream>>>(master1, 0, G1, Atm2, Ma);
    k_dwsplit  <<<dsGridM, 256, 0, stream>>>(Ma, tm2_dw, tm2_dwb, XhM, XlM);
    k_pwmfma   <<<gemmGridM, 512, 0, stream>>>(XhM, XlM, WA4, tm2_pwb, null_res, out, gemmGridM, UM_);
}

// Round 14
// 978.087 us; speedup vs baseline: 1.4206x; 1.0361x over previous
//
#include <hip/hip_runtime.h>
#include <hip/hip_bf16.h>
#include <float.h>
#include <math.h>

// Problem constants
#define B_    4
#define H_    4
#define T_    8
#define D_    7
#define C_    128
#define HH_   14
#define S_    196     // 14*14
#define S4_   49      // S_/4
#define BT_   32      // B*T
#define HC_   512     // H*C
#define NODE_ 57      // 1 + T*D
#define K_    3
#define KD_   21      // K*D

#define BIG_  (BT_*D_*HC_*S_)   // 22,478,848 elements per big buffer
#define MS_   (B_*HC_*S_)       // 401,408 floats (master-size)
#define UB_   (BT_*D_*S_)       // 43904 big-pw u count
#define UM_   (B_*S_)           // 784 master u count
#define UMP_  896               // master u padded to 7*128
#define NT_   48                // K-tiles (3 x 512 / 32)
#define WS_   1024              // Waug stride: [hi 512 | lo 512]

typedef unsigned short u16;
typedef unsigned int   u32;
typedef short bf16x8 __attribute__((ext_vector_type(8)));
typedef float f32x4  __attribute__((ext_vector_type(4)));

__device__ __forceinline__ float wave_max(float v){
    #pragma unroll
    for(int o=32;o>0;o>>=1) v = fmaxf(v, __shfl_xor(v,o,64));
    return v;
}
__device__ __forceinline__ float wave_sum(float v){
    #pragma unroll
    for(int o=32;o>0;o>>=1) v += __shfl_xor(v,o,64);
    return v;
}
__device__ __forceinline__ u16 f2bf(float f){
    u32 u = __float_as_uint(f);
    u += 0x7FFF + ((u>>16)&1);
    return (u16)(u>>16);
}
__device__ __forceinline__ float bf2f(u16 h){ return __uint_as_float(((u32)h)<<16); }

// async global->LDS, 16B per lane; LDS dest = wave-uniform base + lane*16
__device__ __forceinline__ void gld16(const void* g, void* l){
    __builtin_amdgcn_global_load_lds(
        (__attribute__((address_space(1))) void*)(void*)g,
        (__attribute__((address_space(3))) void*)l, 16, 0, 0);
}

// ---------------- pooling (max over S_) ----------------
__global__ void k_pool_x(const float* __restrict__ x, float* __restrict__ out){
    int v = blockIdx.x*4 + (threadIdx.x>>6);
    int lane = threadIdx.x & 63;
    int c = v & (C_-1);
    int r = v >> 7;
    int d = r % D_; r /= D_;
    int h = r & (H_-1); r >>= 2;
    int bt = r;
    int b = bt >> 3, t = bt & 7;
    const float* row = x + ((size_t)((b*H_+h)*NODE_ + 1 + t*D_ + d)*C_ + c)*S_;
    float m = -FLT_MAX;
    for(int s=lane; s<S_; s+=64) m = fmaxf(m, row[s]);
    m = wave_max(m);
    if(lane==0) out[v] = m;
}

__global__ void k_pool_conv(const float* __restrict__ in, float* __restrict__ out){
    int v = blockIdx.x*4 + (threadIdx.x>>6);
    int lane = threadIdx.x & 63;
    int c = v & (C_-1);
    int r = v >> 7;
    int d = r % D_; r /= D_;
    int h = r & (H_-1); r >>= 2;
    int bt = r;
    const float* row = in + ((size_t)((bt*D_+d)*HC_ + h*C_ + c))*S_;
    float m = -FLT_MAX;
    for(int s=lane; s<S_; s+=64) m = fmaxf(m, row[s]);
    m = wave_max(m);
    if(lane==0) out[v] = m;
}

__global__ void k_pool_x_master(const float* __restrict__ x, float* __restrict__ out){
    int v = blockIdx.x*4 + (threadIdx.x>>6);
    int lane = threadIdx.x & 63;
    int c = v & (C_-1);
    int h = (v>>7) & (H_-1);
    int b = v >> 9;
    const float* row = x + ((size_t)((b*H_+h)*NODE_)*C_ + c)*S_;
    float m = -FLT_MAX;
    for(int s=lane; s<S_; s+=64) m = fmaxf(m, row[s]);
    m = wave_max(m);
    if(lane==0) out[v] = m;
}

__global__ void k_pool_m1(const float* __restrict__ in, float* __restrict__ out){
    int v = blockIdx.x*4 + (threadIdx.x>>6);
    int lane = threadIdx.x & 63;
    int c = v & (C_-1);
    int h = (v>>7) & (H_-1);
    int b = v >> 9;
    const float* row = in + ((size_t)(b*HC_ + h*C_ + c))*S_;
    float m = -FLT_MAX;
    for(int s=lane; s<S_; s+=64) m = fmaxf(m, row[s]);
    m = wave_max(m);
    if(lane==0) out[v] = m;
}

__global__ void k_normalize(float* __restrict__ v){
    int vec = blockIdx.x;
    float val = v[(size_t)vec*C_ + threadIdx.x];
    float ss = wave_sum(val*val);
    __shared__ float sh[2];
    if((threadIdx.x&63)==0) sh[threadIdx.x>>6] = ss;
    __syncthreads();
    float tot = sh[0]+sh[1];
    v[(size_t)vec*C_ + threadIdx.x] = val / fmaxf(sqrtf(tot), 1e-12f);
}

// ---------------- A matrices ----------------
__global__ void k_A_if(const float* __restrict__ vn, const float* __restrict__ bias,
                       const float* __restrict__ alpha_p, float* __restrict__ A){
    int bh = blockIdx.x;           // bt*H + h
    __shared__ float vs[D_*C_];
    __shared__ float z[D_][D_];
    for(int e=threadIdx.x; e<D_*C_; e+=64) vs[e] = vn[(size_t)bh*D_*C_ + e];
    __syncthreads();
    float alpha = alpha_p[0];
    if(threadIdx.x < D_*D_){
        int n = threadIdx.x/D_, m = threadIdx.x%D_;
        float acc=0.f;
        for(int c=0;c<C_;c++) acc += vs[n*C_+c]*vs[m*C_+c];
        z[n][m] = acc/alpha + bias[n*D_+m];
    }
    __syncthreads();
    if(threadIdx.x < D_){
        int n = threadIdx.x;
        float mx=-FLT_MAX;
        for(int m=0;m<D_;m++) mx=fmaxf(mx,z[n][m]);
        float e[D_]; float sum=0.f;
        for(int m=0;m<D_;m++){ e[m]=expf(z[n][m]-mx); sum+=e[m]; }
        for(int m=0;m<D_;m++) A[((size_t)bh*D_+n)*D_+m] = e[m]/sum;
    }
}

__global__ void k_A_tm(const float* __restrict__ vm, const float* __restrict__ vnrm,
                       const float* __restrict__ bias, const float* __restrict__ alpha_p,
                       float* __restrict__ A){
    int bh = blockIdx.x;           // b*H + h
    int b = bh>>2, h = bh&3;
    __shared__ float v0[C_];
    __shared__ float z[NODE_];
    for(int e=threadIdx.x;e<C_;e+=64) v0[e]=vm[(size_t)bh*C_+e];
    __syncthreads();
    float alpha=alpha_p[0];
    if(threadIdx.x<NODE_){
        int m=threadIdx.x;
        float acc=0.f;
        if(m==0){
            for(int c=0;c<C_;c++) acc+=v0[c]*v0[c];
        } else {
            int t=(m-1)/D_, d=(m-1)%D_;
            const float* vp = vnrm + (size_t)(((b*T_+t)*H_+h)*D_+d)*C_;
            for(int c=0;c<C_;c++) acc+=v0[c]*vp[c];
        }
        z[m]=acc/alpha + bias[m];
    }
    __syncthreads();
    if(threadIdx.x==0){
        float mx=-FLT_MAX;
        for(int m=0;m<NODE_;m++) mx=fmaxf(mx,z[m]);
        float sum=0.f;
        for(int m=0;m<NODE_;m++){ z[m]=expf(z[m]-mx); sum+=z[m]; }
        for(int m=0;m<NODE_;m++) A[(size_t)bh*NODE_+m]=z[m]/sum;
    }
}

__global__ void k_topk(const float* __restrict__ voHat, int* __restrict__ idx){
    int bh = blockIdx.x;           // b*H + h
    int b = bh>>2, h = bh&3;
    __shared__ float mv[T_][C_];
    __shared__ float As[T_][T_];
    for(int e=threadIdx.x;e<T_*C_;e+=64){
        int t=e>>7, c=e&(C_-1);
        mv[t][c]=voHat[(size_t)(((b*T_+t)*H_+h)*D_+(D_-1))*C_+c];
    }
    __syncthreads();
    {
        int t=threadIdx.x>>3, s2=threadIdx.x&7;
        float acc=0.f;
        for(int c=0;c<C_;c++) acc+=mv[t][c]*mv[s2][c];
        As[t][s2]=acc;
    }
    __syncthreads();
    if(threadIdx.x<T_){
        int t=threadIdx.x;
        bool used[T_];
        for(int j=0;j<T_;j++) used[j]=false;
        for(int k=0;k<K_;k++){
            float mn=FLT_MAX; int bi=0;
            for(int s2=0;s2<T_;s2++){
                if(!used[s2] && As[t][s2]<mn){ mn=As[t][s2]; bi=s2; }
            }
            used[bi]=true;
            idx[((size_t)bh*T_+t)*K_+k]=bi;
        }
    }
}

__global__ void k_A_rev(const float* __restrict__ voHat, const int* __restrict__ idx,
                        const float* __restrict__ bias, const float* __restrict__ alpha_p,
                        float* __restrict__ A){
    int bth = blockIdx.x;          // bt*H + h
    int bt = bth>>2, h = bth&3;
    int b = bt>>3, t = bt&7;
    __shared__ float vo[D_][C_];
    __shared__ float vd[KD_][C_];
    __shared__ float z[D_][KD_];
    for(int e=threadIdx.x;e<D_*C_;e+=256){
        int n=e>>7, c=e&(C_-1);
        vo[n][c]=voHat[(size_t)((bt*H_+h)*D_+n)*C_+c];
    }
    for(int e=threadIdx.x;e<KD_*C_;e+=256){
        int m=e>>7, c=e&(C_-1);
        int k=m/D_, dp=m%D_;
        int tt=idx[((size_t)(b*H_+h)*T_+t)*K_+k];
        vd[m][c]=voHat[(size_t)(((b*T_+tt)*H_+h)*D_+dp)*C_+c];
    }
    __syncthreads();
    float alpha=alpha_p[0];
    if(threadIdx.x<D_*KD_){
        int n=threadIdx.x/KD_, m=threadIdx.x%KD_;
        float acc=0.f;
        for(int c=0;c<C_;c++) acc+=vo[n][c]*vd[m][c];
        z[n][m] = -acc/alpha + bias[n*KD_+m];
    }
    __syncthreads();
    if(threadIdx.x<D_){
        int n=threadIdx.x;
        float mx=-FLT_MAX;
        for(int m=0;m<KD_;m++) mx=fmaxf(mx,z[n][m]);
        float sum=0.f;
        for(int m=0;m<KD_;m++){ z[n][m]=expf(z[n][m]-mx); sum+=z[n][m]; }
        for(int m=0;m<KD_;m++) A[(size_t)((bt*H_+h)*D_+n)*KD_+m]=z[n][m]/sum;
    }
}

// ---------------- master aggregation (float4-vectorized) ----------------
__global__ void k_agg_tm(const float* __restrict__ mastersrc, int master_is_x,
                         const float* __restrict__ normal, const float* __restrict__ A,
                         float* __restrict__ out){
    int v = blockIdx.x*256 + threadIdx.x;       // < MS_/4
    int s4 = v % S4_;
    int r  = v / S4_;
    int hc = r & (HC_-1);
    int b  = r >> 9;
    int h = hc >> 7, c = hc & (C_-1);
    const float* Ap = A + (size_t)(b*H_+h)*NODE_;
    f32x4 m0;
    if(master_is_x) m0 = *(const f32x4*)(mastersrc + ((size_t)((b*H_+h)*NODE_)*C_ + c)*S_ + s4*4);
    else            m0 = *(const f32x4*)(mastersrc + (size_t)(b*HC_+hc)*S_ + s4*4);
    f32x4 acc = Ap[0]*m0;
    for(int t=0;t<T_;t++){
        const float* np = normal + ((size_t)((b*T_+t)*D_)*HC_+hc)*S_ + s4*4;
        #pragma unroll
        for(int d=0;d<D_;d++)
            acc += Ap[1+t*D_+d] * *(const f32x4*)(np + (size_t)d*HC_*S_);
    }
    *(f32x4*)(out + (size_t)r*S_ + s4*4) = acc;
}

// -------- shared dw+split tail (16-channel tiles) --------
__device__ __forceinline__ void dw_split_tail(float (*ti)[S_], float (*to)[S_],
                                              const float* __restrict__ w,
                                              const float* __restrict__ bias,
                                              int img, int ch0,
                                              u16* __restrict__ Xh, u16* __restrict__ Xl){
    int tid = threadIdx.x;
    for(int e=tid; e<16*S_; e+=256){
        int chl = e/S_, s = e - (e/S_)*S_;
        int ch = ch0 + chl;
        int y = s/HH_, xx = s - (s/HH_)*HH_;
        float acc = bias[ch];
        #pragma unroll
        for(int ky=0;ky<3;ky++){
            int yy=y+ky-1;
            if(yy<0||yy>=HH_) continue;
            #pragma unroll
            for(int kx=0;kx<3;kx++){
                int xx2=xx+kx-1;
                if(xx2<0||xx2>=HH_) continue;
                acc += ti[chl][yy*HH_+xx2]*w[ch*9+ky*3+kx];
            }
        }
        to[chl][s]=acc;
    }
    __syncthreads();
    for(int e=tid; e<16*S_; e+=256){
        int s = e>>4, chl = e&15;
        float f = to[chl][s];
        u16 h = f2bf(f);
        float lo = f - bf2f(h);
        size_t o = ((size_t)img*S_ + s)*HC_ + ch0 + chl;
        Xh[o] = h;
        Xl[o] = f2bf(lo);
    }
}

// ---------------- plain depthwise+split (master path) ----------------
__launch_bounds__(256)
__global__ void k_dwsplit(const float* __restrict__ in, const float* __restrict__ w,
                          const float* __restrict__ bias,
                          u16* __restrict__ Xh, u16* __restrict__ Xl){
    int img = blockIdx.x >> 5;
    int ch0 = (blockIdx.x & 31) * 16;
    __shared__ float ti[16][S_];
    __shared__ float to[16][S_];
    int tid = threadIdx.x;
    for(int e=tid; e<16*S4_; e+=256){
        int chl = e/S4_, s4 = e - (e/S4_)*S4_;
        *(f32x4*)&ti[chl][s4*4] =
            *(const f32x4*)(in + ((size_t)img*HC_ + ch0 + chl)*S_ + s4*4);
    }
    __syncthreads();
    dw_split_tail(ti, to, w, bias, img, ch0, Xh, Xl);
}

// ---------------- dwsplit + fused max-pool of the INPUT (pre-dw) ----------------
__launch_bounds__(256)
__global__ void k_dwsplit_pool(const float* __restrict__ in, const float* __restrict__ w,
                               const float* __restrict__ bias,
                               u16* __restrict__ Xh, u16* __restrict__ Xl,
                               float* __restrict__ pooled){
    int img = blockIdx.x >> 5;
    int ch0 = (blockIdx.x & 31) * 16;
    __shared__ float ti[16][S_];
    __shared__ float to[16][S_];
    __shared__ float pm[16][17];
    int tid = threadIdx.x;
    for(int e=tid; e<16*S4_; e+=256){
        int chl = e/S4_, s4 = e - (e/S4_)*S4_;
        *(f32x4*)&ti[chl][s4*4] =
            *(const f32x4*)(in + ((size_t)img*HC_ + ch0 + chl)*S_ + s4*4);
    }
    __syncthreads();
    dw_split_tail(ti, to, w, bias, img, ch0, Xh, Xl);
    {
        int chl = tid & 15, g = tid >> 4;
        float m = -FLT_MAX;
        for(int s=g; s<S_; s+=16) m = fmaxf(m, ti[chl][s]);
        pm[chl][g] = m;
    }
    __syncthreads();
    if(tid < 16){
        float mm = -FLT_MAX;
        #pragma unroll
        for(int g2=0; g2<16; g2++) mm = fmaxf(mm, pm[tid][g2]);
        int bt = img/7, d = img - (img/7)*7;
        pooled[(size_t)((bt*4 + (ch0>>7))*7 + d)*C_ + (ch0 & 127) + tid] = mm;
    }
}

// ---------------- fused IF: agg(7-term, float4) + dw + split (round-9 form) ----------------
__launch_bounds__(256)
__global__ void k_fused_if(const float* __restrict__ x, const float* __restrict__ A,
                           const float* __restrict__ w, const float* __restrict__ bias,
                           u16* __restrict__ Xh, u16* __restrict__ Xl){
    int img = blockIdx.x >> 5;          // bt*7 + d
    int ch0 = (blockIdx.x & 31) * 16;
    int bt = img/7, d = img - bt*7;
    int b = bt >> 3, t = bt & 7;
    int h = ch0 >> 7, c0 = ch0 & 127;
    __shared__ float ti[16][S_];
    __shared__ float to[16][S_];
    float a[D_];
    #pragma unroll
    for(int m=0;m<D_;m++) a[m] = A[(size_t)((bt*4+h)*D_ + d)*D_ + m];
    int tid = threadIdx.x;
    const float* xb = x + ((size_t)((b*H_+h)*NODE_ + 1 + t*D_)*C_ + c0)*S_;
    for(int e=tid; e<16*S4_; e+=256){
        int chl = e/S4_, s4 = e - (e/S4_)*S4_;
        const f32x4* xp = (const f32x4*)(xb + (size_t)chl*S_) + s4;
        f32x4 acc = {0.f,0.f,0.f,0.f};
        #pragma unroll
        for(int m=0;m<D_;m++) acc += a[m]*xp[(size_t)m*C_*S4_];
        *(f32x4*)&ti[chl][s4*4] = acc;
    }
    __syncthreads();
    dw_split_tail(ti, to, w, bias, img, ch0, Xh, Xl);
}

// ---------------- fused REV: gather-agg(21-term, float4) + dw + split (round-9 form) ----------------
__launch_bounds__(256)
__global__ void k_fused_rev(const float* __restrict__ n2, const float* __restrict__ A,
                            const int* __restrict__ idx,
                            const float* __restrict__ w, const float* __restrict__ bias,
                            u16* __restrict__ Xh, u16* __restrict__ Xl){
    int img = blockIdx.x >> 5;          // bt*7 + d
    int ch0 = (blockIdx.x & 31) * 16;
    int bt = img/7, d = img - bt*7;
    int b = bt >> 3, t = bt & 7;
    int h = ch0 >> 7;
    __shared__ float ti[16][S_];
    __shared__ float to[16][S_];
    float a[KD_];
    #pragma unroll
    for(int j=0;j<KD_;j++) a[j] = A[(size_t)((bt*4+h)*D_ + d)*KD_ + j];
    int tt0 = idx[((size_t)(b*H_+h)*T_+t)*K_+0];
    int tt1 = idx[((size_t)(b*H_+h)*T_+t)*K_+1];
    int tt2 = idx[((size_t)(b*H_+h)*T_+t)*K_+2];
    const f32x4* p0 = (const f32x4*)(n2 + ((size_t)((b*T_+tt0)*D_)*HC_ + ch0)*S_);
    const f32x4* p1 = (const f32x4*)(n2 + ((size_t)((b*T_+tt1)*D_)*HC_ + ch0)*S_);
    const f32x4* p2 = (const f32x4*)(n2 + ((size_t)((b*T_+tt2)*D_)*HC_ + ch0)*S_);
    int tid = threadIdx.x;
    for(int e=tid; e<16*S4_; e+=256){
        int chl = e/S4_, s4 = e - (e/S4_)*S4_;
        size_t off = (size_t)chl*S4_ + s4;
        f32x4 acc = {0.f,0.f,0.f,0.f};
        #pragma unroll
        for(int dp=0;dp<D_;dp++){
            size_t o2 = off + (size_t)dp*HC_*S4_;
            acc += a[dp]      * p0[o2];
            acc += a[D_+dp]   * p1[o2];
            acc += a[2*D_+dp] * p2[o2];
        }
        *(f32x4*)&ti[chl][s4*4] = acc;
    }
    __syncthreads();
    dw_split_tail(ti, to, w, bias, img, ch0, Xh, Xl);
}

// ---------------- weight prep: fp32 [oc][ic] -> bf16 Waug [oc][hi 512 | lo 512] ----------------
__global__ void k_prepW(const float* __restrict__ Wg, u16* __restrict__ Waug){
    int i = blockIdx.x*256 + threadIdx.x;   // < 512*512
    int oc = i >> 9, ic = i & 511;
    float f = Wg[i];
    u16 h = f2bf(f);
    float lo = f - bf2f(h);
    size_t base = (size_t)oc*WS_;
    Waug[base + ic]       = h;
    Waug[base + 512 + ic] = f2bf(lo);
}

// ---------------- MFMA pointwise GEMM (split-bf16, BK=32, 48 K-tiles) ----------------
// Tile order: t=2j -> Whi[j*32]*Xh[j*32], t=2j+1 -> Wlo*Xh (same X chunk, L2-hot),
// j=0..15; t=32+j -> Whi*Xl. 128oc x 128u, 8 waves, ring-2 2x16KB = 32KB LDS
// -> 4 blocks/CU. global_load_lds(16B) x2/thread/tile, counted vmcnt(2).
__launch_bounds__(512)
__global__ void k_pwmfma(const u16* __restrict__ Xh, const u16* __restrict__ Xl,
                         const u16* __restrict__ Waug, const float* __restrict__ bias,
                         const float* __restrict__ res, float* __restrict__ out,
                         int nwg, int utot){
    __shared__ u16 SM[2][8192];            // per buf: A 4096 u16 (8KB) | B 4096 u16
    const int tid  = threadIdx.x;
    const int q = nwg >> 3, r = nwg & 7;
    int xcd = blockIdx.x & 7, j = blockIdx.x >> 3;
    int L = xcd*q + (xcd < r ? xcd : r) + j;
    const int u0   = (L >> 2) * 128;
    const int oc0  = (L & 3) * 128;
    const int lane = tid & 63;
    const int w    = tid >> 6;             // 0..7
    const int wr   = w >> 1, wc = w & 1;   // 4 x 2 wave grid
    const int l15  = lane & 15, lg = lane >> 4;

    // staging geometry: row stride 32 u16 (64B), 4 lanes/row, wave stages 16 rows
    const int srow = w*16 + (lane>>2);     // 0..127
    const int scg  = (lane&3) ^ ((lane>>2)&3);  // inverse-swizzled source chunk

    f32x4 acc[2][4];
    #pragma unroll
    for(int mi=0;mi<2;mi++)
        #pragma unroll
        for(int ni=0;ni<4;ni++)
            acc[mi][ni] = (f32x4){0.f,0.f,0.f,0.f};

    auto STAGE = [&](int t){               // 2 gld16 issues per thread (1A + 1B)
        int jj, wk, xk; const u16* Xp;
        if(t < 32){ jj = t>>1; wk = (t&1) ? 512 + jj*32 : jj*32; Xp = Xh; xk = jj*32; }
        else      { jj = t-32; wk = jj*32;                        Xp = Xl; xk = jj*32; }
        u16* Asb = SM[t&1];
        u16* Bsb = Asb + 4096;
        gld16(Waug + (size_t)(oc0+srow)*WS_ + wk + scg*8, Asb + w*512);
        gld16(Xp   + (size_t)(u0 +srow)*512 + xk + scg*8, Bsb + w*512);
    };
    auto COMPUTE = [&](int cur){
        const u16* Asb = SM[cur];
        const u16* Bsb = SM[cur] + 4096;
        bf16x8 a[2], b[4];
        #pragma unroll
        for(int mi=0;mi<2;mi++){
            int row = wr*32 + mi*16 + l15;
            int ch  = lg ^ (row & 3);
            a[mi] = *(const bf16x8*)(Asb + row*32 + ch*8);
        }
        #pragma unroll
        for(int ni=0;ni<4;ni++){
            int row = wc*64 + ni*16 + l15;
            int ch  = lg ^ (row & 3);
            b[ni] = *(const bf16x8*)(Bsb + row*32 + ch*8);
        }
        #pragma unroll
        for(int mi=0;mi<2;mi++)
            #pragma unroll
            for(int ni=0;ni<4;ni++)
                acc[mi][ni] = __builtin_amdgcn_mfma_f32_16x16x32_bf16(a[mi], b[ni], acc[mi][ni], 0,0,0);
    };

    STAGE(0);
    for(int t=0; t<NT_; t++){
        if(t+1 < NT_){
            STAGE(t+1);                                      // 4 outstanding/thread
            asm volatile("s_waitcnt vmcnt(2)" ::: "memory"); // tile t landed
        } else {
            asm volatile("s_waitcnt vmcnt(0)" ::: "memory");
        }
        __builtin_amdgcn_s_barrier();      // all waves' tile-t loads in LDS
        asm volatile("" ::: "memory");
        COMPUTE(t&1);
        asm volatile("" ::: "memory");
        __builtin_amdgcn_s_barrier();      // buf[t&1] free for restage
    }

    #pragma unroll
    for(int ni=0;ni<4;ni++){
        int u = u0 + wc*64 + ni*16 + l15;
        if(u >= utot) continue;
        int img = u / S_, s = u - img*S_;
        #pragma unroll
        for(int mi=0;mi<2;mi++){
            int ocb = oc0 + wr*32 + mi*16 + lg*4;
            #pragma unroll
            for(int q2=0;q2<4;q2++){
                int oc = ocb + q2;
                size_t oidx = ((size_t)img*HC_ + oc)*S_ + s;
                float v = acc[mi][ni][q2] + bias[oc];
                if(res) v += res[oidx];
                out[oidx] = v;
            }
        }
    }
}

extern "C" void kernel_launch(void* const* d_in, const int* in_sizes, int n_in,
                              void* d_out, int out_size, void* d_ws, size_t ws_size,
                              hipStream_t stream){
    (void)in_sizes; (void)n_in; (void)out_size; (void)ws_size;
    const float* x         = (const float*)d_in[0];
    const float* alpha_if  = (const float*)d_in[1];
    const float* alpha_tm1 = (const float*)d_in[2];
    const float* alpha_rev = (const float*)d_in[3];
    const float* alpha_tm2 = (const float*)d_in[4];
    const float* bias_if   = (const float*)d_in[5];
    const float* bias_tm1  = (const float*)d_in[6];
    const float* bias_rev  = (const float*)d_in[7];
    const float* bias_tm2  = (const float*)d_in[8];
    const float* if_dw =(const float*)d_in[9];  const float* if_dwb =(const float*)d_in[10];
    const float* if_pw =(const float*)d_in[11]; const float* if_pwb =(const float*)d_in[12];
    const float* tm1_dw=(const float*)d_in[13]; const float* tm1_dwb=(const float*)d_in[14];
    const float* tm1_pw=(const float*)d_in[15]; const float* tm1_pwb=(const float*)d_in[16];
    const float* rev_dw=(const float*)d_in[17]; const float* rev_dwb=(const float*)d_in[18];
    const float* rev_pw=(const float*)d_in[19]; const float* rev_pwb=(const float*)d_in[20];
    const float* tm2_dw=(const float*)d_in[21]; const float* tm2_dwb=(const float*)d_in[22];
    const float* tm2_pw=(const float*)d_in[23]; const float* tm2_pwb=(const float*)d_in[24];
    const float* tr_dw =(const float*)d_in[25]; const float* tr_dwb =(const float*)d_in[26];
    const float* tr_pw =(const float*)d_in[27]; const float* tr_pwb =(const float*)d_in[28];

    float* ws = (float*)d_ws;
    float* G0      = ws;                          // BIG_ fp32
    float* G1      = G0 + (size_t)BIG_;           // BIG_ fp32
    u16*   Xh      = (u16*)(ws + 2*(size_t)BIG_); // BIG_ u16
    u16*   Xl      = Xh + (size_t)BIG_;           // BIG_ u16
    u16*   WA0     = Xl + (size_t)BIG_;           // 512*1024 u16 each
    u16*   WA1     = WA0 + 512*WS_;
    u16*   WA2     = WA1 + 512*WS_;
    u16*   WA3     = WA2 + 512*WS_;               // tm1
    u16*   WA4     = WA3 + 512*WS_;               // tm2
    u16*   XhM     = WA4 + 512*WS_;               // UMP_*512 u16 master X
    u16*   XlM     = XhM + (size_t)UMP_*HC_;
    float* master1 = (float*)(XlM + (size_t)UMP_*HC_);   // MS_
    float* Ma      = master1 + MS_;               // MS_
    float* pooledN = Ma + MS_;                    // 114688
    float* pooledM = pooledN + BT_*H_*D_*C_;      // 2048
    float* Aif     = pooledM + B_*H_*C_;          // 6272
    float* Atm1    = Aif + BT_*H_*D_*D_;          // 912
    float* Arev    = Atm1 + B_*H_*NODE_;          // 18816
    float* Atm2    = Arev + BT_*H_*D_*KD_;        // 912
    int*   idxb    = (int*)(Atm2 + B_*H_*NODE_);  // 384 ints
    float* out     = (float*)d_out;

    const int NV  = BT_*H_*D_*C_;     // pooled rows
    const int gemmGrid  = (UB_/128)*4;          // 1372
    const int gemmGridM = (UMP_/128)*4;         // 28
    const int dsGrid    = BT_*D_*32;  // 7168 (16-ch chunks)
    const int dsGridM   = B_*32;      // 128
    float* null_res = nullptr;

    // weight prep (all five pw weights)
    k_prepW<<<1024, 256, 0, stream>>>(if_pw,  WA0);
    k_prepW<<<1024, 256, 0, stream>>>(tr_pw,  WA1);
    k_prepW<<<1024, 256, 0, stream>>>(rev_pw, WA2);
    k_prepW<<<1024, 256, 0, stream>>>(tm1_pw, WA3);
    k_prepW<<<1024, 256, 0, stream>>>(tm2_pw, WA4);

    // ---- stage 1: IF ----
    k_pool_x   <<<NV/4, 256, 0, stream>>>(x, pooledN);
    k_normalize<<<NV/C_, 128, 0, stream>>>(pooledN);
    k_A_if     <<<BT_*H_, 64, 0, stream>>>(pooledN, bias_if, alpha_if, Aif);
    k_fused_if <<<dsGrid, 256, 0, stream>>>(x, Aif, if_dw, if_dwb, Xh, Xl);
    k_pwmfma   <<<gemmGrid, 512, 0, stream>>>(Xh, Xl, WA0, if_pwb, null_res, G1, gemmGrid, UB_);
    // G1 = normal1

    // ---- stage 2+3 (reordered): tr dwsplit+pool first, then masters, then tr GEMM ----
    k_dwsplit_pool<<<dsGrid, 256, 0, stream>>>(G1, tr_dw, tr_dwb, Xh, Xl, pooledN);
    k_normalize<<<NV/C_, 128, 0, stream>>>(pooledN);
    k_pool_x_master<<<(B_*H_*C_)/4, 256, 0, stream>>>(x, pooledM);
    k_normalize<<<B_*H_, 128, 0, stream>>>(pooledM);
    k_A_tm     <<<B_*H_, 64, 0, stream>>>(pooledM, pooledN, bias_tm1, alpha_tm1, Atm1);
    k_agg_tm   <<<MS_/1024, 256, 0, stream>>>(x, 1, G1, Atm1, Ma);
    k_dwsplit  <<<dsGridM, 256, 0, stream>>>(Ma, tm1_dw, tm1_dwb, XhM, XlM);
    k_pwmfma   <<<gemmGridM, 512, 0, stream>>>(XhM, XlM, WA3, tm1_pwb, null_res, master1, gemmGridM, UM_);
    k_pwmfma   <<<gemmGrid, 512, 0, stream>>>(Xh, Xl, WA1, tr_pwb, null_res, G0, gemmGrid, UB_);
    // G0 = normal2

    // ---- stage 4: rev ----
    k_pool_conv<<<NV/4, 256, 0, stream>>>(G0, pooledN);
    k_normalize<<<NV/C_, 128, 0, stream>>>(pooledN);
    k_topk     <<<B_*H_, 64, 0, stream>>>(pooledN, idxb);
    k_A_rev    <<<BT_*H_, 256, 0, stream>>>(pooledN, idxb, bias_rev, alpha_rev, Arev);
    k_fused_rev<<<dsGrid, 256, 0, stream>>>(G0, Arev, idxb, rev_dw, rev_dwb, Xh, Xl);
    k_pwmfma   <<<gemmGrid, 512, 0, stream>>>(Xh, Xl, WA2, rev_pwb, G0, G1, gemmGrid, UB_);
    // G1 = normal3 (residual fused)

    // ---- stage 5: tm2 master -> output ----
    k_pool_conv<<<NV/4, 256, 0, stream>>>(G1, pooledN);
    k_normalize<<<NV/C_, 128, 0, stream>>>(pooledN);
    k_pool_m1  <<<(B_*H_*C_)/4, 256, 0, stream>>>(master1, pooledM);
    k_normalize<<<B_*H_, 128, 0, stream>>>(pooledM);
    k_A_tm     <<<B_*H_, 64, 0, stream>>>(pooledM, pooledN, bias_tm2, alpha_tm2, Atm2);
    k_agg_tm   <<<MS_/1024, 256, 0, stream>>>(master1, 0, G1, Atm2, Ma);
    k_dwsplit  <<<dsGridM, 256, 0, stream>>>(Ma, tm2_dw, tm2_dwb, XhM, XlM);
    k_pwmfma   <<<gemmGridM, 512, 0, stream>>>(XhM, XlM, WA4, tm2_pwb, null_res, out, gemmGridM, UM_);
}

// Round 15
// 965.493 us; speedup vs baseline: 1.4392x; 1.0130x over previous
//
#include <hip/hip_runtime.h>
#include <hip/hip_bf16.h>
#include <float.h>
#include <math.h>

// Problem constants
#define B_    4
#define H_    4
#define T_    8
#define D_    7
#define C_    128
#define HH_   14
#define S_    196     // 14*14
#define S4_   49      // S_/4
#define BT_   32      // B*T
#define HC_   512     // H*C
#define NODE_ 57      // 1 + T*D
#define K_    3
#define KD_   21      // K*D

#define BIG_  (BT_*D_*HC_*S_)   // 22,478,848 elements per big buffer
#define MS_   (B_*HC_*S_)       // 401,408 floats (master-size)
#define UB_   (BT_*D_*S_)       // 43904 big-pw u count
#define UM_   (B_*S_)           // 784 master u count
#define UMP_  896               // master u padded to 7*128
#define NT_   24                // K-tiles (3 x 512 / 64)
#define WS_   1024              // Waug stride: [hi 512 | lo 512]

typedef unsigned short u16;
typedef unsigned int   u32;
typedef short bf16x8 __attribute__((ext_vector_type(8)));
typedef float f32x4  __attribute__((ext_vector_type(4)));

__device__ __forceinline__ float wave_max(float v){
    #pragma unroll
    for(int o=32;o>0;o>>=1) v = fmaxf(v, __shfl_xor(v,o,64));
    return v;
}
__device__ __forceinline__ float wave_sum(float v){
    #pragma unroll
    for(int o=32;o>0;o>>=1) v += __shfl_xor(v,o,64);
    return v;
}
__device__ __forceinline__ u16 f2bf(float f){
    u32 u = __float_as_uint(f);
    u += 0x7FFF + ((u>>16)&1);
    return (u16)(u>>16);
}
__device__ __forceinline__ float bf2f(u16 h){ return __uint_as_float(((u32)h)<<16); }

// async global->LDS, 16B per lane; LDS dest = wave-uniform base + lane*16
__device__ __forceinline__ void gld16(const void* g, void* l){
    __builtin_amdgcn_global_load_lds(
        (__attribute__((address_space(1))) void*)(void*)g,
        (__attribute__((address_space(3))) void*)l, 16, 0, 0);
}

// monotone float->uint key (for atomicMax-based pooling)
__device__ __forceinline__ u32 fkey(float f){
    u32 u = __float_as_uint(f);
    return (u & 0x80000000u) ? ~u : (u | 0x80000000u);
}

// ---------------- pooling (max over S_) ----------------
__global__ void k_pool_x(const float* __restrict__ x, float* __restrict__ out){
    int v = blockIdx.x*4 + (threadIdx.x>>6);
    int lane = threadIdx.x & 63;
    int c = v & (C_-1);
    int r = v >> 7;
    int d = r % D_; r /= D_;
    int h = r & (H_-1); r >>= 2;
    int bt = r;
    int b = bt >> 3, t = bt & 7;
    const float* row = x + ((size_t)((b*H_+h)*NODE_ + 1 + t*D_ + d)*C_ + c)*S_;
    float m = -FLT_MAX;
    for(int s=lane; s<S_; s+=64) m = fmaxf(m, row[s]);
    m = wave_max(m);
    if(lane==0) out[v] = m;
}

__global__ void k_pool_x_master(const float* __restrict__ x, float* __restrict__ out){
    int v = blockIdx.x*4 + (threadIdx.x>>6);
    int lane = threadIdx.x & 63;
    int c = v & (C_-1);
    int h = (v>>7) & (H_-1);
    int b = v >> 9;
    const float* row = x + ((size_t)((b*H_+h)*NODE_)*C_ + c)*S_;
    float m = -FLT_MAX;
    for(int s=lane; s<S_; s+=64) m = fmaxf(m, row[s]);
    m = wave_max(m);
    if(lane==0) out[v] = m;
}

__global__ void k_pool_m1(const float* __restrict__ in, float* __restrict__ out){
    int v = blockIdx.x*4 + (threadIdx.x>>6);
    int lane = threadIdx.x & 63;
    int c = v & (C_-1);
    int h = (v>>7) & (H_-1);
    int b = v >> 9;
    const float* row = in + ((size_t)(b*HC_ + h*C_ + c))*S_;
    float m = -FLT_MAX;
    for(int s=lane; s<S_; s+=64) m = fmaxf(m, row[s]);
    m = wave_max(m);
    if(lane==0) out[v] = m;
}

__global__ void k_normalize(float* __restrict__ v){
    int vec = blockIdx.x;
    float val = v[(size_t)vec*C_ + threadIdx.x];
    float ss = wave_sum(val*val);
    __shared__ float sh[2];
    if((threadIdx.x&63)==0) sh[threadIdx.x>>6] = ss;
    __syncthreads();
    float tot = sh[0]+sh[1];
    v[(size_t)vec*C_ + threadIdx.x] = val / fmaxf(sqrtf(tot), 1e-12f);
}

// decode uint pool-keys (from GEMM-epilogue atomicMax) then normalize, in place
__global__ void k_decode_normalize(float* __restrict__ v){
    int vec = blockIdx.x;
    u32 key = ((const u32*)v)[(size_t)vec*C_ + threadIdx.x];
    u32 uu = (key & 0x80000000u) ? (key ^ 0x80000000u) : ~key;
    float val = __uint_as_float(uu);
    float ss = wave_sum(val*val);
    __shared__ float sh[2];
    if((threadIdx.x&63)==0) sh[threadIdx.x>>6] = ss;
    __syncthreads();
    float tot = sh[0]+sh[1];
    v[(size_t)vec*C_ + threadIdx.x] = val / fmaxf(sqrtf(tot), 1e-12f);
}

// ---------------- A matrices ----------------
__global__ void k_A_if(const float* __restrict__ vn, const float* __restrict__ bias,
                       const float* __restrict__ alpha_p, float* __restrict__ A){
    int bh = blockIdx.x;           // bt*H + h
    __shared__ float vs[D_*C_];
    __shared__ float z[D_][D_];
    for(int e=threadIdx.x; e<D_*C_; e+=64) vs[e] = vn[(size_t)bh*D_*C_ + e];
    __syncthreads();
    float alpha = alpha_p[0];
    if(threadIdx.x < D_*D_){
        int n = threadIdx.x/D_, m = threadIdx.x%D_;
        float acc=0.f;
        for(int c=0;c<C_;c++) acc += vs[n*C_+c]*vs[m*C_+c];
        z[n][m] = acc/alpha + bias[n*D_+m];
    }
    __syncthreads();
    if(threadIdx.x < D_){
        int n = threadIdx.x;
        float mx=-FLT_MAX;
        for(int m=0;m<D_;m++) mx=fmaxf(mx,z[n][m]);
        float e[D_]; float sum=0.f;
        for(int m=0;m<D_;m++){ e[m]=expf(z[n][m]-mx); sum+=e[m]; }
        for(int m=0;m<D_;m++) A[((size_t)bh*D_+n)*D_+m] = e[m]/sum;
    }
}

__global__ void k_A_tm(const float* __restrict__ vm, const float* __restrict__ vnrm,
                       const float* __restrict__ bias, const float* __restrict__ alpha_p,
                       float* __restrict__ A){
    int bh = blockIdx.x;           // b*H + h
    int b = bh>>2, h = bh&3;
    __shared__ float v0[C_];
    __shared__ float z[NODE_];
    for(int e=threadIdx.x;e<C_;e+=64) v0[e]=vm[(size_t)bh*C_+e];
    __syncthreads();
    float alpha=alpha_p[0];
    if(threadIdx.x<NODE_){
        int m=threadIdx.x;
        float acc=0.f;
        if(m==0){
            for(int c=0;c<C_;c++) acc+=v0[c]*v0[c];
        } else {
            int t=(m-1)/D_, d=(m-1)%D_;
            const float* vp = vnrm + (size_t)(((b*T_+t)*H_+h)*D_+d)*C_;
            for(int c=0;c<C_;c++) acc+=v0[c]*vp[c];
        }
        z[m]=acc/alpha + bias[m];
    }
    __syncthreads();
    if(threadIdx.x==0){
        float mx=-FLT_MAX;
        for(int m=0;m<NODE_;m++) mx=fmaxf(mx,z[m]);
        float sum=0.f;
        for(int m=0;m<NODE_;m++){ z[m]=expf(z[m]-mx); sum+=z[m]; }
        for(int m=0;m<NODE_;m++) A[(size_t)bh*NODE_+m]=z[m]/sum;
    }
}

__global__ void k_topk(const float* __restrict__ voHat, int* __restrict__ idx){
    int bh = blockIdx.x;           // b*H + h
    int b = bh>>2, h = bh&3;
    __shared__ float mv[T_][C_];
    __shared__ float As[T_][T_];
    for(int e=threadIdx.x;e<T_*C_;e+=64){
        int t=e>>7, c=e&(C_-1);
        mv[t][c]=voHat[(size_t)(((b*T_+t)*H_+h)*D_+(D_-1))*C_+c];
    }
    __syncthreads();
    {
        int t=threadIdx.x>>3, s2=threadIdx.x&7;
        float acc=0.f;
        for(int c=0;c<C_;c++) acc+=mv[t][c]*mv[s2][c];
        As[t][s2]=acc;
    }
    __syncthreads();
    if(threadIdx.x<T_){
        int t=threadIdx.x;
        bool used[T_];
        for(int j=0;j<T_;j++) used[j]=false;
        for(int k=0;k<K_;k++){
            float mn=FLT_MAX; int bi=0;
            for(int s2=0;s2<T_;s2++){
                if(!used[s2] && As[t][s2]<mn){ mn=As[t][s2]; bi=s2; }
            }
            used[bi]=true;
            idx[((size_t)bh*T_+t)*K_+k]=bi;
        }
    }
}

__global__ void k_A_rev(const float* __restrict__ voHat, const int* __restrict__ idx,
                        const float* __restrict__ bias, const float* __restrict__ alpha_p,
                        float* __restrict__ A){
    int bth = blockIdx.x;          // bt*H + h
    int bt = bth>>2, h = bth&3;
    int b = bt>>3, t = bt&7;
    __shared__ float vo[D_][C_];
    __shared__ float vd[KD_][C_];
    __shared__ float z[D_][KD_];
    for(int e=threadIdx.x;e<D_*C_;e+=256){
        int n=e>>7, c=e&(C_-1);
        vo[n][c]=voHat[(size_t)((bt*H_+h)*D_+n)*C_+c];
    }
    for(int e=threadIdx.x;e<KD_*C_;e+=256){
        int m=e>>7, c=e&(C_-1);
        int k=m/D_, dp=m%D_;
        int tt=idx[((size_t)(b*H_+h)*T_+t)*K_+k];
        vd[m][c]=voHat[(size_t)(((b*T_+tt)*H_+h)*D_+dp)*C_+c];
    }
    __syncthreads();
    float alpha=alpha_p[0];
    if(threadIdx.x<D_*KD_){
        int n=threadIdx.x/KD_, m=threadIdx.x%KD_;
        float acc=0.f;
        for(int c=0;c<C_;c++) acc+=vo[n][c]*vd[m][c];
        z[n][m] = -acc/alpha + bias[n*KD_+m];
    }
    __syncthreads();
    if(threadIdx.x<D_){
        int n=threadIdx.x;
        float mx=-FLT_MAX;
        for(int m=0;m<KD_;m++) mx=fmaxf(mx,z[n][m]);
        float sum=0.f;
        for(int m=0;m<KD_;m++){ z[n][m]=expf(z[n][m]-mx); sum+=z[n][m]; }
        for(int m=0;m<KD_;m++) A[(size_t)((bt*H_+h)*D_+n)*KD_+m]=z[n][m]/sum;
    }
}

// ---------------- master aggregation (float4-vectorized) ----------------
__global__ void k_agg_tm(const float* __restrict__ mastersrc, int master_is_x,
                         const float* __restrict__ normal, const float* __restrict__ A,
                         float* __restrict__ out){
    int v = blockIdx.x*256 + threadIdx.x;       // < MS_/4
    int s4 = v % S4_;
    int r  = v / S4_;
    int hc = r & (HC_-1);
    int b  = r >> 9;
    int h = hc >> 7, c = hc & (C_-1);
    const float* Ap = A + (size_t)(b*H_+h)*NODE_;
    f32x4 m0;
    if(master_is_x) m0 = *(const f32x4*)(mastersrc + ((size_t)((b*H_+h)*NODE_)*C_ + c)*S_ + s4*4);
    else            m0 = *(const f32x4*)(mastersrc + (size_t)(b*HC_+hc)*S_ + s4*4);
    f32x4 acc = Ap[0]*m0;
    for(int t=0;t<T_;t++){
        const float* np = normal + ((size_t)((b*T_+t)*D_)*HC_+hc)*S_ + s4*4;
        #pragma unroll
        for(int d=0;d<D_;d++)
            acc += Ap[1+t*D_+d] * *(const f32x4*)(np + (size_t)d*HC_*S_);
    }
    *(f32x4*)(out + (size_t)r*S_ + s4*4) = acc;
}

// -------- shared dw+split tail (16-channel tiles) --------
__device__ __forceinline__ void dw_split_tail(float (*ti)[S_], float (*to)[S_],
                                              const float* __restrict__ w,
                                              const float* __restrict__ bias,
                                              int img, int ch0,
                                              u16* __restrict__ Xh, u16* __restrict__ Xl){
    int tid = threadIdx.x;
    for(int e=tid; e<16*S_; e+=256){
        int chl = e/S_, s = e - (e/S_)*S_;
        int ch = ch0 + chl;
        int y = s/HH_, xx = s - (s/HH_)*HH_;
        float acc = bias[ch];
        #pragma unroll
        for(int ky=0;ky<3;ky++){
            int yy=y+ky-1;
            if(yy<0||yy>=HH_) continue;
            #pragma unroll
            for(int kx=0;kx<3;kx++){
                int xx2=xx+kx-1;
                if(xx2<0||xx2>=HH_) continue;
                acc += ti[chl][yy*HH_+xx2]*w[ch*9+ky*3+kx];
            }
        }
        to[chl][s]=acc;
    }
    __syncthreads();
    for(int e=tid; e<16*S_; e+=256){
        int s = e>>4, chl = e&15;
        float f = to[chl][s];
        u16 h = f2bf(f);
        float lo = f - bf2f(h);
        size_t o = ((size_t)img*S_ + s)*HC_ + ch0 + chl;
        Xh[o] = h;
        Xl[o] = f2bf(lo);
    }
}

// ---------------- plain depthwise+split (master path) ----------------
__launch_bounds__(256)
__global__ void k_dwsplit(const float* __restrict__ in, const float* __restrict__ w,
                          const float* __restrict__ bias,
                          u16* __restrict__ Xh, u16* __restrict__ Xl){
    int img = blockIdx.x >> 5;
    int ch0 = (blockIdx.x & 31) * 16;
    __shared__ float ti[16][S_];
    __shared__ float to[16][S_];
    int tid = threadIdx.x;
    for(int e=tid; e<16*S4_; e+=256){
        int chl = e/S4_, s4 = e - (e/S4_)*S4_;
        *(f32x4*)&ti[chl][s4*4] =
            *(const f32x4*)(in + ((size_t)img*HC_ + ch0 + chl)*S_ + s4*4);
    }
    __syncthreads();
    dw_split_tail(ti, to, w, bias, img, ch0, Xh, Xl);
}

// ---------------- dwsplit + fused max-pool of the INPUT (pre-dw) ----------------
__launch_bounds__(256)
__global__ void k_dwsplit_pool(const float* __restrict__ in, const float* __restrict__ w,
                               const float* __restrict__ bias,
                               u16* __restrict__ Xh, u16* __restrict__ Xl,
                               float* __restrict__ pooled){
    int img = blockIdx.x >> 5;
    int ch0 = (blockIdx.x & 31) * 16;
    __shared__ float ti[16][S_];
    __shared__ float to[16][S_];
    __shared__ float pm[16][17];
    int tid = threadIdx.x;
    for(int e=tid; e<16*S4_; e+=256){
        int chl = e/S4_, s4 = e - (e/S4_)*S4_;
        *(f32x4*)&ti[chl][s4*4] =
            *(const f32x4*)(in + ((size_t)img*HC_ + ch0 + chl)*S_ + s4*4);
    }
    __syncthreads();
    {
        int chl = tid & 15, g = tid >> 4;
        float m = -FLT_MAX;
        for(int s=g; s<S_; s+=16) m = fmaxf(m, ti[chl][s]);
        pm[chl][g] = m;
    }
    __syncthreads();
    if(tid < 16){
        float mm = -FLT_MAX;
        #pragma unroll
        for(int g2=0; g2<16; g2++) mm = fmaxf(mm, pm[tid][g2]);
        int bt = img/7, d = img - (img/7)*7;
        pooled[(size_t)((bt*4 + (ch0>>7))*7 + d)*C_ + (ch0 & 127) + tid] = mm;
    }
    __syncthreads();
    dw_split_tail(ti, to, w, bias, img, ch0, Xh, Xl);
}

// ---------------- fused IF: agg(7-term, float4) + dw + split ----------------
__launch_bounds__(256)
__global__ void k_fused_if(const float* __restrict__ x, const float* __restrict__ A,
                           const float* __restrict__ w, const float* __restrict__ bias,
                           u16* __restrict__ Xh, u16* __restrict__ Xl){
    int img = blockIdx.x >> 5;          // bt*7 + d
    int ch0 = (blockIdx.x & 31) * 16;
    int bt = img/7, d = img - bt*7;
    int b = bt >> 3, t = bt & 7;
    int h = ch0 >> 7, c0 = ch0 & 127;
    __shared__ float ti[16][S_];
    __shared__ float to[16][S_];
    float a[D_];
    #pragma unroll
    for(int m=0;m<D_;m++) a[m] = A[(size_t)((bt*4+h)*D_ + d)*D_ + m];
    int tid = threadIdx.x;
    const float* xb = x + ((size_t)((b*H_+h)*NODE_ + 1 + t*D_)*C_ + c0)*S_;
    for(int e=tid; e<16*S4_; e+=256){
        int chl = e/S4_, s4 = e - (e/S4_)*S4_;
        const f32x4* xp = (const f32x4*)(xb + (size_t)chl*S_) + s4;
        f32x4 acc = {0.f,0.f,0.f,0.f};
        #pragma unroll
        for(int m=0;m<D_;m++) acc += a[m]*xp[(size_t)m*C_*S4_];
        *(f32x4*)&ti[chl][s4*4] = acc;
    }
    __syncthreads();
    dw_split_tail(ti, to, w, bias, img, ch0, Xh, Xl);
}

// ---------------- fused REV: gather-agg(21-term, float4) + dw + split ----------------
__launch_bounds__(256)
__global__ void k_fused_rev(const float* __restrict__ n2, const float* __restrict__ A,
                            const int* __restrict__ idx,
                            const float* __restrict__ w, const float* __restrict__ bias,
                            u16* __restrict__ Xh, u16* __restrict__ Xl){
    int img = blockIdx.x >> 5;          // bt*7 + d
    int ch0 = (blockIdx.x & 31) * 16;
    int bt = img/7, d = img - bt*7;
    int b = bt >> 3, t = bt & 7;
    int h = ch0 >> 7;
    __shared__ float ti[16][S_];
    __shared__ float to[16][S_];
    float a[KD_];
    #pragma unroll
    for(int j=0;j<KD_;j++) a[j] = A[(size_t)((bt*4+h)*D_ + d)*KD_ + j];
    int tt0 = idx[((size_t)(b*H_+h)*T_+t)*K_+0];
    int tt1 = idx[((size_t)(b*H_+h)*T_+t)*K_+1];
    int tt2 = idx[((size_t)(b*H_+h)*T_+t)*K_+2];
    const f32x4* p0 = (const f32x4*)(n2 + ((size_t)((b*T_+tt0)*D_)*HC_ + ch0)*S_);
    const f32x4* p1 = (const f32x4*)(n2 + ((size_t)((b*T_+tt1)*D_)*HC_ + ch0)*S_);
    const f32x4* p2 = (const f32x4*)(n2 + ((size_t)((b*T_+tt2)*D_)*HC_ + ch0)*S_);
    int tid = threadIdx.x;
    for(int e=tid; e<16*S4_; e+=256){
        int chl = e/S4_, s4 = e - (e/S4_)*S4_;
        size_t off = (size_t)chl*S4_ + s4;
        f32x4 acc = {0.f,0.f,0.f,0.f};
        #pragma unroll
        for(int dp=0;dp<D_;dp++){
            size_t o2 = off + (size_t)dp*HC_*S4_;
            acc += a[dp]      * p0[o2];
            acc += a[D_+dp]   * p1[o2];
            acc += a[2*D_+dp] * p2[o2];
        }
        *(f32x4*)&ti[chl][s4*4] = acc;
    }
    __syncthreads();
    dw_split_tail(ti, to, w, bias, img, ch0, Xh, Xl);
}

// ---------------- weight prep: fp32 [oc][ic] -> bf16 Waug [oc][hi 512 | lo 512] ----------------
__global__ void k_prepW(const float* __restrict__ Wg, u16* __restrict__ Waug){
    int i = blockIdx.x*256 + threadIdx.x;   // < 512*512
    int oc = i >> 9, ic = i & 511;
    float f = Wg[i];
    u16 h = f2bf(f);
    float lo = f - bf2f(h);
    size_t base = (size_t)oc*WS_;
    Waug[base + ic]       = h;
    Waug[base + 512 + ic] = f2bf(lo);
}

// ---------------- MFMA pointwise GEMM (split-bf16, 24 K-tiles, BK=64) ----------------
// Round-9 structure: ring-2 64KB LDS, 8 waves, gld16, counted vmcnt(4),
// XCD-chunked oc-fastest swizzle. Optional fused max-pool epilogue (pooled!=0):
// LDS atomicMax into <=2 img x 128 oc slots, then global atomicMax of uint keys.
__launch_bounds__(512)
__global__ void k_pwmfma(const u16* __restrict__ Xh, const u16* __restrict__ Xl,
                         const u16* __restrict__ Waug, const float* __restrict__ bias,
                         const float* __restrict__ res, float* __restrict__ out,
                         int nwg, int utot, u32* __restrict__ pooled){
    __shared__ u16 SM[2][16384];           // 2 x 32KB: [As 8192 u16 | Bs 8192 u16]
    const int tid  = threadIdx.x;
    const int q = nwg >> 3, r = nwg & 7;
    int xcd = blockIdx.x & 7, j = blockIdx.x >> 3;
    int L = xcd*q + (xcd < r ? xcd : r) + j;
    const int u0   = (L >> 2) * 128;
    const int oc0  = (L & 3) * 128;
    const int lane = tid & 63;
    const int w    = tid >> 6;             // 0..7
    const int wr   = w >> 1, wc = w & 1;   // 4 x 2 wave grid
    const int l15  = lane & 15, lg = lane >> 4;

    f32x4 acc[2][4];
    #pragma unroll
    for(int mi=0;mi<2;mi++)
        #pragma unroll
        for(int ni=0;ni<4;ni++)
            acc[mi][ni] = (f32x4){0.f,0.f,0.f,0.f};

    auto STAGE = [&](int t){               // 4 gld16 issues per wave (2A + 2B)
        int jj, wk, xk; const u16* Xp;
        if(t < 16){ jj = t>>1; wk = (t&1) ? 512 + jj*64 : jj*64; Xp = Xh; xk = jj*64; }
        else      { jj = t-16; wk = jj*64;                        Xp = Xl; xk = jj*64; }
        u16* Asb = SM[t&1];
        u16* Bsb = Asb + 8192;
        #pragma unroll
        for(int i=0;i<2;i++){
            int seg = w*2 + i;             // 0..15, 8 rows each
            int row = seg*8 + (lane>>3);
            int cg  = (lane&7) ^ (lane>>3);
            gld16(Waug + (size_t)(oc0+row)*WS_ + wk + cg*8, Asb + seg*512);
            gld16(Xp   + (size_t)(u0 +row)*512 + xk + cg*8, Bsb + seg*512);
        }
    };
    auto COMPUTE = [&](int cur){
        const u16* Asb = SM[cur];
        const u16* Bsb = SM[cur] + 8192;
        #pragma unroll
        for(int ks=0;ks<2;ks++){
            bf16x8 a[2], b[4];
            #pragma unroll
            for(int mi=0;mi<2;mi++){
                int row = wr*32 + mi*16 + l15;
                int ch  = ((ks<<2) + lg) ^ (row & 7);
                a[mi] = *(const bf16x8*)(Asb + row*64 + ch*8);
            }
            #pragma unroll
            for(int ni=0;ni<4;ni++){
                int row = wc*64 + ni*16 + l15;
                int ch  = ((ks<<2) + lg) ^ (row & 7);
                b[ni] = *(const bf16x8*)(Bsb + row*64 + ch*8);
            }
            #pragma unroll
            for(int mi=0;mi<2;mi++)
                #pragma unroll
                for(int ni=0;ni<4;ni++)
                    acc[mi][ni] = __builtin_amdgcn_mfma_f32_16x16x32_bf16(a[mi], b[ni], acc[mi][ni], 0,0,0);
        }
    };

    STAGE(0);
    for(int t=0; t<NT_; t++){
        if(t+1 < NT_){
            STAGE(t+1);                                      // 8 outstanding/wave
            asm volatile("s_waitcnt vmcnt(4)" ::: "memory"); // tile t landed
        } else {
            asm volatile("s_waitcnt vmcnt(0)" ::: "memory");
        }
        __builtin_amdgcn_s_barrier();      // all waves' tile-t loads in LDS
        asm volatile("" ::: "memory");
        COMPUTE(t&1);
        asm volatile("" ::: "memory");
        __builtin_amdgcn_s_barrier();      // buf[t&1] free for restage
    }

    // epilogue pool slots (reuse SM; main loop ended with a barrier)
    u32* pl = (u32*)&SM[0][0];
    const int img0 = u0 / S_;
    if(pooled){
        if(tid < 256) pl[tid] = 0u;
        __syncthreads();
    }

    #pragma unroll
    for(int ni=0;ni<4;ni++){
        int u = u0 + wc*64 + ni*16 + l15;
        if(u >= utot) continue;
        int img = u / S_, s = u - img*S_;
        int li = (img - img0) << 7;
        #pragma unroll
        for(int mi=0;mi<2;mi++){
            int ocl = wr*32 + mi*16 + lg*4;
            #pragma unroll
            for(int q2=0;q2<4;q2++){
                int oc = oc0 + ocl + q2;
                size_t oidx = ((size_t)img*HC_ + oc)*S_ + s;
                float v = acc[mi][ni][q2] + bias[oc];
                if(res) v += res[oidx];
                out[oidx] = v;
                if(pooled) atomicMax(&pl[li + ocl + q2], fkey(v));
            }
        }
    }

    if(pooled){
        __syncthreads();
        if(tid < 256){
            int li2 = tid >> 7, ocl = tid & 127;
            int img = img0 + li2;
            int ulast = (u0 + 127 < utot) ? (u0 + 127) : (utot - 1);
            if(img <= ulast / S_){
                int oc = oc0 + ocl;
                int bt = img / D_, d = img - (img/D_)*D_;
                int h = oc >> 7, c = oc & 127;
                atomicMax(pooled + ((size_t)((bt*4+h)*D_ + d)*C_ + c), pl[tid]);
            }
        }
    }
}

extern "C" void kernel_launch(void* const* d_in, const int* in_sizes, int n_in,
                              void* d_out, int out_size, void* d_ws, size_t ws_size,
                              hipStream_t stream){
    (void)in_sizes; (void)n_in; (void)out_size; (void)ws_size;
    const float* x         = (const float*)d_in[0];
    const float* alpha_if  = (const float*)d_in[1];
    const float* alpha_tm1 = (const float*)d_in[2];
    const float* alpha_rev = (const float*)d_in[3];
    const float* alpha_tm2 = (const float*)d_in[4];
    const float* bias_if   = (const float*)d_in[5];
    const float* bias_tm1  = (const float*)d_in[6];
    const float* bias_rev  = (const float*)d_in[7];
    const float* bias_tm2  = (const float*)d_in[8];
    const float* if_dw =(const float*)d_in[9];  const float* if_dwb =(const float*)d_in[10];
    const float* if_pw =(const float*)d_in[11]; const float* if_pwb =(const float*)d_in[12];
    const float* tm1_dw=(const float*)d_in[13]; const float* tm1_dwb=(const float*)d_in[14];
    const float* tm1_pw=(const float*)d_in[15]; const float* tm1_pwb=(const float*)d_in[16];
    const float* rev_dw=(const float*)d_in[17]; const float* rev_dwb=(const float*)d_in[18];
    const float* rev_pw=(const float*)d_in[19]; const float* rev_pwb=(const float*)d_in[20];
    const float* tm2_dw=(const float*)d_in[21]; const float* tm2_dwb=(const float*)d_in[22];
    const float* tm2_pw=(const float*)d_in[23]; const float* tm2_pwb=(const float*)d_in[24];
    const float* tr_dw =(const float*)d_in[25]; const float* tr_dwb =(const float*)d_in[26];
    const float* tr_pw =(const float*)d_in[27]; const float* tr_pwb =(const float*)d_in[28];

    float* ws = (float*)d_ws;
    float* G0      = ws;                          // BIG_ fp32
    float* G1      = G0 + (size_t)BIG_;           // BIG_ fp32
    u16*   Xh      = (u16*)(ws + 2*(size_t)BIG_); // BIG_ u16
    u16*   Xl      = Xh + (size_t)BIG_;           // BIG_ u16
    u16*   WA0     = Xl + (size_t)BIG_;           // 512*1024 u16 each
    u16*   WA1     = WA0 + 512*WS_;
    u16*   WA2     = WA1 + 512*WS_;
    u16*   WA3     = WA2 + 512*WS_;               // tm1
    u16*   WA4     = WA3 + 512*WS_;               // tm2
    u16*   XhM     = WA4 + 512*WS_;               // UMP_*512 u16 master X
    u16*   XlM     = XhM + (size_t)UMP_*HC_;
    float* master1 = (float*)(XlM + (size_t)UMP_*HC_);   // MS_
    float* Ma      = master1 + MS_;               // MS_
    float* pooledN = Ma + MS_;                    // 114688
    float* pooledM = pooledN + BT_*H_*D_*C_;      // 2048
    float* Aif     = pooledM + B_*H_*C_;          // 6272
    float* Atm1    = Aif + BT_*H_*D_*D_;          // 912
    float* Arev    = Atm1 + B_*H_*NODE_;          // 18816
    float* Atm2    = Arev + BT_*H_*D_*KD_;        // 912
    int*   idxb    = (int*)(Atm2 + B_*H_*NODE_);  // 384 ints
    float* out     = (float*)d_out;

    const int NV  = BT_*H_*D_*C_;     // pooled rows (114688)
    const int gemmGrid  = (UB_/128)*4;          // 1372
    const int gemmGridM = (UMP_/128)*4;         // 28
    const int dsGrid    = BT_*D_*32;  // 7168 (16-ch chunks)
    const int dsGridM   = B_*32;      // 128
    float* null_res = nullptr;
    u32*   no_pool  = nullptr;

    // weight prep (all five pw weights)
    k_prepW<<<1024, 256, 0, stream>>>(if_pw,  WA0);
    k_prepW<<<1024, 256, 0, stream>>>(tr_pw,  WA1);
    k_prepW<<<1024, 256, 0, stream>>>(rev_pw, WA2);
    k_prepW<<<1024, 256, 0, stream>>>(tm1_pw, WA3);
    k_prepW<<<1024, 256, 0, stream>>>(tm2_pw, WA4);

    // ---- stage 1: IF ----
    k_pool_x   <<<NV/4, 256, 0, stream>>>(x, pooledN);
    k_normalize<<<NV/C_, 128, 0, stream>>>(pooledN);
    k_A_if     <<<BT_*H_, 64, 0, stream>>>(pooledN, bias_if, alpha_if, Aif);
    k_fused_if <<<dsGrid, 256, 0, stream>>>(x, Aif, if_dw, if_dwb, Xh, Xl);
    k_pwmfma   <<<gemmGrid, 512, 0, stream>>>(Xh, Xl, WA0, if_pwb, null_res, G1, gemmGrid, UB_, no_pool);
    // G1 = normal1

    // ---- stage 2+3 (reordered): tr dwsplit+pool first, then masters, then tr GEMM ----
    k_dwsplit_pool<<<dsGrid, 256, 0, stream>>>(G1, tr_dw, tr_dwb, Xh, Xl, pooledN);
    k_normalize<<<NV/C_, 128, 0, stream>>>(pooledN);
    k_pool_x_master<<<(B_*H_*C_)/4, 256, 0, stream>>>(x, pooledM);
    k_normalize<<<B_*H_, 128, 0, stream>>>(pooledM);
    k_A_tm     <<<B_*H_, 64, 0, stream>>>(pooledM, pooledN, bias_tm1, alpha_tm1, Atm1);
    k_agg_tm   <<<MS_/1024, 256, 0, stream>>>(x, 1, G1, Atm1, Ma);
    k_dwsplit  <<<dsGridM, 256, 0, stream>>>(Ma, tm1_dw, tm1_dwb, XhM, XlM);
    k_pwmfma   <<<gemmGridM, 512, 0, stream>>>(XhM, XlM, WA3, tm1_pwb, null_res, master1, gemmGridM, UM_, no_pool);
    hipMemsetAsync(pooledN, 0, (size_t)NV*sizeof(float), stream);
    k_pwmfma   <<<gemmGrid, 512, 0, stream>>>(Xh, Xl, WA1, tr_pwb, null_res, G0, gemmGrid, UB_, (u32*)pooledN);
    // G0 = normal2; pooledN = uint keys of max over s

    // ---- stage 4: rev ----
    k_decode_normalize<<<NV/C_, 128, 0, stream>>>(pooledN);
    k_topk     <<<B_*H_, 64, 0, stream>>>(pooledN, idxb);
    k_A_rev    <<<BT_*H_, 256, 0, stream>>>(pooledN, idxb, bias_rev, alpha_rev, Arev);
    k_fused_rev<<<dsGrid, 256, 0, stream>>>(G0, Arev, idxb, rev_dw, rev_dwb, Xh, Xl);
    hipMemsetAsync(pooledN, 0, (size_t)NV*sizeof(float), stream);
    k_pwmfma   <<<gemmGrid, 512, 0, stream>>>(Xh, Xl, WA2, rev_pwb, G0, G1, gemmGrid, UB_, (u32*)pooledN);
    // G1 = normal3 (residual fused); pooledN = uint keys

    // ---- stage 5: tm2 master -> output ----
    k_decode_normalize<<<NV/C_, 128, 0, stream>>>(pooledN);
    k_pool_m1  <<<(B_*H_*C_)/4, 256, 0, stream>>>(master1, pooledM);
    k_normalize<<<B_*H_, 128, 0, stream>>>(pooledM);
    k_A_tm     <<<B_*H_, 64, 0, stream>>>(pooledM, pooledN, bias_tm2, alpha_tm2, Atm2);
    k_agg_tm   <<<MS_/1024, 256, 0, stream>>>(master1, 0, G1, Atm2, Ma);
    k_dwsplit  <<<dsGridM, 256, 0, stream>>>(Ma, tm2_dw, tm2_dwb, XhM, XlM);
    k_pwmfma   <<<gemmGridM, 512, 0, stream>>>(XhM, XlM, WA4, tm2_pwb, null_res, out, gemmGridM, UM_, no_pool);
}

// Round 16
// 927.056 us; speedup vs baseline: 1.4988x; 1.0415x over previous
//
#include <hip/hip_runtime.h>
#include <hip/hip_bf16.h>
#include <float.h>
#include <math.h>

// Problem constants
#define B_    4
#define H_    4
#define T_    8
#define D_    7
#define C_    128
#define HH_   14
#define S_    196     // 14*14
#define S4_   49      // S_/4
#define BT_   32      // B*T
#define HC_   512     // H*C
#define NODE_ 57      // 1 + T*D
#define K_    3
#define KD_   21      // K*D

#define BIG_  (BT_*D_*HC_*S_)   // 22,478,848 elements per big buffer
#define MS_   (B_*HC_*S_)       // 401,408 floats (master-size)
#define UB_   (BT_*D_*S_)       // 43904 big-pw u count
#define UM_   (B_*S_)           // 784 master u count
#define UMP_  896               // master u padded to 7*128
#define NT_   24                // K-tiles (3 x 512 / 64)
#define WS_   1024              // Waug stride: [hi 512 | lo 512]

typedef unsigned short u16;
typedef unsigned int   u32;
typedef short bf16x8 __attribute__((ext_vector_type(8)));
typedef float f32x4  __attribute__((ext_vector_type(4)));

__device__ __forceinline__ float wave_max(float v){
    #pragma unroll
    for(int o=32;o>0;o>>=1) v = fmaxf(v, __shfl_xor(v,o,64));
    return v;
}
__device__ __forceinline__ float wave_sum(float v){
    #pragma unroll
    for(int o=32;o>0;o>>=1) v += __shfl_xor(v,o,64);
    return v;
}
__device__ __forceinline__ u16 f2bf(float f){
    u32 u = __float_as_uint(f);
    u += 0x7FFF + ((u>>16)&1);
    return (u16)(u>>16);
}
__device__ __forceinline__ float bf2f(u16 h){ return __uint_as_float(((u32)h)<<16); }

// async global->LDS, 16B per lane; LDS dest = wave-uniform base + lane*16
__device__ __forceinline__ void gld16(const void* g, void* l){
    __builtin_amdgcn_global_load_lds(
        (__attribute__((address_space(1))) void*)(void*)g,
        (__attribute__((address_space(3))) void*)l, 16, 0, 0);
}

// ---------------- pooling (max over S_) ----------------
__global__ void k_pool_x(const float* __restrict__ x, float* __restrict__ out){
    int v = blockIdx.x*4 + (threadIdx.x>>6);
    int lane = threadIdx.x & 63;
    int c = v & (C_-1);
    int r = v >> 7;
    int d = r % D_; r /= D_;
    int h = r & (H_-1); r >>= 2;
    int bt = r;
    int b = bt >> 3, t = bt & 7;
    const float* row = x + ((size_t)((b*H_+h)*NODE_ + 1 + t*D_ + d)*C_ + c)*S_;
    float m = -FLT_MAX;
    for(int s=lane; s<S_; s+=64) m = fmaxf(m, row[s]);
    m = wave_max(m);
    if(lane==0) out[v] = m;
}

__global__ void k_pool_conv(const float* __restrict__ in, float* __restrict__ out){
    int v = blockIdx.x*4 + (threadIdx.x>>6);
    int lane = threadIdx.x & 63;
    int c = v & (C_-1);
    int r = v >> 7;
    int d = r % D_; r /= D_;
    int h = r & (H_-1); r >>= 2;
    int bt = r;
    const float* row = in + ((size_t)((bt*D_+d)*HC_ + h*C_ + c))*S_;
    float m = -FLT_MAX;
    for(int s=lane; s<S_; s+=64) m = fmaxf(m, row[s]);
    m = wave_max(m);
    if(lane==0) out[v] = m;
}

__global__ void k_pool_x_master(const float* __restrict__ x, float* __restrict__ out){
    int v = blockIdx.x*4 + (threadIdx.x>>6);
    int lane = threadIdx.x & 63;
    int c = v & (C_-1);
    int h = (v>>7) & (H_-1);
    int b = v >> 9;
    const float* row = x + ((size_t)((b*H_+h)*NODE_)*C_ + c)*S_;
    float m = -FLT_MAX;
    for(int s=lane; s<S_; s+=64) m = fmaxf(m, row[s]);
    m = wave_max(m);
    if(lane==0) out[v] = m;
}

__global__ void k_pool_m1(const float* __restrict__ in, float* __restrict__ out){
    int v = blockIdx.x*4 + (threadIdx.x>>6);
    int lane = threadIdx.x & 63;
    int c = v & (C_-1);
    int h = (v>>7) & (H_-1);
    int b = v >> 9;
    const float* row = in + ((size_t)(b*HC_ + h*C_ + c))*S_;
    float m = -FLT_MAX;
    for(int s=lane; s<S_; s+=64) m = fmaxf(m, row[s]);
    m = wave_max(m);
    if(lane==0) out[v] = m;
}

__global__ void k_normalize(float* __restrict__ v){
    int vec = blockIdx.x;
    float val = v[(size_t)vec*C_ + threadIdx.x];
    float ss = wave_sum(val*val);
    __shared__ float sh[2];
    if((threadIdx.x&63)==0) sh[threadIdx.x>>6] = ss;
    __syncthreads();
    float tot = sh[0]+sh[1];
    v[(size_t)vec*C_ + threadIdx.x] = val / fmaxf(sqrtf(tot), 1e-12f);
}

// ---------------- A matrices ----------------
__global__ void k_A_if(const float* __restrict__ vn, const float* __restrict__ bias,
                       const float* __restrict__ alpha_p, float* __restrict__ A){
    int bh = blockIdx.x;           // bt*H + h
    __shared__ float vs[D_*C_];
    __shared__ float z[D_][D_];
    for(int e=threadIdx.x; e<D_*C_; e+=64) vs[e] = vn[(size_t)bh*D_*C_ + e];
    __syncthreads();
    float alpha = alpha_p[0];
    if(threadIdx.x < D_*D_){
        int n = threadIdx.x/D_, m = threadIdx.x%D_;
        float acc=0.f;
        for(int c=0;c<C_;c++) acc += vs[n*C_+c]*vs[m*C_+c];
        z[n][m] = acc/alpha + bias[n*D_+m];
    }
    __syncthreads();
    if(threadIdx.x < D_){
        int n = threadIdx.x;
        float mx=-FLT_MAX;
        for(int m=0;m<D_;m++) mx=fmaxf(mx,z[n][m]);
        float e[D_]; float sum=0.f;
        for(int m=0;m<D_;m++){ e[m]=expf(z[n][m]-mx); sum+=e[m]; }
        for(int m=0;m<D_;m++) A[((size_t)bh*D_+n)*D_+m] = e[m]/sum;
    }
}

__global__ void k_A_tm(const float* __restrict__ vm, const float* __restrict__ vnrm,
                       const float* __restrict__ bias, const float* __restrict__ alpha_p,
                       float* __restrict__ A){
    int bh = blockIdx.x;           // b*H + h
    int b = bh>>2, h = bh&3;
    __shared__ float v0[C_];
    __shared__ float z[NODE_];
    for(int e=threadIdx.x;e<C_;e+=64) v0[e]=vm[(size_t)bh*C_+e];
    __syncthreads();
    float alpha=alpha_p[0];
    if(threadIdx.x<NODE_){
        int m=threadIdx.x;
        float acc=0.f;
        if(m==0){
            for(int c=0;c<C_;c++) acc+=v0[c]*v0[c];
        } else {
            int t=(m-1)/D_, d=(m-1)%D_;
            const float* vp = vnrm + (size_t)(((b*T_+t)*H_+h)*D_+d)*C_;
            for(int c=0;c<C_;c++) acc+=v0[c]*vp[c];
        }
        z[m]=acc/alpha + bias[m];
    }
    __syncthreads();
    if(threadIdx.x==0){
        float mx=-FLT_MAX;
        for(int m=0;m<NODE_;m++) mx=fmaxf(mx,z[m]);
        float sum=0.f;
        for(int m=0;m<NODE_;m++){ z[m]=expf(z[m]-mx); sum+=z[m]; }
        for(int m=0;m<NODE_;m++) A[(size_t)bh*NODE_+m]=z[m]/sum;
    }
}

__global__ void k_topk(const float* __restrict__ voHat, int* __restrict__ idx){
    int bh = blockIdx.x;           // b*H + h
    int b = bh>>2, h = bh&3;
    __shared__ float mv[T_][C_];
    __shared__ float As[T_][T_];
    for(int e=threadIdx.x;e<T_*C_;e+=64){
        int t=e>>7, c=e&(C_-1);
        mv[t][c]=voHat[(size_t)(((b*T_+t)*H_+h)*D_+(D_-1))*C_+c];
    }
    __syncthreads();
    {
        int t=threadIdx.x>>3, s2=threadIdx.x&7;
        float acc=0.f;
        for(int c=0;c<C_;c++) acc+=mv[t][c]*mv[s2][c];
        As[t][s2]=acc;
    }
    __syncthreads();
    if(threadIdx.x<T_){
        int t=threadIdx.x;
        bool used[T_];
        for(int j=0;j<T_;j++) used[j]=false;
        for(int k=0;k<K_;k++){
            float mn=FLT_MAX; int bi=0;
            for(int s2=0;s2<T_;s2++){
                if(!used[s2] && As[t][s2]<mn){ mn=As[t][s2]; bi=s2; }
            }
            used[bi]=true;
            idx[((size_t)bh*T_+t)*K_+k]=bi;
        }
    }
}

__global__ void k_A_rev(const float* __restrict__ voHat, const int* __restrict__ idx,
                        const float* __restrict__ bias, const float* __restrict__ alpha_p,
                        float* __restrict__ A){
    int bth = blockIdx.x;          // bt*H + h
    int bt = bth>>2, h = bth&3;
    int b = bt>>3, t = bt&7;
    __shared__ float vo[D_][C_];
    __shared__ float vd[KD_][C_];
    __shared__ float z[D_][KD_];
    for(int e=threadIdx.x;e<D_*C_;e+=256){
        int n=e>>7, c=e&(C_-1);
        vo[n][c]=voHat[(size_t)((bt*H_+h)*D_+n)*C_+c];
    }
    for(int e=threadIdx.x;e<KD_*C_;e+=256){
        int m=e>>7, c=e&(C_-1);
        int k=m/D_, dp=m%D_;
        int tt=idx[((size_t)(b*H_+h)*T_+t)*K_+k];
        vd[m][c]=voHat[(size_t)(((b*T_+tt)*H_+h)*D_+dp)*C_+c];
    }
    __syncthreads();
    float alpha=alpha_p[0];
    if(threadIdx.x<D_*KD_){
        int n=threadIdx.x/KD_, m=threadIdx.x%KD_;
        float acc=0.f;
        for(int c=0;c<C_;c++) acc+=vo[n][c]*vd[m][c];
        z[n][m] = -acc/alpha + bias[n*KD_+m];
    }
    __syncthreads();
    if(threadIdx.x<D_){
        int n=threadIdx.x;
        float mx=-FLT_MAX;
        for(int m=0;m<KD_;m++) mx=fmaxf(mx,z[n][m]);
        float sum=0.f;
        for(int m=0;m<KD_;m++){ z[n][m]=expf(z[n][m]-mx); sum+=z[n][m]; }
        for(int m=0;m<KD_;m++) A[(size_t)((bt*H_+h)*D_+n)*KD_+m]=z[n][m]/sum;
    }
}

// ---------------- master aggregation (float4-vectorized) ----------------
__global__ void k_agg_tm(const float* __restrict__ mastersrc, int master_is_x,
                         const float* __restrict__ normal, const float* __restrict__ A,
                         float* __restrict__ out){
    int v = blockIdx.x*256 + threadIdx.x;       // < MS_/4
    int s4 = v % S4_;
    int r  = v / S4_;
    int hc = r & (HC_-1);
    int b  = r >> 9;
    int h = hc >> 7, c = hc & (C_-1);
    const float* Ap = A + (size_t)(b*H_+h)*NODE_;
    f32x4 m0;
    if(master_is_x) m0 = *(const f32x4*)(mastersrc + ((size_t)((b*H_+h)*NODE_)*C_ + c)*S_ + s4*4);
    else            m0 = *(const f32x4*)(mastersrc + (size_t)(b*HC_+hc)*S_ + s4*4);
    f32x4 acc = Ap[0]*m0;
    for(int t=0;t<T_;t++){
        const float* np = normal + ((size_t)((b*T_+t)*D_)*HC_+hc)*S_ + s4*4;
        #pragma unroll
        for(int d=0;d<D_;d++)
            acc += Ap[1+t*D_+d] * *(const f32x4*)(np + (size_t)d*HC_*S_);
    }
    *(f32x4*)(out + (size_t)r*S_ + s4*4) = acc;
}

// -------- shared dw+split tail (operates on ti -> to -> Xh/Xl) --------
__device__ __forceinline__ void dw_split_tail(float (*ti)[S_], float (*to)[S_],
                                              const float* __restrict__ w,
                                              const float* __restrict__ bias,
                                              int img, int ch0,
                                              u16* __restrict__ Xh, u16* __restrict__ Xl){
    int tid = threadIdx.x;
    for(int e=tid; e<16*S_; e+=256){
        int chl = e/S_, s = e - (e/S_)*S_;
        int ch = ch0 + chl;
        int y = s/HH_, xx = s - (s/HH_)*HH_;
        float acc = bias[ch];
        #pragma unroll
        for(int ky=0;ky<3;ky++){
            int yy=y+ky-1;
            if(yy<0||yy>=HH_) continue;
            #pragma unroll
            for(int kx=0;kx<3;kx++){
                int xx2=xx+kx-1;
                if(xx2<0||xx2>=HH_) continue;
                acc += ti[chl][yy*HH_+xx2]*w[ch*9+ky*3+kx];
            }
        }
        to[chl][s]=acc;
    }
    __syncthreads();
    for(int e=tid; e<16*S_; e+=256){
        int s = e>>4, chl = e&15;
        float f = to[chl][s];
        u16 h = f2bf(f);
        float lo = f - bf2f(h);
        size_t o = ((size_t)img*S_ + s)*HC_ + ch0 + chl;
        Xh[o] = h;
        Xl[o] = f2bf(lo);
    }
}

// ---------------- plain depthwise+split (master path) ----------------
__launch_bounds__(256)
__global__ void k_dwsplit(const float* __restrict__ in, const float* __restrict__ w,
                          const float* __restrict__ bias,
                          u16* __restrict__ Xh, u16* __restrict__ Xl){
    int img = blockIdx.x >> 5;
    int ch0 = (blockIdx.x & 31) * 16;
    __shared__ float ti[16][S_];
    __shared__ float to[16][S_];
    int tid = threadIdx.x;
    for(int e=tid; e<16*S4_; e+=256){
        int chl = e/S4_, s4 = e - (e/S4_)*S4_;
        *(f32x4*)&ti[chl][s4*4] =
            *(const f32x4*)(in + ((size_t)img*HC_ + ch0 + chl)*S_ + s4*4);
    }
    __syncthreads();
    dw_split_tail(ti, to, w, bias, img, ch0, Xh, Xl);
}

// ---------------- dwsplit + fused max-pool of the INPUT (pre-dw) ----------------
__launch_bounds__(256)
__global__ void k_dwsplit_pool(const float* __restrict__ in, const float* __restrict__ w,
                               const float* __restrict__ bias,
                               u16* __restrict__ Xh, u16* __restrict__ Xl,
                               float* __restrict__ pooled){
    int img = blockIdx.x >> 5;
    int ch0 = (blockIdx.x & 31) * 16;
    __shared__ float ti[16][S_];
    __shared__ float to[16][S_];
    __shared__ float pm[16][17];
    int tid = threadIdx.x;
    for(int e=tid; e<16*S4_; e+=256){
        int chl = e/S4_, s4 = e - (e/S4_)*S4_;
        *(f32x4*)&ti[chl][s4*4] =
            *(const f32x4*)(in + ((size_t)img*HC_ + ch0 + chl)*S_ + s4*4);
    }
    __syncthreads();
    dw_split_tail(ti, to, w, bias, img, ch0, Xh, Xl);
    {
        int chl = tid & 15, g = tid >> 4;
        float m = -FLT_MAX;
        for(int s=g; s<S_; s+=16) m = fmaxf(m, ti[chl][s]);
        pm[chl][g] = m;
    }
    __syncthreads();
    if(tid < 16){
        float mm = -FLT_MAX;
        #pragma unroll
        for(int g2=0; g2<16; g2++) mm = fmaxf(mm, pm[tid][g2]);
        int bt = img/7, d = img - (img/7)*7;
        pooled[(size_t)((bt*4 + (ch0>>7))*7 + d)*C_ + (ch0 & 127) + tid] = mm;
    }
}

// ---------------- fused IF: agg(7-term, float4) + dw + split ----------------
__launch_bounds__(256)
__global__ void k_fused_if(const float* __restrict__ x, const float* __restrict__ A,
                           const float* __restrict__ w, const float* __restrict__ bias,
                           u16* __restrict__ Xh, u16* __restrict__ Xl){
    int img = blockIdx.x >> 5;          // bt*7 + d
    int ch0 = (blockIdx.x & 31) * 16;
    int bt = img/7, d = img - bt*7;
    int b = bt >> 3, t = bt & 7;
    int h = ch0 >> 7, c0 = ch0 & 127;
    __shared__ float ti[16][S_];
    __shared__ float to[16][S_];
    float a[D_];
    #pragma unroll
    for(int m=0;m<D_;m++) a[m] = A[(size_t)((bt*4+h)*D_ + d)*D_ + m];
    int tid = threadIdx.x;
    const float* xb = x + ((size_t)((b*H_+h)*NODE_ + 1 + t*D_)*C_ + c0)*S_;
    for(int e=tid; e<16*S4_; e+=256){
        int chl = e/S4_, s4 = e - (e/S4_)*S4_;
        const f32x4* xp = (const f32x4*)(xb + (size_t)chl*S_) + s4;
        f32x4 acc = {0.f,0.f,0.f,0.f};
        #pragma unroll
        for(int m=0;m<D_;m++) acc += a[m]*xp[(size_t)m*C_*S4_];
        *(f32x4*)&ti[chl][s4*4] = acc;
    }
    __syncthreads();
    dw_split_tail(ti, to, w, bias, img, ch0, Xh, Xl);
}

// ---------------- fused REV: gather-agg(21-term, float4) + dw + split ----------------
__launch_bounds__(256)
__global__ void k_fused_rev(const float* __restrict__ n2, const float* __restrict__ A,
                            const int* __restrict__ idx,
                            const float* __restrict__ w, const float* __restrict__ bias,
                            u16* __restrict__ Xh, u16* __restrict__ Xl){
    int img = blockIdx.x >> 5;          // bt*7 + d
    int ch0 = (blockIdx.x & 31) * 16;
    int bt = img/7, d = img - bt*7;
    int b = bt >> 3, t = bt & 7;
    int h = ch0 >> 7;
    __shared__ float ti[16][S_];
    __shared__ float to[16][S_];
    float a[KD_];
    #pragma unroll
    for(int j=0;j<KD_;j++) a[j] = A[(size_t)((bt*4+h)*D_ + d)*KD_ + j];
    int tt0 = idx[((size_t)(b*H_+h)*T_+t)*K_+0];
    int tt1 = idx[((size_t)(b*H_+h)*T_+t)*K_+1];
    int tt2 = idx[((size_t)(b*H_+h)*T_+t)*K_+2];
    const f32x4* p0 = (const f32x4*)(n2 + ((size_t)((b*T_+tt0)*D_)*HC_ + ch0)*S_);
    const f32x4* p1 = (const f32x4*)(n2 + ((size_t)((b*T_+tt1)*D_)*HC_ + ch0)*S_);
    const f32x4* p2 = (const f32x4*)(n2 + ((size_t)((b*T_+tt2)*D_)*HC_ + ch0)*S_);
    int tid = threadIdx.x;
    for(int e=tid; e<16*S4_; e+=256){
        int chl = e/S4_, s4 = e - (e/S4_)*S4_;
        size_t off = (size_t)chl*S4_ + s4;
        f32x4 acc = {0.f,0.f,0.f,0.f};
        #pragma unroll
        for(int dp=0;dp<D_;dp++){
            size_t o2 = off + (size_t)dp*HC_*S4_;
            acc += a[dp]      * p0[o2];
            acc += a[D_+dp]   * p1[o2];
            acc += a[2*D_+dp] * p2[o2];
        }
        *(f32x4*)&ti[chl][s4*4] = acc;
    }
    __syncthreads();
    dw_split_tail(ti, to, w, bias, img, ch0, Xh, Xl);
}

// ---------------- weight prep: fp32 [oc][ic] -> bf16 Waug [oc][hi 512 | lo 512] ----------------
__global__ void k_prepW(const float* __restrict__ Wg, u16* __restrict__ Waug){
    int i = blockIdx.x*256 + threadIdx.x;   // < 512*512
    int oc = i >> 9, ic = i & 511;
    float f = Wg[i];
    u16 h = f2bf(f);
    float lo = f - bf2f(h);
    size_t base = (size_t)oc*WS_;
    Waug[base + ic]       = h;
    Waug[base + 512 + ic] = f2bf(lo);
}

// ---------------- MFMA pointwise GEMM (split-bf16, 24 K-tiles) ----------------
__launch_bounds__(512)
__global__ void k_pwmfma(const u16* __restrict__ Xh, const u16* __restrict__ Xl,
                         const u16* __restrict__ Waug, const float* __restrict__ bias,
                         const float* __restrict__ res, float* __restrict__ out,
                         int nwg, int utot){
    __shared__ u16 SM[2][16384];           // 2 x 32KB: [As 8192 u16 | Bs 8192 u16]
    const int tid  = threadIdx.x;
    const int q = nwg >> 3, r = nwg & 7;
    int xcd = blockIdx.x & 7, j = blockIdx.x >> 3;
    int L = xcd*q + (xcd < r ? xcd : r) + j;
    const int u0   = (L >> 2) * 128;
    const int oc0  = (L & 3) * 128;
    const int lane = tid & 63;
    const int w    = tid >> 6;             // 0..7
    const int wr   = w >> 1, wc = w & 1;   // 4 x 2 wave grid
    const int l15  = lane & 15, lg = lane >> 4;

    f32x4 acc[2][4];
    #pragma unroll
    for(int mi=0;mi<2;mi++)
        #pragma unroll
        for(int ni=0;ni<4;ni++)
            acc[mi][ni] = (f32x4){0.f,0.f,0.f,0.f};

    auto STAGE = [&](int t){               // 4 gld16 issues per wave (2A + 2B)
        int jj, wk, xk; const u16* Xp;
        if(t < 16){ jj = t>>1; wk = (t&1) ? 512 + jj*64 : jj*64; Xp = Xh; xk = jj*64; }
        else      { jj = t-16; wk = jj*64;                        Xp = Xl; xk = jj*64; }
        u16* Asb = SM[t&1];
        u16* Bsb = Asb + 8192;
        #pragma unroll
        for(int i=0;i<2;i++){
            int seg = w*2 + i;             // 0..15, 8 rows each
            int row = seg*8 + (lane>>3);
            int cg  = (lane&7) ^ (lane>>3);
            gld16(Waug + (size_t)(oc0+row)*WS_ + wk + cg*8, Asb + seg*512);
            gld16(Xp   + (size_t)(u0 +row)*512 + xk + cg*8, Bsb + seg*512);
        }
    };
    auto COMPUTE = [&](int cur){
        const u16* Asb = SM[cur];
        const u16* Bsb = SM[cur] + 8192;
        #pragma unroll
        for(int ks=0;ks<2;ks++){
            bf16x8 a[2], b[4];
            #pragma unroll
            for(int mi=0;mi<2;mi++){
                int row = wr*32 + mi*16 + l15;
                int ch  = ((ks<<2) + lg) ^ (row & 7);
                a[mi] = *(const bf16x8*)(Asb + row*64 + ch*8);
            }
            #pragma unroll
            for(int ni=0;ni<4;ni++){
                int row = wc*64 + ni*16 + l15;
                int ch  = ((ks<<2) + lg) ^ (row & 7);
                b[ni] = *(const bf16x8*)(Bsb + row*64 + ch*8);
            }
            #pragma unroll
            for(int mi=0;mi<2;mi++)
                #pragma unroll
                for(int ni=0;ni<4;ni++)
                    acc[mi][ni] = __builtin_amdgcn_mfma_f32_16x16x32_bf16(a[mi], b[ni], acc[mi][ni], 0,0,0);
        }
    };

    STAGE(0);
    for(int t=0; t<NT_; t++){
        if(t+1 < NT_){
            STAGE(t+1);                                      // 8 outstanding/wave
            asm volatile("s_waitcnt vmcnt(4)" ::: "memory"); // tile t landed
        } else {
            asm volatile("s_waitcnt vmcnt(0)" ::: "memory");
        }
        __builtin_amdgcn_s_barrier();      // all waves' tile-t loads in LDS
        asm volatile("" ::: "memory");
        COMPUTE(t&1);
        asm volatile("" ::: "memory");
        __builtin_amdgcn_s_barrier();      // buf[t&1] free for restage
    }

    #pragma unroll
    for(int ni=0;ni<4;ni++){
        int u = u0 + wc*64 + ni*16 + l15;
        if(u >= utot) continue;
        int img = u / S_, s = u - img*S_;
        #pragma unroll
        for(int mi=0;mi<2;mi++){
            int ocb = oc0 + wr*32 + mi*16 + lg*4;
            #pragma unroll
            for(int q2=0;q2<4;q2++){
                int oc = ocb + q2;
                size_t oidx = ((size_t)img*HC_ + oc)*S_ + s;
                float v = acc[mi][ni][q2] + bias[oc];
                if(res) v += res[oidx];
                out[oidx] = v;
            }
        }
    }
}

extern "C" void kernel_launch(void* const* d_in, const int* in_sizes, int n_in,
                              void* d_out, int out_size, void* d_ws, size_t ws_size,
                              hipStream_t stream){
    (void)in_sizes; (void)n_in; (void)out_size; (void)ws_size;
    const float* x         = (const float*)d_in[0];
    const float* alpha_if  = (const float*)d_in[1];
    const float* alpha_tm1 = (const float*)d_in[2];
    const float* alpha_rev = (const float*)d_in[3];
    const float* alpha_tm2 = (const float*)d_in[4];
    const float* bias_if   = (const float*)d_in[5];
    const float* bias_tm1  = (const float*)d_in[6];
    const float* bias_rev  = (const float*)d_in[7];
    const float* bias_tm2  = (const float*)d_in[8];
    const float* if_dw =(const float*)d_in[9];  const float* if_dwb =(const float*)d_in[10];
    const float* if_pw =(const float*)d_in[11]; const float* if_pwb =(const float*)d_in[12];
    const float* tm1_dw=(const float*)d_in[13]; const float* tm1_dwb=(const float*)d_in[14];
    const float* tm1_pw=(const float*)d_in[15]; const float* tm1_pwb=(const float*)d_in[16];
    const float* rev_dw=(const float*)d_in[17]; const float* rev_dwb=(const float*)d_in[18];
    const float* rev_pw=(const float*)d_in[19]; const float* rev_pwb=(const float*)d_in[20];
    const float* tm2_dw=(const float*)d_in[21]; const float* tm2_dwb=(const float*)d_in[22];
    const float* tm2_pw=(const float*)d_in[23]; const float* tm2_pwb=(const float*)d_in[24];
    const float* tr_dw =(const float*)d_in[25]; const float* tr_dwb =(const float*)d_in[26];
    const float* tr_pw =(const float*)d_in[27]; const float* tr_pwb =(const float*)d_in[28];

    float* ws = (float*)d_ws;
    float* G0      = ws;                          // BIG_ fp32
    float* G1      = G0 + (size_t)BIG_;           // BIG_ fp32
    u16*   Xh      = (u16*)(ws + 2*(size_t)BIG_); // BIG_ u16
    u16*   Xl      = Xh + (size_t)BIG_;           // BIG_ u16
    u16*   WA0     = Xl + (size_t)BIG_;           // 512*1024 u16 each
    u16*   WA1     = WA0 + 512*WS_;
    u16*   WA2     = WA1 + 512*WS_;
    u16*   WA3     = WA2 + 512*WS_;               // tm1
    u16*   WA4     = WA3 + 512*WS_;               // tm2
    u16*   XhM     = WA4 + 512*WS_;               // UMP_*512 u16 master X
    u16*   XlM     = XhM + (size_t)UMP_*HC_;
    float* master1 = (float*)(XlM + (size_t)UMP_*HC_);   // MS_
    float* Ma      = master1 + MS_;               // MS_
    float* pooledN = Ma + MS_;                    // 114688
    float* pooledM = pooledN + BT_*H_*D_*C_;      // 2048
    float* Aif     = pooledM + B_*H_*C_;          // 6272
    float* Atm1    = Aif + BT_*H_*D_*D_;          // 912
    float* Arev    = Atm1 + B_*H_*NODE_;          // 18816
    float* Atm2    = Arev + BT_*H_*D_*KD_;        // 912
    int*   idxb    = (int*)(Atm2 + B_*H_*NODE_);  // 384 ints
    float* out     = (float*)d_out;

    const int NV  = BT_*H_*D_*C_;     // pooled rows
    const int gemmGrid  = (UB_/128)*4;          // 1372
    const int gemmGridM = (UMP_/128)*4;         // 28
    const int dsGrid    = BT_*D_*32;  // 7168 (16-ch chunks)
    const int dsGridM   = B_*32;      // 128
    float* null_res = nullptr;

    // weight prep (all five pw weights)
    k_prepW<<<1024, 256, 0, stream>>>(if_pw,  WA0);
    k_prepW<<<1024, 256, 0, stream>>>(tr_pw,  WA1);
    k_prepW<<<1024, 256, 0, stream>>>(rev_pw, WA2);
    k_prepW<<<1024, 256, 0, stream>>>(tm1_pw, WA3);
    k_prepW<<<1024, 256, 0, stream>>>(tm2_pw, WA4);

    // ---- stage 1: IF ----
    k_pool_x   <<<NV/4, 256, 0, stream>>>(x, pooledN);
    k_normalize<<<NV/C_, 128, 0, stream>>>(pooledN);
    k_A_if     <<<BT_*H_, 64, 0, stream>>>(pooledN, bias_if, alpha_if, Aif);
    k_fused_if <<<dsGrid, 256, 0, stream>>>(x, Aif, if_dw, if_dwb, Xh, Xl);
    k_pwmfma   <<<gemmGrid, 512, 0, stream>>>(Xh, Xl, WA0, if_pwb, null_res, G1, gemmGrid, UB_);
    // G1 = normal1

    // ---- stage 2+3 (reordered): tr dwsplit+pool first, then masters, then tr GEMM ----
    k_dwsplit_pool<<<dsGrid, 256, 0, stream>>>(G1, tr_dw, tr_dwb, Xh, Xl, pooledN);
    k_normalize<<<NV/C_, 128, 0, stream>>>(pooledN);
    k_pool_x_master<<<(B_*H_*C_)/4, 256, 0, stream>>>(x, pooledM);
    k_normalize<<<B_*H_, 128, 0, stream>>>(pooledM);
    k_A_tm     <<<B_*H_, 64, 0, stream>>>(pooledM, pooledN, bias_tm1, alpha_tm1, Atm1);
    k_agg_tm   <<<MS_/1024, 256, 0, stream>>>(x, 1, G1, Atm1, Ma);
    k_dwsplit  <<<dsGridM, 256, 0, stream>>>(Ma, tm1_dw, tm1_dwb, XhM, XlM);
    k_pwmfma   <<<gemmGridM, 512, 0, stream>>>(XhM, XlM, WA3, tm1_pwb, null_res, master1, gemmGridM, UM_);
    k_pwmfma   <<<gemmGrid, 512, 0, stream>>>(Xh, Xl, WA1, tr_pwb, null_res, G0, gemmGrid, UB_);
    // G0 = normal2

    // ---- stage 4: rev ----
    k_pool_conv<<<NV/4, 256, 0, stream>>>(G0, pooledN);
    k_normalize<<<NV/C_, 128, 0, stream>>>(pooledN);
    k_topk     <<<B_*H_, 64, 0, stream>>>(pooledN, idxb);
    k_A_rev    <<<BT_*H_, 256, 0, stream>>>(pooledN, idxb, bias_rev, alpha_rev, Arev);
    k_fused_rev<<<dsGrid, 256, 0, stream>>>(G0, Arev, idxb, rev_dw, rev_dwb, Xh, Xl);
    k_pwmfma   <<<gemmGrid, 512, 0, stream>>>(Xh, Xl, WA2, rev_pwb, G0, G1, gemmGrid, UB_);
    // G1 = normal3 (residual fused)

    // ---- stage 5: tm2 master -> output ----
    k_pool_conv<<<NV/4, 256, 0, stream>>>(G1, pooledN);
    k_normalize<<<NV/C_, 128, 0, stream>>>(pooledN);
    k_pool_m1  <<<(B_*H_*C_)/4, 256, 0, stream>>>(master1, pooledM);
    k_normalize<<<B_*H_, 128, 0, stream>>>(pooledM);
    k_A_tm     <<<B_*H_, 64, 0, stream>>>(pooledM, pooledN, bias_tm2, alpha_tm2, Atm2);
    k_agg_tm   <<<MS_/1024, 256, 0, stream>>>(master1, 0, G1, Atm2, Ma);
    k_dwsplit  <<<dsGridM, 256, 0, stream>>>(Ma, tm2_dw, tm2_dwb, XhM, XlM);
    k_pwmfma   <<<gemmGridM, 512, 0, stream>>>(XhM, XlM, WA4, tm2_pwb, null_res, out, gemmGridM, UM_);
}